// Round 11
// baseline (277.252 us; speedup 1.0000x reference)
//
#include <hip/hip_runtime.h>

#define BB   8
#define CIN  96
#define DIN  192
#define HH   64
#define WW   64
#define LL   4096
#define KK   4
#define COUT 96
#define SS   128  // scan segments
#define LC   32   // segment length = LL/SS

#define LOG2E 1.4426950408889634f
#define LN2   0.6931471805599453f

__device__ __forceinline__ float exp2fast(float x) { return __builtin_amdgcn_exp2f(x); }
__device__ __forceinline__ float log2fast(float x) { return __builtin_amdgcn_logf(x); }
__device__ __forceinline__ float sigf(float x) { return 1.0f / (1.0f + __expf(-x)); }
__device__ __forceinline__ int trp(int p) { return ((p & 63) << 6) | (p >> 6); }
__device__ __forceinline__ int pix_of(int k, int l) {
  if (k == 0) return l;
  if (k == 1) return trp(l);
  if (k == 2) return LL - 1 - l;
  return trp(LL - 1 - l);
}

// ---------------------------------------------------------------------------
// Per-pixel GEMM: out[b,o,p] = sum_c in[b,c,p] * W[o,c]   (in_proj)
// ---------------------------------------------------------------------------
template <int C>
__global__ __launch_bounds__(256) void gemm_pix_k(const float* __restrict__ in,
                                                  const float* __restrict__ W,
                                                  float* __restrict__ out, int O) {
  __shared__ float sW[C * 8];
  const int tid = threadIdx.x;
  const int b  = blockIdx.z;
  const int o0 = blockIdx.y * 8;
  const int p0 = blockIdx.x * 1024;
  for (int idx = tid; idx < C * 8; idx += 256) {
    int c = idx >> 3, j = idx & 7;
    sW[idx] = W[(o0 + j) * C + c];
  }
  __syncthreads();
  float acc[4][8];
#pragma unroll
  for (int jp = 0; jp < 4; ++jp)
#pragma unroll
    for (int j = 0; j < 8; ++j) acc[jp][j] = 0.0f;
  const float* inb = in + (size_t)b * C * LL + p0 + tid;
#pragma unroll 2
  for (int c = 0; c < C; ++c) {
    float xv[4];
#pragma unroll
    for (int jp = 0; jp < 4; ++jp) xv[jp] = inb[(size_t)c * LL + jp * 256];
    const float4 w0 = *(const float4*)&sW[c * 8];
    const float4 w1 = *(const float4*)&sW[c * 8 + 4];
#pragma unroll
    for (int jp = 0; jp < 4; ++jp) {
      acc[jp][0] = fmaf(xv[jp], w0.x, acc[jp][0]);
      acc[jp][1] = fmaf(xv[jp], w0.y, acc[jp][1]);
      acc[jp][2] = fmaf(xv[jp], w0.z, acc[jp][2]);
      acc[jp][3] = fmaf(xv[jp], w0.w, acc[jp][3]);
      acc[jp][4] = fmaf(xv[jp], w1.x, acc[jp][4]);
      acc[jp][5] = fmaf(xv[jp], w1.y, acc[jp][5]);
      acc[jp][6] = fmaf(xv[jp], w1.z, acc[jp][6]);
      acc[jp][7] = fmaf(xv[jp], w1.w, acc[jp][7]);
    }
  }
  float* ob = out + (size_t)b * O * LL + p0 + tid;
#pragma unroll
  for (int j = 0; j < 8; ++j)
#pragma unroll
    for (int jp = 0; jp < 4; ++jp) ob[(size_t)(o0 + j) * LL + jp * 256] = acc[jp][j];
}

// ---------------------------------------------------------------------------
// PriorToWeights MLP -> Wg[B,4,L].  Block 0: transpose xpw -> xpwT[k][dd][8].
// Block 1: transpose opw -> opwT[dd][o].  (consumers launch later; no race)
// ---------------------------------------------------------------------------
__global__ __launch_bounds__(256) void p2w_k(const float* __restrict__ prior,
                                             const float* __restrict__ alpha,
                                             const float* __restrict__ w1,
                                             const float* __restrict__ b1,
                                             const float* __restrict__ bnw,
                                             const float* __restrict__ bnb,
                                             const float* __restrict__ bnm,
                                             const float* __restrict__ bnv,
                                             const float* __restrict__ w2,
                                             const float* __restrict__ b2,
                                             const float* __restrict__ xpw,
                                             const float* __restrict__ opw,
                                             float* __restrict__ xpwT,
                                             float* __restrict__ opwT,
                                             float* __restrict__ Wg) {
  if (blockIdx.x == 0) {
    for (int idx = threadIdx.x; idx < KK * DIN * 8; idx += 256) {
      int kk = idx / (DIN * 8);
      int rem = idx % (DIN * 8);
      int dd = rem >> 3, c = rem & 7;
      xpwT[idx] = xpw[(kk * 8 + c) * DIN + dd];
    }
  }
  if (blockIdx.x == 1) {
    for (int idx = threadIdx.x; idx < DIN * COUT; idx += 256) {
      int dd = idx / COUT, o = idx % COUT;
      opwT[idx] = opw[o * DIN + dd];
    }
  }
  int idx = blockIdx.x * 256 + threadIdx.x;
  int p = idx & (LL - 1);
  int b = idx >> 12;
  float pr[4];
#pragma unroll
  for (int c = 0; c < 4; ++c) pr[c] = prior[((size_t)b * 4 + c) * LL + p];
  float s = sigf(alpha[0]);
  float g2[4];
#pragma unroll
  for (int j = 0; j < 4; ++j) g2[j] = b2[j];
  for (int o = 0; o < 32; ++o) {
    float g = b1[o];
#pragma unroll
    for (int c = 0; c < 4; ++c) g = fmaf(pr[c], w1[o * 4 + c], g);
    g = (g - bnm[o]) * rsqrtf(bnv[o] + 1e-5f) * bnw[o] + bnb[o];
    g = fmaxf(g, 0.0f);
#pragma unroll
    for (int j = 0; j < 4; ++j) g2[j] = fmaf(g, w2[j * 32 + o], g2[j]);
  }
#pragma unroll
  for (int j = 0; j < 4; ++j)
    Wg[((size_t)b * 4 + j) * LL + p] = 1.0f + s * (sigf(g2[j]) - 1.0f);
}

// ---------------------------------------------------------------------------
// FUSED conv+proj (R9 version: 64-px row tiles, best measured: 78.6us).
// ---------------------------------------------------------------------------
__global__ __launch_bounds__(256) void convproj_k(const float* __restrict__ xz,
                                                  const float* __restrict__ cw,
                                                  const float* __restrict__ cb,
                                                  const float* __restrict__ xpwT,
                                                  float* __restrict__ xcT,
                                                  float* __restrict__ projS) {
  __shared__ float sX[96 * 65];  // 24.96 KB
  const int tid = threadIdx.x;
  const int b = blockIdx.y;
  const int h = blockIdx.x;
  const int px = tid & 63;
  const int ku = __builtin_amdgcn_readfirstlane(tid >> 6);  // wave-uniform k
  const float* wpk = xpwT + (size_t)ku * (DIN * 8);
  float acc[8];
#pragma unroll
  for (int c = 0; c < 8; ++c) acc[c] = 0.0f;

#pragma unroll
  for (int half = 0; half < 2; ++half) {
    for (int idx = tid; idx < 96 * 64; idx += 256) {
      int ddl = idx >> 6, pxx = idx & 63;
      int dd = half * 96 + ddl;
      const float* xp = xz + ((size_t)b * 384 + dd) * LL + h * 64 + pxx;
      const float* wp = cw + dd * 9;
      float s = cb[dd];
#pragma unroll
      for (int dh = -1; dh <= 1; ++dh) {
        int hh = h + dh;
        if (hh < 0 || hh >= HH) continue;
        const float* row = xp + dh * 64;
        float w0 = wp[(dh + 1) * 3], w1 = wp[(dh + 1) * 3 + 1], w2 = wp[(dh + 1) * 3 + 2];
        if (pxx > 0) s = fmaf(row[-1], w0, s);
        s = fmaf(row[0], w1, s);
        if (pxx < 63) s = fmaf(row[1], w2, s);
      }
      sX[ddl * 65 + pxx] = s * sigf(s);
    }
    __syncthreads();
    for (int idx = tid; idx < 64 * 96; idx += 256) {
      int pp = idx / 96, ddl = idx % 96;
      xcT[((size_t)b * LL + h * 64 + pp) * DIN + half * 96 + ddl] = sX[ddl * 65 + pp];
    }
    const float* wp = wpk + half * 96 * 8;
    for (int ddl = 0; ddl < 96; ++ddl) {
      float xv = sX[ddl * 65 + px];
      const float4 w0 = *(const float4*)(wp + ddl * 8);
      const float4 w1 = *(const float4*)(wp + ddl * 8 + 4);
      acc[0] = fmaf(xv, w0.x, acc[0]);
      acc[1] = fmaf(xv, w0.y, acc[1]);
      acc[2] = fmaf(xv, w0.z, acc[2]);
      acc[3] = fmaf(xv, w0.w, acc[3]);
      acc[4] = fmaf(xv, w1.x, acc[4]);
      acc[5] = fmaf(xv, w1.y, acc[5]);
      acc[6] = fmaf(xv, w1.z, acc[6]);
      acc[7] = fmaf(xv, w1.w, acc[7]);
    }
    __syncthreads();
  }
  const int p = h * 64 + px;
  int l;
  if (ku == 0) l = p;
  else if (ku == 1) l = trp(p);
  else if (ku == 2) l = LL - 1 - p;
  else l = LL - 1 - trp(p);
  float* pb = projS + (((size_t)b * KK + ku) * LL + l) * 8;
  *(float4*)pb = make_float4(acc[0], acc[1], acc[2], acc[3]);
  *(float4*)(pb + 4) = make_float4(acc[4], acc[5], acc[6], acc[7]);
}

// ---------------------------------------------------------------------------
// Scan pass 1 (PAIRED): one xcT pass computes carries for BOTH opposite
// directions. Forward dir kA: compose-after (H=aH+b; P*=a). Reverse dir kB
// (same pixels, reverse order): compose-before (H += P*b; P *= a).
// ---------------------------------------------------------------------------
__global__ __launch_bounds__(192) void scan_part_k(const float* __restrict__ xcT,
                                                   const float* __restrict__ projS,
                                                   const float* __restrict__ dtw,
                                                   const float* __restrict__ dtb,
                                                   const float* __restrict__ A_logs,
                                                   float* __restrict__ carrP,
                                                   float* __restrict__ carrH) {
  const int s = blockIdx.x, kp = blockIdx.y, b = blockIdx.z;
  const int d = threadIdx.x;
  const int kA = kp, kB = kp + 2;
  const int s2 = SS - 1 - s;
  const int kdA = kA * DIN + d, kdB = kB * DIN + d;
  float wrA[6], wrB[6];
#pragma unroll
  for (int r = 0; r < 6; ++r) { wrA[r] = dtw[kdA * 6 + r]; wrB[r] = dtw[kdB * 6 + r]; }
  const float biasA = dtb[kdA], biasB = dtb[kdB];
  const float AaA = -__expf(A_logs[kdA]), AaB = -__expf(A_logs[kdB]);
  const int l0 = s * LC;
  const int p0 = pix_of(kA, l0);
  const int dp = pix_of(kA, l0 + 1) - p0;
  const float* xp = xcT + ((size_t)b * LL + p0) * DIN + d;
  const long xstep = (long)dp * DIN;
  const float* prA = projS + (((size_t)b * KK + kA) * LL + l0) * 8;
  const float* prB = projS + (((size_t)b * KK + kB) * LL + s2 * LC + (LC - 1)) * 8;
  float PA = 1.0f, HA = 0.0f, PB = 1.0f, HB = 0.0f;
#pragma unroll 2
  for (int j = 0; j < LC; ++j) {
    float4 a0 = *(const float4*)prA;
    float4 a1 = *(const float4*)(prA + 4);
    prA += 8;
    float4 b0 = *(const float4*)prB;
    float4 b1 = *(const float4*)(prB + 4);
    prB -= 8;
    float xv = *xp;
    xp += xstep;
    // dir A
    {
      float dtr = biasA;
      dtr = fmaf(a0.x, wrA[0], dtr);
      dtr = fmaf(a0.y, wrA[1], dtr);
      dtr = fmaf(a0.z, wrA[2], dtr);
      dtr = fmaf(a0.w, wrA[3], dtr);
      dtr = fmaf(a1.x, wrA[4], dtr);
      dtr = fmaf(a1.y, wrA[5], dtr);
      float e = exp2fast(fminf(dtr, 80.0f) * LOG2E);
      float u = log2fast(1.0f + e);
      float a = exp2fast(u * AaA);
      float dt = u * LN2;
      HA = fmaf(a, HA, dt * a1.z * xv);
      PA *= a;
    }
    // dir B (compose-before)
    {
      float dtr = biasB;
      dtr = fmaf(b0.x, wrB[0], dtr);
      dtr = fmaf(b0.y, wrB[1], dtr);
      dtr = fmaf(b0.z, wrB[2], dtr);
      dtr = fmaf(b0.w, wrB[3], dtr);
      dtr = fmaf(b1.x, wrB[4], dtr);
      dtr = fmaf(b1.y, wrB[5], dtr);
      float e = exp2fast(fminf(dtr, 80.0f) * LOG2E);
      float u = log2fast(1.0f + e);
      float a = exp2fast(u * AaB);
      float dt = u * LN2;
      HB = fmaf(PB, dt * b1.z * xv, HB);
      PB *= a;
    }
  }
  size_t oA = ((size_t)((b * KK + kA) * SS + s)) * DIN + d;
  size_t oB = ((size_t)((b * KK + kB) * SS + s2)) * DIN + d;
  carrP[oA] = PA;
  carrH[oA] = HA;
  carrP[oB] = PB;
  carrH[oB] = HB;
}

// ---------------------------------------------------------------------------
// Scan pass 2: serial combine of SS carries -> per-segment initial state h0
// ---------------------------------------------------------------------------
__global__ __launch_bounds__(192) void scan_fix_k(const float* __restrict__ carrP,
                                                  const float* __restrict__ carrH,
                                                  float* __restrict__ h0) {
  const int k = blockIdx.x, b = blockIdx.y, d = threadIdx.x;
  size_t base = ((size_t)(b * KK + k)) * SS * DIN + d;
  float h = 0.0f;
#pragma unroll 4
  for (int s = 0; s < SS; ++s) {
    h0[base + (size_t)s * DIN] = h;
    h = fmaf(carrP[base + (size_t)s * DIN], h, carrH[base + (size_t)s * DIN]);
  }
}

// ---------------------------------------------------------------------------
// Scan pass 3: apply + gate + paired-direction merge via 24 KB LDS.
// ---------------------------------------------------------------------------
__global__ __launch_bounds__(192) void scan_apply_k(const float* __restrict__ xcT,
                                                    const float* __restrict__ projS,
                                                    const float* __restrict__ Wg,
                                                    const float* __restrict__ h0,
                                                    const float* __restrict__ dtw,
                                                    const float* __restrict__ dtb,
                                                    const float* __restrict__ A_logs,
                                                    const float* __restrict__ Ds,
                                                    float* __restrict__ ymT,
                                                    float* __restrict__ ymT2) {
  const int s = blockIdx.x, kp = blockIdx.y, b = blockIdx.z;
  const int d = threadIdx.x;
  __shared__ float sAcc[LC * DIN];  // 24 KB, column d thread-private
  {
    const int k = kp, kd = k * DIN + d;
    float wr[6];
#pragma unroll
    for (int r = 0; r < 6; ++r) wr[r] = dtw[kd * 6 + r];
    const float bias = dtb[kd];
    const float Aa = -__expf(A_logs[kd]);
    const float Dv = Ds[kd];
    const int l0 = s * LC;
    const int p0 = pix_of(k, l0);
    const int dp = pix_of(k, l0 + 1) - p0;
    const float* xp = xcT + ((size_t)b * LL + p0) * DIN + d;
    const long xstep = (long)dp * DIN;
    const float* pr = projS + (((size_t)b * KK + k) * LL + l0) * 8;
    const float* wg = Wg + ((size_t)b * KK + k) * LL + l0;
    float h = h0[((size_t)((b * KK + k) * SS + s)) * DIN + d];
#pragma unroll 4
    for (int j = 0; j < LC; ++j) {
      float4 q0 = *(const float4*)pr;
      float4 q1 = *(const float4*)(pr + 4);
      pr += 8;
      float xv = *xp;
      xp += xstep;
      float dtr = bias;
      dtr = fmaf(q0.x, wr[0], dtr);
      dtr = fmaf(q0.y, wr[1], dtr);
      dtr = fmaf(q0.z, wr[2], dtr);
      dtr = fmaf(q0.w, wr[3], dtr);
      dtr = fmaf(q1.x, wr[4], dtr);
      dtr = fmaf(q1.y, wr[5], dtr);
      float e = exp2fast(fminf(dtr, 80.0f) * LOG2E);
      float u = log2fast(1.0f + e);
      float a = exp2fast(u * Aa);
      float dt = u * LN2;
      h = fmaf(a, h, dt * q1.z * xv);
      sAcc[j * DIN + d] = fmaf(h, q1.w, Dv * xv) * wg[j];
    }
  }
  {
    const int k = kp + 2, kd = k * DIN + d;
    const int s2 = SS - 1 - s;
    float wr[6];
#pragma unroll
    for (int r = 0; r < 6; ++r) wr[r] = dtw[kd * 6 + r];
    const float bias = dtb[kd];
    const float Aa = -__expf(A_logs[kd]);
    const float Dv = Ds[kd];
    const int l0 = s2 * LC;
    const int p0 = pix_of(k, l0);
    const int dp = pix_of(k, l0 + 1) - p0;
    const float* xp = xcT + ((size_t)b * LL + p0) * DIN + d;
    const long xstep = (long)dp * DIN;
    const float* pr = projS + (((size_t)b * KK + k) * LL + l0) * 8;
    const float* wg = Wg + ((size_t)b * KK + k) * LL + l0;
    float h = h0[((size_t)((b * KK + k) * SS + s2)) * DIN + d];
#pragma unroll 4
    for (int j = 0; j < LC; ++j) {
      float4 q0 = *(const float4*)pr;
      float4 q1 = *(const float4*)(pr + 4);
      pr += 8;
      float xv = *xp;
      xp += xstep;
      float dtr = bias;
      dtr = fmaf(q0.x, wr[0], dtr);
      dtr = fmaf(q0.y, wr[1], dtr);
      dtr = fmaf(q0.z, wr[2], dtr);
      dtr = fmaf(q0.w, wr[3], dtr);
      dtr = fmaf(q1.x, wr[4], dtr);
      dtr = fmaf(q1.y, wr[5], dtr);
      float e = exp2fast(fminf(dtr, 80.0f) * LOG2E);
      float u = log2fast(1.0f + e);
      float a = exp2fast(u * Aa);
      float dt = u * LN2;
      h = fmaf(a, h, dt * q1.z * xv);
      float y = fmaf(h, q1.w, Dv * xv) * wg[j];
      sAcc[(LC - 1 - j) * DIN + d] += y;
    }
  }
  float* dst;
  if (kp == 0)
    dst = ymT + (size_t)b * (384 * (size_t)LL) + (size_t)(s * LC) * DIN + d;  // xz overlay
  else
    dst = ymT2 + ((size_t)b * LL + s * LC) * DIN + d;
#pragma unroll 4
  for (int j = 0; j < LC; ++j) dst[(size_t)j * DIN] = sAcc[j * DIN + d];
}

// ---------------------------------------------------------------------------
// FUSED LayerNorm(channel) * silu(z) + out_proj GEMM.  Block = 64 px, 512 thr.
// u-tile stays in LDS; wave g computes out-ch [g*12, g*12+12).
// ---------------------------------------------------------------------------
__global__ __launch_bounds__(512) void ln_gemm_k(const float* __restrict__ ymT,
                                                 const float* __restrict__ ymT2,
                                                 const float* __restrict__ xz,
                                                 const float* __restrict__ gamma,
                                                 const float* __restrict__ beta,
                                                 const float* __restrict__ opwT,
                                                 float* __restrict__ out) {
  const int b = blockIdx.y;
  const int h = blockIdx.x;
  const int p0 = h * 64;
  __shared__ float sY[64 * 193];  // 49.4 KB
  __shared__ float sS[8][64], sQ[8][64];
  const int tid = threadIdx.x;
  const float* ymb = ymT + (size_t)b * (384 * (size_t)LL);  // xz overlay
  for (int idx = tid; idx < 64 * DIN; idx += 512) {
    int pp = idx / DIN, dd = idx % DIN;
    sY[pp * 193 + dd] = ymb[(size_t)(p0 + pp) * DIN + dd] +
                        ymT2[((size_t)b * LL + pp * 64 + h) * DIN + dd];
  }
  __syncthreads();
  const int px = tid & 63, g = tid >> 6;  // g in [0,8)
  float sum = 0.0f, ss = 0.0f;
  for (int dd = g * 24; dd < g * 24 + 24; ++dd) {
    float v = sY[px * 193 + dd];
    sum += v;
    ss = fmaf(v, v, ss);
  }
  sS[g][px] = sum;
  sQ[g][px] = ss;
  __syncthreads();
  sum = 0.0f; ss = 0.0f;
#pragma unroll
  for (int gg = 0; gg < 8; ++gg) { sum += sS[gg][px]; ss += sQ[gg][px]; }
  const float mu = sum * (1.0f / DIN);
  float var = ss * (1.0f / DIN) - mu * mu;
  const float rstd = rsqrtf(fmaxf(var, 0.0f) + 1e-5f);
  // u = LN(y)*silu(z), written in place into sY
  const float* zb = xz + ((size_t)b * 384 + DIN) * LL + p0 + px;
  for (int dd = g * 24; dd < g * 24 + 24; ++dd) {
    float v = sY[px * 193 + dd];
    float z = zb[(size_t)dd * LL];
    float tn = fmaf((v - mu) * rstd, gamma[dd], beta[dd]);
    sY[px * 193 + dd] = tn * (z * sigf(z));
  }
  __syncthreads();
  // out_proj: wave g -> out channels [g*12, g*12+12)
  float acc[12];
#pragma unroll
  for (int j = 0; j < 12; ++j) acc[j] = 0.0f;
  const float* wbase = opwT + g * 12;
  for (int dd = 0; dd < DIN; ++dd) {
    float xv = sY[px * 193 + dd];
    const float4 wa = *(const float4*)(wbase + (size_t)dd * COUT);
    const float4 wb = *(const float4*)(wbase + (size_t)dd * COUT + 4);
    const float4 wc = *(const float4*)(wbase + (size_t)dd * COUT + 8);
    acc[0]  = fmaf(xv, wa.x, acc[0]);
    acc[1]  = fmaf(xv, wa.y, acc[1]);
    acc[2]  = fmaf(xv, wa.z, acc[2]);
    acc[3]  = fmaf(xv, wa.w, acc[3]);
    acc[4]  = fmaf(xv, wb.x, acc[4]);
    acc[5]  = fmaf(xv, wb.y, acc[5]);
    acc[6]  = fmaf(xv, wb.z, acc[6]);
    acc[7]  = fmaf(xv, wb.w, acc[7]);
    acc[8]  = fmaf(xv, wc.x, acc[8]);
    acc[9]  = fmaf(xv, wc.y, acc[9]);
    acc[10] = fmaf(xv, wc.z, acc[10]);
    acc[11] = fmaf(xv, wc.w, acc[11]);
  }
  float* ob = out + ((size_t)b * COUT + g * 12) * LL + p0 + px;
#pragma unroll
  for (int j = 0; j < 12; ++j) ob[(size_t)j * LL] = acc[j];
}

// ---------------------------------------------------------------------------
extern "C" void kernel_launch(void* const* d_in, const int* in_sizes, int n_in,
                              void* d_out, int out_size, void* d_ws, size_t ws_size,
                              hipStream_t stream) {
  const float* x      = (const float*)d_in[0];
  const float* prior  = (const float*)d_in[1];
  const float* alpha  = (const float*)d_in[2];
  const float* ipw    = (const float*)d_in[3];
  const float* cw     = (const float*)d_in[4];
  const float* cb     = (const float*)d_in[5];
  const float* xpw    = (const float*)d_in[6];
  const float* dtw    = (const float*)d_in[7];
  const float* dtb    = (const float*)d_in[8];
  const float* A_logs = (const float*)d_in[9];
  const float* Ds     = (const float*)d_in[10];
  const float* onw    = (const float*)d_in[11];
  const float* onb    = (const float*)d_in[12];
  const float* opw    = (const float*)d_in[13];
  const float* w1     = (const float*)d_in[14];
  const float* b1     = (const float*)d_in[15];
  const float* bnw    = (const float*)d_in[16];
  const float* bnb    = (const float*)d_in[17];
  const float* bnm    = (const float*)d_in[18];
  const float* bnv    = (const float*)d_in[19];
  const float* w2     = (const float*)d_in[20];
  const float* b2     = (const float*)d_in[21];
  float* out = (float*)d_out;

  char* ws = (char*)d_ws;
  // Footprint ends at 114,917,376 B (< 135,266,304 proven in R2).
  float* xz    = (float*)(ws);              // [B,384,L]     50.3 MB
  float* xcT   = (float*)(ws + 50331648);   // [B,L,192]     25.2 MB
  float* ymT2  = (float*)(ws + 75497472);   // [B,L,192]     25.2 MB
  float* projS = (float*)(ws + 100663296);  // [B,K,L,8]      4.2 MB (scan order)
  float* Wgb   = (float*)(ws + 104857600);  // [B,4,L]        0.5 MB
  float* carrP = (float*)(ws + 105381888);  // [B,K,SS,192]   3.0 MB
  float* carrH = (float*)(ws + 108527616);  // [B,K,SS,192]   3.0 MB
  float* h0b   = (float*)(ws + 111673344);  // [B,K,SS,192]   3.0 MB
  float* xpwT  = (float*)(ws + 114819072);  // [K,DIN,8]      24.6 KB
  float* opwT  = (float*)(ws + 114843648);  // [DIN,COUT]     73.7 KB (ends 114917376)
  float* ymT   = xz;   // overlay: x_ssm half of xz (dead after convproj)

  // 1) in_proj GEMM: [B,96,L] -> [B,384,L]
  gemm_pix_k<CIN><<<dim3(LL / 1024, 384 / 8, BB), 256, 0, stream>>>(x, ipw, xz, 384);
  // 2) prior -> direction gates (+ weight transposes in blocks 0,1)
  p2w_k<<<(BB * LL) / 256, 256, 0, stream>>>(prior, alpha, w1, b1, bnw, bnb, bnm,
                                             bnv, w2, b2, xpw, opw, xpwT, opwT, Wgb);
  // 3) fused dwconv+SiLU + x_proj(scan-order) + transpose (R9 64-px tiles)
  convproj_k<<<dim3(HH, BB), 256, 0, stream>>>(xz, cw, cb, xpwT, xcT, projS);
  // 4) scan: paired segment carries (both directions per xcT pass)
  scan_part_k<<<dim3(SS, 2, BB), 192, 0, stream>>>(xcT, projS, dtw, dtb, A_logs,
                                                   carrP, carrH);
  // 5) scan: serial carry combine
  scan_fix_k<<<dim3(KK, BB), 192, 0, stream>>>(carrP, carrH, h0b);
  // 6) scan: apply + gate + paired merge (ymT overlaid on xz x_ssm half)
  scan_apply_k<<<dim3(SS, 2, BB), 192, 0, stream>>>(xcT, projS, Wgb, h0b, dtw, dtb,
                                                    A_logs, Ds, ymT, ymT2);
  // 7) fused LayerNorm * silu(z) + out_proj GEMM
  ln_gemm_k<<<dim3(HH, BB), 512, 0, stream>>>(ymT, ymT2, xz, onw, onb, opwT, out);
}

// Round 12
// 251.430 us; speedup vs baseline: 1.1027x; 1.1027x over previous
//
#include <hip/hip_runtime.h>

#define BB   8
#define CIN  96
#define DIN  192
#define HH   64
#define WW   64
#define LL   4096
#define KK   4
#define COUT 96
#define SS   128  // scan segments
#define LC   32   // segment length = LL/SS

#define LOG2E 1.4426950408889634f
#define LN2   0.6931471805599453f

__device__ __forceinline__ float exp2fast(float x) { return __builtin_amdgcn_exp2f(x); }
__device__ __forceinline__ float log2fast(float x) { return __builtin_amdgcn_logf(x); }
__device__ __forceinline__ float sigf(float x) { return 1.0f / (1.0f + __expf(-x)); }
__device__ __forceinline__ int trp(int p) { return ((p & 63) << 6) | (p >> 6); }
__device__ __forceinline__ int pix_of(int k, int l) {
  if (k == 0) return l;
  if (k == 1) return trp(l);
  if (k == 2) return LL - 1 - l;
  return trp(LL - 1 - l);
}

// ---------------------------------------------------------------------------
// Per-pixel GEMM: out[b,o,p] = sum_c in[b,c,p] * W[o,c]
// ---------------------------------------------------------------------------
template <int C>
__global__ __launch_bounds__(256) void gemm_pix_k(const float* __restrict__ in,
                                                  const float* __restrict__ W,
                                                  float* __restrict__ out, int O) {
  __shared__ float sW[C * 8];
  const int tid = threadIdx.x;
  const int b  = blockIdx.z;
  const int o0 = blockIdx.y * 8;
  const int p0 = blockIdx.x * 1024;
  for (int idx = tid; idx < C * 8; idx += 256) {
    int c = idx >> 3, j = idx & 7;
    sW[idx] = W[(o0 + j) * C + c];
  }
  __syncthreads();
  float acc[4][8];
#pragma unroll
  for (int jp = 0; jp < 4; ++jp)
#pragma unroll
    for (int j = 0; j < 8; ++j) acc[jp][j] = 0.0f;
  const float* inb = in + (size_t)b * C * LL + p0 + tid;
#pragma unroll 2
  for (int c = 0; c < C; ++c) {
    float xv[4];
#pragma unroll
    for (int jp = 0; jp < 4; ++jp) xv[jp] = inb[(size_t)c * LL + jp * 256];
    const float4 w0 = *(const float4*)&sW[c * 8];
    const float4 w1 = *(const float4*)&sW[c * 8 + 4];
#pragma unroll
    for (int jp = 0; jp < 4; ++jp) {
      acc[jp][0] = fmaf(xv[jp], w0.x, acc[jp][0]);
      acc[jp][1] = fmaf(xv[jp], w0.y, acc[jp][1]);
      acc[jp][2] = fmaf(xv[jp], w0.z, acc[jp][2]);
      acc[jp][3] = fmaf(xv[jp], w0.w, acc[jp][3]);
      acc[jp][4] = fmaf(xv[jp], w1.x, acc[jp][4]);
      acc[jp][5] = fmaf(xv[jp], w1.y, acc[jp][5]);
      acc[jp][6] = fmaf(xv[jp], w1.z, acc[jp][6]);
      acc[jp][7] = fmaf(xv[jp], w1.w, acc[jp][7]);
    }
  }
  float* ob = out + (size_t)b * O * LL + p0 + tid;
#pragma unroll
  for (int j = 0; j < 8; ++j)
#pragma unroll
    for (int jp = 0; jp < 4; ++jp) ob[(size_t)(o0 + j) * LL + jp * 256] = acc[jp][j];
}

// ---------------------------------------------------------------------------
// PriorToWeights MLP -> Wg[B,4,L].  Block 0: transpose xpw -> xpwT[k][dd][8].
// ---------------------------------------------------------------------------
__global__ __launch_bounds__(256) void p2w_k(const float* __restrict__ prior,
                                             const float* __restrict__ alpha,
                                             const float* __restrict__ w1,
                                             const float* __restrict__ b1,
                                             const float* __restrict__ bnw,
                                             const float* __restrict__ bnb,
                                             const float* __restrict__ bnm,
                                             const float* __restrict__ bnv,
                                             const float* __restrict__ w2,
                                             const float* __restrict__ b2,
                                             const float* __restrict__ xpw,
                                             float* __restrict__ xpwT,
                                             float* __restrict__ Wg) {
  if (blockIdx.x == 0) {
    for (int idx = threadIdx.x; idx < KK * DIN * 8; idx += 256) {
      int kk = idx / (DIN * 8);
      int rem = idx % (DIN * 8);
      int dd = rem >> 3, c = rem & 7;
      xpwT[idx] = xpw[(kk * 8 + c) * DIN + dd];
    }
  }
  int idx = blockIdx.x * 256 + threadIdx.x;
  int p = idx & (LL - 1);
  int b = idx >> 12;
  float pr[4];
#pragma unroll
  for (int c = 0; c < 4; ++c) pr[c] = prior[((size_t)b * 4 + c) * LL + p];
  float s = sigf(alpha[0]);
  float g2[4];
#pragma unroll
  for (int j = 0; j < 4; ++j) g2[j] = b2[j];
  for (int o = 0; o < 32; ++o) {
    float g = b1[o];
#pragma unroll
    for (int c = 0; c < 4; ++c) g = fmaf(pr[c], w1[o * 4 + c], g);
    g = (g - bnm[o]) * rsqrtf(bnv[o] + 1e-5f) * bnw[o] + bnb[o];
    g = fmaxf(g, 0.0f);
#pragma unroll
    for (int j = 0; j < 4; ++j) g2[j] = fmaf(g, w2[j * 32 + o], g2[j]);
  }
#pragma unroll
  for (int j = 0; j < 4; ++j)
    Wg[((size_t)b * 4 + j) * LL + p] = 1.0f + s * (sigf(g2[j]) - 1.0f);
}

// ---------------------------------------------------------------------------
// FUSED conv+proj v4: 64-px row tiles (keeps halo L2 reuse), 512 threads for
// 16 waves/CU; proj split by hf -> 4 outputs/thread over dd=0..191.
// ---------------------------------------------------------------------------
__global__ __launch_bounds__(512) void convproj_k(const float* __restrict__ xz,
                                                  const float* __restrict__ cw,
                                                  const float* __restrict__ cb,
                                                  const float* __restrict__ xpwT,
                                                  float* __restrict__ xcT,
                                                  float* __restrict__ projS) {
  __shared__ float sX[96 * 65];  // 24.96 KB
  const int tid = threadIdx.x;
  const int b = blockIdx.y;
  const int h = blockIdx.x;
  const int px = tid & 63;
  const int ku = (tid >> 6) & 3;   // wave-uniform
  const int hf = tid >> 8;         // wave-uniform 0/1
  const float* wpk = xpwT + (size_t)ku * (DIN * 8) + hf * 4;
  float a0 = 0.0f, a1 = 0.0f, a2 = 0.0f, a3 = 0.0f;

#pragma unroll
  for (int half = 0; half < 2; ++half) {
    // conv + bias + SiLU for channels [half*96, half*96+96) into sX[ddl][px]
    for (int idx = tid; idx < 96 * 64; idx += 512) {
      int ddl = idx >> 6, pxx = idx & 63;
      int dd = half * 96 + ddl;
      const float* xp = xz + ((size_t)b * 384 + dd) * LL + h * 64 + pxx;
      const float* wp = cw + dd * 9;
      float s = cb[dd];
#pragma unroll
      for (int dh = -1; dh <= 1; ++dh) {
        int hh = h + dh;
        if (hh < 0 || hh >= HH) continue;
        const float* row = xp + dh * 64;
        float c0 = wp[(dh + 1) * 3], c1 = wp[(dh + 1) * 3 + 1], c2 = wp[(dh + 1) * 3 + 2];
        if (pxx > 0) s = fmaf(row[-1], c0, s);
        s = fmaf(row[0], c1, s);
        if (pxx < 63) s = fmaf(row[1], c2, s);
      }
      sX[ddl * 65 + pxx] = s * sigf(s);
    }
    __syncthreads();
    // transposed write xcT[b][p][half*96+ddl] (coalesced over ddl)
    for (int idx = tid; idx < 64 * 96; idx += 512) {
      int pp = idx / 96, ddl = idx % 96;
      xcT[((size_t)b * LL + h * 64 + pp) * DIN + half * 96 + ddl] = sX[ddl * 65 + pp];
    }
    // x_proj partial: 4 outputs (hf quad), channels of this half in order
    const float* wp = wpk + half * 96 * 8;
    for (int ddl = 0; ddl < 96; ++ddl) {
      float xv = sX[ddl * 65 + px];
      const float4 w4 = *(const float4*)(wp + ddl * 8);
      a0 = fmaf(xv, w4.x, a0);
      a1 = fmaf(xv, w4.y, a1);
      a2 = fmaf(xv, w4.z, a2);
      a3 = fmaf(xv, w4.w, a3);
    }
    __syncthreads();  // protect sX before next half overwrites
  }
  // write projS in scan order [b][k][l][8] (+hf*4)
  const int p = h * 64 + px;
  int l;
  if (ku == 0) l = p;
  else if (ku == 1) l = trp(p);
  else if (ku == 2) l = LL - 1 - p;
  else l = LL - 1 - trp(p);
  float* pb = projS + (((size_t)b * KK + ku) * LL + l) * 8 + hf * 4;
  *(float4*)pb = make_float4(a0, a1, a2, a3);
}

// ---------------------------------------------------------------------------
// Scan pass 1 (PAIRED): one xcT pass computes carries for BOTH opposite
// directions. Forward kA: H=aH+b, P*=a. Reverse kB: H += P*b, P *= a.
// ---------------------------------------------------------------------------
__global__ __launch_bounds__(192) void scan_part_k(const float* __restrict__ xcT,
                                                   const float* __restrict__ projS,
                                                   const float* __restrict__ dtw,
                                                   const float* __restrict__ dtb,
                                                   const float* __restrict__ A_logs,
                                                   float* __restrict__ carrP,
                                                   float* __restrict__ carrH) {
  const int s = blockIdx.x, kp = blockIdx.y, b = blockIdx.z;
  const int d = threadIdx.x;
  const int kA = kp, kB = kp + 2;
  const int s2 = SS - 1 - s;
  const int kdA = kA * DIN + d, kdB = kB * DIN + d;
  float wrA[6], wrB[6];
#pragma unroll
  for (int r = 0; r < 6; ++r) { wrA[r] = dtw[kdA * 6 + r]; wrB[r] = dtw[kdB * 6 + r]; }
  const float biasA = dtb[kdA], biasB = dtb[kdB];
  const float AaA = -__expf(A_logs[kdA]), AaB = -__expf(A_logs[kdB]);
  const int l0 = s * LC;
  const int p0 = pix_of(kA, l0);
  const int dp = pix_of(kA, l0 + 1) - p0;
  const float* xp = xcT + ((size_t)b * LL + p0) * DIN + d;
  const long xstep = (long)dp * DIN;
  const float* prA = projS + (((size_t)b * KK + kA) * LL + l0) * 8;
  const float* prB = projS + (((size_t)b * KK + kB) * LL + s2 * LC + (LC - 1)) * 8;
  float PA = 1.0f, HA = 0.0f, PB = 1.0f, HB = 0.0f;
#pragma unroll 2
  for (int j = 0; j < LC; ++j) {
    float4 a0 = *(const float4*)prA;
    float4 a1 = *(const float4*)(prA + 4);
    prA += 8;
    float4 b0 = *(const float4*)prB;
    float4 b1 = *(const float4*)(prB + 4);
    prB -= 8;
    float xv = *xp;
    xp += xstep;
    {
      float dtr = biasA;
      dtr = fmaf(a0.x, wrA[0], dtr);
      dtr = fmaf(a0.y, wrA[1], dtr);
      dtr = fmaf(a0.z, wrA[2], dtr);
      dtr = fmaf(a0.w, wrA[3], dtr);
      dtr = fmaf(a1.x, wrA[4], dtr);
      dtr = fmaf(a1.y, wrA[5], dtr);
      float e = exp2fast(fminf(dtr, 80.0f) * LOG2E);
      float u = log2fast(1.0f + e);
      float a = exp2fast(u * AaA);
      float dt = u * LN2;
      HA = fmaf(a, HA, dt * a1.z * xv);
      PA *= a;
    }
    {
      float dtr = biasB;
      dtr = fmaf(b0.x, wrB[0], dtr);
      dtr = fmaf(b0.y, wrB[1], dtr);
      dtr = fmaf(b0.z, wrB[2], dtr);
      dtr = fmaf(b0.w, wrB[3], dtr);
      dtr = fmaf(b1.x, wrB[4], dtr);
      dtr = fmaf(b1.y, wrB[5], dtr);
      float e = exp2fast(fminf(dtr, 80.0f) * LOG2E);
      float u = log2fast(1.0f + e);
      float a = exp2fast(u * AaB);
      float dt = u * LN2;
      HB = fmaf(PB, dt * b1.z * xv, HB);
      PB *= a;
    }
  }
  size_t oA = ((size_t)((b * KK + kA) * SS + s)) * DIN + d;
  size_t oB = ((size_t)((b * KK + kB) * SS + s2)) * DIN + d;
  carrP[oA] = PA;
  carrH[oA] = HA;
  carrP[oB] = PB;
  carrH[oB] = HB;
}

// ---------------------------------------------------------------------------
// Scan pass 2: serial combine of SS carries -> per-segment initial state h0
// ---------------------------------------------------------------------------
__global__ __launch_bounds__(192) void scan_fix_k(const float* __restrict__ carrP,
                                                  const float* __restrict__ carrH,
                                                  float* __restrict__ h0) {
  const int k = blockIdx.x, b = blockIdx.y, d = threadIdx.x;
  size_t base = ((size_t)(b * KK + k)) * SS * DIN + d;
  float h = 0.0f;
#pragma unroll 4
  for (int s = 0; s < SS; ++s) {
    h0[base + (size_t)s * DIN] = h;
    h = fmaf(carrP[base + (size_t)s * DIN], h, carrH[base + (size_t)s * DIN]);
  }
}

// ---------------------------------------------------------------------------
// Scan pass 3: apply + gate + paired-direction merge via 24 KB LDS.
// ---------------------------------------------------------------------------
__global__ __launch_bounds__(192) void scan_apply_k(const float* __restrict__ xcT,
                                                    const float* __restrict__ projS,
                                                    const float* __restrict__ Wg,
                                                    const float* __restrict__ h0,
                                                    const float* __restrict__ dtw,
                                                    const float* __restrict__ dtb,
                                                    const float* __restrict__ A_logs,
                                                    const float* __restrict__ Ds,
                                                    float* __restrict__ ymT,
                                                    float* __restrict__ ymT2) {
  const int s = blockIdx.x, kp = blockIdx.y, b = blockIdx.z;
  const int d = threadIdx.x;
  __shared__ float sAcc[LC * DIN];  // 24 KB, column d thread-private
  {
    const int k = kp, kd = k * DIN + d;
    float wr[6];
#pragma unroll
    for (int r = 0; r < 6; ++r) wr[r] = dtw[kd * 6 + r];
    const float bias = dtb[kd];
    const float Aa = -__expf(A_logs[kd]);
    const float Dv = Ds[kd];
    const int l0 = s * LC;
    const int p0 = pix_of(k, l0);
    const int dp = pix_of(k, l0 + 1) - p0;
    const float* xp = xcT + ((size_t)b * LL + p0) * DIN + d;
    const long xstep = (long)dp * DIN;
    const float* pr = projS + (((size_t)b * KK + k) * LL + l0) * 8;
    const float* wg = Wg + ((size_t)b * KK + k) * LL + l0;
    float h = h0[((size_t)((b * KK + k) * SS + s)) * DIN + d];
#pragma unroll 4
    for (int j = 0; j < LC; ++j) {
      float4 q0 = *(const float4*)pr;
      float4 q1 = *(const float4*)(pr + 4);
      pr += 8;
      float xv = *xp;
      xp += xstep;
      float dtr = bias;
      dtr = fmaf(q0.x, wr[0], dtr);
      dtr = fmaf(q0.y, wr[1], dtr);
      dtr = fmaf(q0.z, wr[2], dtr);
      dtr = fmaf(q0.w, wr[3], dtr);
      dtr = fmaf(q1.x, wr[4], dtr);
      dtr = fmaf(q1.y, wr[5], dtr);
      float e = exp2fast(fminf(dtr, 80.0f) * LOG2E);
      float u = log2fast(1.0f + e);
      float a = exp2fast(u * Aa);
      float dt = u * LN2;
      h = fmaf(a, h, dt * q1.z * xv);
      sAcc[j * DIN + d] = fmaf(h, q1.w, Dv * xv) * wg[j];
    }
  }
  {
    const int k = kp + 2, kd = k * DIN + d;
    const int s2 = SS - 1 - s;
    float wr[6];
#pragma unroll
    for (int r = 0; r < 6; ++r) wr[r] = dtw[kd * 6 + r];
    const float bias = dtb[kd];
    const float Aa = -__expf(A_logs[kd]);
    const float Dv = Ds[kd];
    const int l0 = s2 * LC;
    const int p0 = pix_of(k, l0);
    const int dp = pix_of(k, l0 + 1) - p0;
    const float* xp = xcT + ((size_t)b * LL + p0) * DIN + d;
    const long xstep = (long)dp * DIN;
    const float* pr = projS + (((size_t)b * KK + k) * LL + l0) * 8;
    const float* wg = Wg + ((size_t)b * KK + k) * LL + l0;
    float h = h0[((size_t)((b * KK + k) * SS + s2)) * DIN + d];
#pragma unroll 4
    for (int j = 0; j < LC; ++j) {
      float4 q0 = *(const float4*)pr;
      float4 q1 = *(const float4*)(pr + 4);
      pr += 8;
      float xv = *xp;
      xp += xstep;
      float dtr = bias;
      dtr = fmaf(q0.x, wr[0], dtr);
      dtr = fmaf(q0.y, wr[1], dtr);
      dtr = fmaf(q0.z, wr[2], dtr);
      dtr = fmaf(q0.w, wr[3], dtr);
      dtr = fmaf(q1.x, wr[4], dtr);
      dtr = fmaf(q1.y, wr[5], dtr);
      float e = exp2fast(fminf(dtr, 80.0f) * LOG2E);
      float u = log2fast(1.0f + e);
      float a = exp2fast(u * Aa);
      float dt = u * LN2;
      h = fmaf(a, h, dt * q1.z * xv);
      float y = fmaf(h, q1.w, Dv * xv) * wg[j];
      sAcc[(LC - 1 - j) * DIN + d] += y;
    }
  }
  float* dst;
  if (kp == 0)
    dst = ymT + (size_t)b * (384 * (size_t)LL) + (size_t)(s * LC) * DIN + d;  // xz overlay
  else
    dst = ymT2 + ((size_t)b * LL + s * LC) * DIN + d;
#pragma unroll 4
  for (int j = 0; j < LC; ++j) dst[(size_t)j * DIN] = sAcc[j * DIN + d];
}

// ---------------------------------------------------------------------------
// LayerNorm(channel) * silu(z): reads ymT(overlay)[p,:] + ymT2[tr(p),:], writes u
// ---------------------------------------------------------------------------
__global__ __launch_bounds__(256) void ln_silu_k(const float* __restrict__ ymT,
                                                 const float* __restrict__ ymT2,
                                                 const float* __restrict__ xz,
                                                 const float* __restrict__ gamma,
                                                 const float* __restrict__ beta,
                                                 float* __restrict__ u) {
  const int b = blockIdx.y;
  const int h = blockIdx.x;
  const int p0 = h * 64;
  __shared__ float sY[64 * 193];
  __shared__ float sS[4][64], sQ[4][64];
  const int tid = threadIdx.x;
  const float* ymb = ymT + (size_t)b * (384 * (size_t)LL);  // xz overlay
  for (int idx = tid; idx < 64 * DIN; idx += 256) {
    int pp = idx / DIN, dd = idx % DIN;
    float v = ymb[(size_t)(p0 + pp) * DIN + dd] +
              ymT2[((size_t)b * LL + pp * 64 + h) * DIN + dd];
    sY[pp * 193 + dd] = v;
  }
  __syncthreads();
  const int px = tid & 63, g = tid >> 6;
  float sum = 0.0f, ss = 0.0f;
  for (int dd = g * 48; dd < g * 48 + 48; ++dd) {
    float v = sY[px * 193 + dd];
    sum += v;
    ss = fmaf(v, v, ss);
  }
  sS[g][px] = sum;
  sQ[g][px] = ss;
  __syncthreads();
  sum = sS[0][px] + sS[1][px] + sS[2][px] + sS[3][px];
  ss  = sQ[0][px] + sQ[1][px] + sQ[2][px] + sQ[3][px];
  const float mu = sum * (1.0f / DIN);
  float var = ss * (1.0f / DIN) - mu * mu;
  const float rstd = rsqrtf(fmaxf(var, 0.0f) + 1e-5f);
  const float* zb = xz + ((size_t)b * 384 + DIN) * LL + p0 + px;
  float* ub = u + (size_t)b * DIN * LL + p0 + px;
  for (int dd = g * 48; dd < g * 48 + 48; ++dd) {
    float v = sY[px * 193 + dd];
    float z = zb[(size_t)dd * LL];
    float tn = fmaf((v - mu) * rstd, gamma[dd], beta[dd]);
    ub[(size_t)dd * LL] = tn * (z * sigf(z));
  }
}

// ---------------------------------------------------------------------------
extern "C" void kernel_launch(void* const* d_in, const int* in_sizes, int n_in,
                              void* d_out, int out_size, void* d_ws, size_t ws_size,
                              hipStream_t stream) {
  const float* x      = (const float*)d_in[0];
  const float* prior  = (const float*)d_in[1];
  const float* alpha  = (const float*)d_in[2];
  const float* ipw    = (const float*)d_in[3];
  const float* cw     = (const float*)d_in[4];
  const float* cb     = (const float*)d_in[5];
  const float* xpw    = (const float*)d_in[6];
  const float* dtw    = (const float*)d_in[7];
  const float* dtb    = (const float*)d_in[8];
  const float* A_logs = (const float*)d_in[9];
  const float* Ds     = (const float*)d_in[10];
  const float* onw    = (const float*)d_in[11];
  const float* onb    = (const float*)d_in[12];
  const float* opw    = (const float*)d_in[13];
  const float* w1     = (const float*)d_in[14];
  const float* b1     = (const float*)d_in[15];
  const float* bnw    = (const float*)d_in[16];
  const float* bnb    = (const float*)d_in[17];
  const float* bnm    = (const float*)d_in[18];
  const float* bnv    = (const float*)d_in[19];
  const float* w2     = (const float*)d_in[20];
  const float* b2     = (const float*)d_in[21];
  float* out = (float*)d_out;

  char* ws = (char*)d_ws;
  // Footprint ends at 114,843,648 B (< 135,266,304 proven in R2).
  float* xz    = (float*)(ws);              // [B,384,L]     50.3 MB
  float* xcT   = (float*)(ws + 50331648);   // [B,L,192]     25.2 MB (-> u after apply)
  float* ymT2  = (float*)(ws + 75497472);   // [B,L,192]     25.2 MB
  float* projS = (float*)(ws + 100663296);  // [B,K,L,8]      4.2 MB (scan order)
  float* Wgb   = (float*)(ws + 104857600);  // [B,4,L]        0.5 MB
  float* carrP = (float*)(ws + 105381888);  // [B,K,SS,192]   3.0 MB
  float* carrH = (float*)(ws + 108527616);  // [B,K,SS,192]   3.0 MB
  float* h0b   = (float*)(ws + 111673344);  // [B,K,SS,192]   3.0 MB
  float* xpwT  = (float*)(ws + 114819072);  // [K,DIN,8]      24.6 KB (ends 114843648)
  float* ymT   = xz;   // overlay: x_ssm half of xz (dead after convproj)
  float* u     = xcT;  // xcT dead after scan_apply_k

  // 1) in_proj GEMM: [B,96,L] -> [B,384,L]
  gemm_pix_k<CIN><<<dim3(LL / 1024, 384 / 8, BB), 256, 0, stream>>>(x, ipw, xz, 384);
  // 2) prior -> direction gates  (+ weight transpose in block 0)
  p2w_k<<<(BB * LL) / 256, 256, 0, stream>>>(prior, alpha, w1, b1, bnw, bnb, bnm,
                                             bnv, w2, b2, xpw, xpwT, Wgb);
  // 3) fused dwconv+SiLU + x_proj(scan-order) + transpose (64-px, 512 thr)
  convproj_k<<<dim3(HH, BB), 512, 0, stream>>>(xz, cw, cb, xpwT, xcT, projS);
  // 4) scan: paired segment carries (both directions per xcT pass)
  scan_part_k<<<dim3(SS, 2, BB), 192, 0, stream>>>(xcT, projS, dtw, dtb, A_logs,
                                                   carrP, carrH);
  // 5) scan: serial carry combine
  scan_fix_k<<<dim3(KK, BB), 192, 0, stream>>>(carrP, carrH, h0b);
  // 6) scan: apply + gate + paired merge (ymT overlaid on xz x_ssm half)
  scan_apply_k<<<dim3(SS, 2, BB), 192, 0, stream>>>(xcT, projS, Wgb, h0b, dtw, dtb,
                                                    A_logs, Ds, ymT, ymT2);
  // 7) LayerNorm(channel) * silu(z)
  ln_silu_k<<<dim3(HH, BB), 256, 0, stream>>>(ymT, ymT2, xz, onw, onb, u);
  // 8) out_proj GEMM
  gemm_pix_k<DIN><<<dim3(LL / 1024, COUT / 8, BB), 256, 0, stream>>>(u, opw, out, COUT);
}

// Round 13
// 221.745 us; speedup vs baseline: 1.2503x; 1.1339x over previous
//
#include <hip/hip_runtime.h>

#define BB   8
#define CIN  96
#define DIN  192
#define HH   64
#define WW   64
#define LL   4096
#define KK   4
#define COUT 96
#define SS   128  // scan segments
#define LC   32   // segment length = LL/SS

#define LOG2E 1.4426950408889634f
#define LN2   0.6931471805599453f

__device__ __forceinline__ float exp2fast(float x) { return __builtin_amdgcn_exp2f(x); }
__device__ __forceinline__ float log2fast(float x) { return __builtin_amdgcn_logf(x); }
__device__ __forceinline__ float sigf(float x) { return 1.0f / (1.0f + __expf(-x)); }
__device__ __forceinline__ int trp(int p) { return ((p & 63) << 6) | (p >> 6); }
__device__ __forceinline__ int pix_of(int k, int l) {
  if (k == 0) return l;
  if (k == 1) return trp(l);
  if (k == 2) return LL - 1 - l;
  return trp(LL - 1 - l);
}

// ---------------------------------------------------------------------------
// Per-pixel GEMM: out[b,o,p] = sum_c in[b,c,p] * W[o,c]
// ---------------------------------------------------------------------------
template <int C>
__global__ __launch_bounds__(256) void gemm_pix_k(const float* __restrict__ in,
                                                  const float* __restrict__ W,
                                                  float* __restrict__ out, int O) {
  __shared__ float sW[C * 8];
  const int tid = threadIdx.x;
  const int b  = blockIdx.z;
  const int o0 = blockIdx.y * 8;
  const int p0 = blockIdx.x * 1024;
  for (int idx = tid; idx < C * 8; idx += 256) {
    int c = idx >> 3, j = idx & 7;
    sW[idx] = W[(o0 + j) * C + c];
  }
  __syncthreads();
  float acc[4][8];
#pragma unroll
  for (int jp = 0; jp < 4; ++jp)
#pragma unroll
    for (int j = 0; j < 8; ++j) acc[jp][j] = 0.0f;
  const float* inb = in + (size_t)b * C * LL + p0 + tid;
#pragma unroll 2
  for (int c = 0; c < C; ++c) {
    float xv[4];
#pragma unroll
    for (int jp = 0; jp < 4; ++jp) xv[jp] = inb[(size_t)c * LL + jp * 256];
    const float4 w0 = *(const float4*)&sW[c * 8];
    const float4 w1 = *(const float4*)&sW[c * 8 + 4];
#pragma unroll
    for (int jp = 0; jp < 4; ++jp) {
      acc[jp][0] = fmaf(xv[jp], w0.x, acc[jp][0]);
      acc[jp][1] = fmaf(xv[jp], w0.y, acc[jp][1]);
      acc[jp][2] = fmaf(xv[jp], w0.z, acc[jp][2]);
      acc[jp][3] = fmaf(xv[jp], w0.w, acc[jp][3]);
      acc[jp][4] = fmaf(xv[jp], w1.x, acc[jp][4]);
      acc[jp][5] = fmaf(xv[jp], w1.y, acc[jp][5]);
      acc[jp][6] = fmaf(xv[jp], w1.z, acc[jp][6]);
      acc[jp][7] = fmaf(xv[jp], w1.w, acc[jp][7]);
    }
  }
  float* ob = out + (size_t)b * O * LL + p0 + tid;
#pragma unroll
  for (int j = 0; j < 8; ++j)
#pragma unroll
    for (int jp = 0; jp < 4; ++jp) ob[(size_t)(o0 + j) * LL + jp * 256] = acc[jp][j];
}

// ---------------------------------------------------------------------------
// PriorToWeights MLP -> Wg[B,4,L].  Block 0: transpose xpw -> xpwT[k][dd][8].
// ---------------------------------------------------------------------------
__global__ __launch_bounds__(256) void p2w_k(const float* __restrict__ prior,
                                             const float* __restrict__ alpha,
                                             const float* __restrict__ w1,
                                             const float* __restrict__ b1,
                                             const float* __restrict__ bnw,
                                             const float* __restrict__ bnb,
                                             const float* __restrict__ bnm,
                                             const float* __restrict__ bnv,
                                             const float* __restrict__ w2,
                                             const float* __restrict__ b2,
                                             const float* __restrict__ xpw,
                                             float* __restrict__ xpwT,
                                             float* __restrict__ Wg) {
  if (blockIdx.x == 0) {
    for (int idx = threadIdx.x; idx < KK * DIN * 8; idx += 256) {
      int kk = idx / (DIN * 8);
      int rem = idx % (DIN * 8);
      int dd = rem >> 3, c = rem & 7;
      xpwT[idx] = xpw[(kk * 8 + c) * DIN + dd];
    }
  }
  int idx = blockIdx.x * 256 + threadIdx.x;
  int p = idx & (LL - 1);
  int b = idx >> 12;
  float pr[4];
#pragma unroll
  for (int c = 0; c < 4; ++c) pr[c] = prior[((size_t)b * 4 + c) * LL + p];
  float s = sigf(alpha[0]);
  float g2[4];
#pragma unroll
  for (int j = 0; j < 4; ++j) g2[j] = b2[j];
  for (int o = 0; o < 32; ++o) {
    float g = b1[o];
#pragma unroll
    for (int c = 0; c < 4; ++c) g = fmaf(pr[c], w1[o * 4 + c], g);
    g = (g - bnm[o]) * rsqrtf(bnv[o] + 1e-5f) * bnw[o] + bnb[o];
    g = fmaxf(g, 0.0f);
#pragma unroll
    for (int j = 0; j < 4; ++j) g2[j] = fmaf(g, w2[j * 32 + o], g2[j]);
  }
#pragma unroll
  for (int j = 0; j < 4; ++j)
    Wg[((size_t)b * 4 + j) * LL + p] = 1.0f + s * (sigf(g2[j]) - 1.0f);
}

// ---------------------------------------------------------------------------
// FUSED conv+proj v5: 64-px row tiles, 1024 threads (32 waves/CU).
// Thread = (px, k, hf, q); q splits each 96-ch half into 48+48 -> 96-step
// chain; q-partials combined via 8 KB LDS. Weights via scalar (readfirstlane)
// loads from xpwT.
// ---------------------------------------------------------------------------
__global__ __launch_bounds__(1024) void convproj_k(const float* __restrict__ xz,
                                                   const float* __restrict__ cw,
                                                   const float* __restrict__ cb,
                                                   const float* __restrict__ xpwT,
                                                   float* __restrict__ xcT,
                                                   float* __restrict__ projS) {
  __shared__ float sX[96 * 65];   // 24.96 KB
  __shared__ float4 sP[512];      // 8 KB q-partials
  const int tid = threadIdx.x;
  const int b = blockIdx.y;
  const int h = blockIdx.x;
  const int px = tid & 63;
  const int ku = __builtin_amdgcn_readfirstlane((tid >> 6) & 3);
  const int hf = __builtin_amdgcn_readfirstlane((tid >> 8) & 1);
  const int q  = __builtin_amdgcn_readfirstlane(tid >> 9);
  float a0 = 0.0f, a1 = 0.0f, a2 = 0.0f, a3 = 0.0f;

#pragma unroll
  for (int half = 0; half < 2; ++half) {
    // conv + bias + SiLU for channels [half*96, half*96+96) into sX[ddl][px]
    for (int idx = tid; idx < 96 * 64; idx += 1024) {
      int ddl = idx >> 6, pxx = idx & 63;
      int dd = half * 96 + ddl;
      const float* xp = xz + ((size_t)b * 384 + dd) * LL + h * 64 + pxx;
      const float* wp = cw + dd * 9;
      float s = cb[dd];
#pragma unroll
      for (int dh = -1; dh <= 1; ++dh) {
        int hh = h + dh;
        if (hh < 0 || hh >= HH) continue;
        const float* row = xp + dh * 64;
        float c0 = wp[(dh + 1) * 3], c1 = wp[(dh + 1) * 3 + 1], c2 = wp[(dh + 1) * 3 + 2];
        if (pxx > 0) s = fmaf(row[-1], c0, s);
        s = fmaf(row[0], c1, s);
        if (pxx < 63) s = fmaf(row[1], c2, s);
      }
      sX[ddl * 65 + pxx] = s * sigf(s);
    }
    __syncthreads();
    // transposed write xcT[b][p][half*96+ddl] (coalesced over ddl)
    for (int idx = tid; idx < 64 * 96; idx += 1024) {
      int pp = idx / 96, ddl = idx % 96;
      xcT[((size_t)b * LL + h * 64 + pp) * DIN + half * 96 + ddl] = sX[ddl * 65 + pp];
    }
    // x_proj partial: this thread's q-range of 48 channels, 4 outputs (hf quad)
    {
      const int ddl0 = q * 48;
      const float* wp = xpwT + (size_t)ku * (DIN * 8) + (half * 96 + ddl0) * 8 + hf * 4;
#pragma unroll 8
      for (int d48 = 0; d48 < 48; ++d48) {
        float xv = sX[(ddl0 + d48) * 65 + px];
        const float4 w4 = *(const float4*)(wp + d48 * 8);
        a0 = fmaf(xv, w4.x, a0);
        a1 = fmaf(xv, w4.y, a1);
        a2 = fmaf(xv, w4.z, a2);
        a3 = fmaf(xv, w4.w, a3);
      }
    }
    __syncthreads();  // protect sX before next half overwrites
  }
  // combine q-partials: q=1 publishes, q=0 adds and writes out
  const int slot = tid & 511;
  if (q == 1) sP[slot] = make_float4(a0, a1, a2, a3);
  __syncthreads();
  if (q == 0) {
    float4 o = sP[slot];
    a0 += o.x; a1 += o.y; a2 += o.z; a3 += o.w;
    const int p = h * 64 + px;
    int l;
    if (ku == 0) l = p;
    else if (ku == 1) l = trp(p);
    else if (ku == 2) l = LL - 1 - p;
    else l = LL - 1 - trp(p);
    float* pb = projS + (((size_t)b * KK + ku) * LL + l) * 8 + hf * 4;
    *(float4*)pb = make_float4(a0, a1, a2, a3);
  }
}

// ---------------------------------------------------------------------------
// Scan pass 1 (PAIRED): one xcT pass computes carries for BOTH opposite
// directions. Forward kA: H=aH+b, P*=a. Reverse kB: H += P*b, P *= a.
// ---------------------------------------------------------------------------
__global__ __launch_bounds__(192) void scan_part_k(const float* __restrict__ xcT,
                                                   const float* __restrict__ projS,
                                                   const float* __restrict__ dtw,
                                                   const float* __restrict__ dtb,
                                                   const float* __restrict__ A_logs,
                                                   float* __restrict__ carrP,
                                                   float* __restrict__ carrH) {
  const int s = blockIdx.x, kp = blockIdx.y, b = blockIdx.z;
  const int d = threadIdx.x;
  const int kA = kp, kB = kp + 2;
  const int s2 = SS - 1 - s;
  const int kdA = kA * DIN + d, kdB = kB * DIN + d;
  float wrA[6], wrB[6];
#pragma unroll
  for (int r = 0; r < 6; ++r) { wrA[r] = dtw[kdA * 6 + r]; wrB[r] = dtw[kdB * 6 + r]; }
  const float biasA = dtb[kdA], biasB = dtb[kdB];
  const float AaA = -__expf(A_logs[kdA]), AaB = -__expf(A_logs[kdB]);
  const int l0 = s * LC;
  const int p0 = pix_of(kA, l0);
  const int dp = pix_of(kA, l0 + 1) - p0;
  const float* xp = xcT + ((size_t)b * LL + p0) * DIN + d;
  const long xstep = (long)dp * DIN;
  const float* prA = projS + (((size_t)b * KK + kA) * LL + l0) * 8;
  const float* prB = projS + (((size_t)b * KK + kB) * LL + s2 * LC + (LC - 1)) * 8;
  float PA = 1.0f, HA = 0.0f, PB = 1.0f, HB = 0.0f;
#pragma unroll 2
  for (int j = 0; j < LC; ++j) {
    float4 a0 = *(const float4*)prA;
    float4 a1 = *(const float4*)(prA + 4);
    prA += 8;
    float4 b0 = *(const float4*)prB;
    float4 b1 = *(const float4*)(prB + 4);
    prB -= 8;
    float xv = *xp;
    xp += xstep;
    {
      float dtr = biasA;
      dtr = fmaf(a0.x, wrA[0], dtr);
      dtr = fmaf(a0.y, wrA[1], dtr);
      dtr = fmaf(a0.z, wrA[2], dtr);
      dtr = fmaf(a0.w, wrA[3], dtr);
      dtr = fmaf(a1.x, wrA[4], dtr);
      dtr = fmaf(a1.y, wrA[5], dtr);
      float e = exp2fast(fminf(dtr, 80.0f) * LOG2E);
      float u = log2fast(1.0f + e);
      float a = exp2fast(u * AaA);
      float dt = u * LN2;
      HA = fmaf(a, HA, dt * a1.z * xv);
      PA *= a;
    }
    {
      float dtr = biasB;
      dtr = fmaf(b0.x, wrB[0], dtr);
      dtr = fmaf(b0.y, wrB[1], dtr);
      dtr = fmaf(b0.z, wrB[2], dtr);
      dtr = fmaf(b0.w, wrB[3], dtr);
      dtr = fmaf(b1.x, wrB[4], dtr);
      dtr = fmaf(b1.y, wrB[5], dtr);
      float e = exp2fast(fminf(dtr, 80.0f) * LOG2E);
      float u = log2fast(1.0f + e);
      float a = exp2fast(u * AaB);
      float dt = u * LN2;
      HB = fmaf(PB, dt * b1.z * xv, HB);
      PB *= a;
    }
  }
  size_t oA = ((size_t)((b * KK + kA) * SS + s)) * DIN + d;
  size_t oB = ((size_t)((b * KK + kB) * SS + s2)) * DIN + d;
  carrP[oA] = PA;
  carrH[oA] = HA;
  carrP[oB] = PB;
  carrH[oB] = HB;
}

// ---------------------------------------------------------------------------
// Scan pass 2: serial combine of SS carries -> per-segment initial state h0
// ---------------------------------------------------------------------------
__global__ __launch_bounds__(192) void scan_fix_k(const float* __restrict__ carrP,
                                                  const float* __restrict__ carrH,
                                                  float* __restrict__ h0) {
  const int k = blockIdx.x, b = blockIdx.y, d = threadIdx.x;
  size_t base = ((size_t)(b * KK + k)) * SS * DIN + d;
  float h = 0.0f;
#pragma unroll 4
  for (int s = 0; s < SS; ++s) {
    h0[base + (size_t)s * DIN] = h;
    h = fmaf(carrP[base + (size_t)s * DIN], h, carrH[base + (size_t)s * DIN]);
  }
}

// ---------------------------------------------------------------------------
// Scan pass 3: apply + gate + paired-direction merge via 24 KB LDS.
// ---------------------------------------------------------------------------
__global__ __launch_bounds__(192) void scan_apply_k(const float* __restrict__ xcT,
                                                    const float* __restrict__ projS,
                                                    const float* __restrict__ Wg,
                                                    const float* __restrict__ h0,
                                                    const float* __restrict__ dtw,
                                                    const float* __restrict__ dtb,
                                                    const float* __restrict__ A_logs,
                                                    const float* __restrict__ Ds,
                                                    float* __restrict__ ymT,
                                                    float* __restrict__ ymT2) {
  const int s = blockIdx.x, kp = blockIdx.y, b = blockIdx.z;
  const int d = threadIdx.x;
  __shared__ float sAcc[LC * DIN];  // 24 KB, column d thread-private
  {
    const int k = kp, kd = k * DIN + d;
    float wr[6];
#pragma unroll
    for (int r = 0; r < 6; ++r) wr[r] = dtw[kd * 6 + r];
    const float bias = dtb[kd];
    const float Aa = -__expf(A_logs[kd]);
    const float Dv = Ds[kd];
    const int l0 = s * LC;
    const int p0 = pix_of(k, l0);
    const int dp = pix_of(k, l0 + 1) - p0;
    const float* xp = xcT + ((size_t)b * LL + p0) * DIN + d;
    const long xstep = (long)dp * DIN;
    const float* pr = projS + (((size_t)b * KK + k) * LL + l0) * 8;
    const float* wg = Wg + ((size_t)b * KK + k) * LL + l0;
    float h = h0[((size_t)((b * KK + k) * SS + s)) * DIN + d];
#pragma unroll 4
    for (int j = 0; j < LC; ++j) {
      float4 q0 = *(const float4*)pr;
      float4 q1 = *(const float4*)(pr + 4);
      pr += 8;
      float xv = *xp;
      xp += xstep;
      float dtr = bias;
      dtr = fmaf(q0.x, wr[0], dtr);
      dtr = fmaf(q0.y, wr[1], dtr);
      dtr = fmaf(q0.z, wr[2], dtr);
      dtr = fmaf(q0.w, wr[3], dtr);
      dtr = fmaf(q1.x, wr[4], dtr);
      dtr = fmaf(q1.y, wr[5], dtr);
      float e = exp2fast(fminf(dtr, 80.0f) * LOG2E);
      float u = log2fast(1.0f + e);
      float a = exp2fast(u * Aa);
      float dt = u * LN2;
      h = fmaf(a, h, dt * q1.z * xv);
      sAcc[j * DIN + d] = fmaf(h, q1.w, Dv * xv) * wg[j];
    }
  }
  {
    const int k = kp + 2, kd = k * DIN + d;
    const int s2 = SS - 1 - s;
    float wr[6];
#pragma unroll
    for (int r = 0; r < 6; ++r) wr[r] = dtw[kd * 6 + r];
    const float bias = dtb[kd];
    const float Aa = -__expf(A_logs[kd]);
    const float Dv = Ds[kd];
    const int l0 = s2 * LC;
    const int p0 = pix_of(k, l0);
    const int dp = pix_of(k, l0 + 1) - p0;
    const float* xp = xcT + ((size_t)b * LL + p0) * DIN + d;
    const long xstep = (long)dp * DIN;
    const float* pr = projS + (((size_t)b * KK + k) * LL + l0) * 8;
    const float* wg = Wg + ((size_t)b * KK + k) * LL + l0;
    float h = h0[((size_t)((b * KK + k) * SS + s2)) * DIN + d];
#pragma unroll 4
    for (int j = 0; j < LC; ++j) {
      float4 q0 = *(const float4*)pr;
      float4 q1 = *(const float4*)(pr + 4);
      pr += 8;
      float xv = *xp;
      xp += xstep;
      float dtr = bias;
      dtr = fmaf(q0.x, wr[0], dtr);
      dtr = fmaf(q0.y, wr[1], dtr);
      dtr = fmaf(q0.z, wr[2], dtr);
      dtr = fmaf(q0.w, wr[3], dtr);
      dtr = fmaf(q1.x, wr[4], dtr);
      dtr = fmaf(q1.y, wr[5], dtr);
      float e = exp2fast(fminf(dtr, 80.0f) * LOG2E);
      float u = log2fast(1.0f + e);
      float a = exp2fast(u * Aa);
      float dt = u * LN2;
      h = fmaf(a, h, dt * q1.z * xv);
      float y = fmaf(h, q1.w, Dv * xv) * wg[j];
      sAcc[(LC - 1 - j) * DIN + d] += y;
    }
  }
  float* dst;
  if (kp == 0)
    dst = ymT + (size_t)b * (384 * (size_t)LL) + (size_t)(s * LC) * DIN + d;  // xz overlay
  else
    dst = ymT2 + ((size_t)b * LL + s * LC) * DIN + d;
#pragma unroll 4
  for (int j = 0; j < LC; ++j) dst[(size_t)j * DIN] = sAcc[j * DIN + d];
}

// ---------------------------------------------------------------------------
// LayerNorm(channel) * silu(z): reads ymT(overlay)[p,:] + ymT2[tr(p),:], writes u
// ---------------------------------------------------------------------------
__global__ __launch_bounds__(256) void ln_silu_k(const float* __restrict__ ymT,
                                                 const float* __restrict__ ymT2,
                                                 const float* __restrict__ xz,
                                                 const float* __restrict__ gamma,
                                                 const float* __restrict__ beta,
                                                 float* __restrict__ u) {
  const int b = blockIdx.y;
  const int h = blockIdx.x;
  const int p0 = h * 64;
  __shared__ float sY[64 * 193];
  __shared__ float sS[4][64], sQ[4][64];
  const int tid = threadIdx.x;
  const float* ymb = ymT + (size_t)b * (384 * (size_t)LL);  // xz overlay
  for (int idx = tid; idx < 64 * DIN; idx += 256) {
    int pp = idx / DIN, dd = idx % DIN;
    float v = ymb[(size_t)(p0 + pp) * DIN + dd] +
              ymT2[((size_t)b * LL + pp * 64 + h) * DIN + dd];
    sY[pp * 193 + dd] = v;
  }
  __syncthreads();
  const int px = tid & 63, g = tid >> 6;
  float sum = 0.0f, ss = 0.0f;
  for (int dd = g * 48; dd < g * 48 + 48; ++dd) {
    float v = sY[px * 193 + dd];
    sum += v;
    ss = fmaf(v, v, ss);
  }
  sS[g][px] = sum;
  sQ[g][px] = ss;
  __syncthreads();
  sum = sS[0][px] + sS[1][px] + sS[2][px] + sS[3][px];
  ss  = sQ[0][px] + sQ[1][px] + sQ[2][px] + sQ[3][px];
  const float mu = sum * (1.0f / DIN);
  float var = ss * (1.0f / DIN) - mu * mu;
  const float rstd = rsqrtf(fmaxf(var, 0.0f) + 1e-5f);
  const float* zb = xz + ((size_t)b * 384 + DIN) * LL + p0 + px;
  float* ub = u + (size_t)b * DIN * LL + p0 + px;
  for (int dd = g * 48; dd < g * 48 + 48; ++dd) {
    float v = sY[px * 193 + dd];
    float z = zb[(size_t)dd * LL];
    float tn = fmaf((v - mu) * rstd, gamma[dd], beta[dd]);
    ub[(size_t)dd * LL] = tn * (z * sigf(z));
  }
}

// ---------------------------------------------------------------------------
extern "C" void kernel_launch(void* const* d_in, const int* in_sizes, int n_in,
                              void* d_out, int out_size, void* d_ws, size_t ws_size,
                              hipStream_t stream) {
  const float* x      = (const float*)d_in[0];
  const float* prior  = (const float*)d_in[1];
  const float* alpha  = (const float*)d_in[2];
  const float* ipw    = (const float*)d_in[3];
  const float* cw     = (const float*)d_in[4];
  const float* cb     = (const float*)d_in[5];
  const float* xpw    = (const float*)d_in[6];
  const float* dtw    = (const float*)d_in[7];
  const float* dtb    = (const float*)d_in[8];
  const float* A_logs = (const float*)d_in[9];
  const float* Ds     = (const float*)d_in[10];
  const float* onw    = (const float*)d_in[11];
  const float* onb    = (const float*)d_in[12];
  const float* opw    = (const float*)d_in[13];
  const float* w1     = (const float*)d_in[14];
  const float* b1     = (const float*)d_in[15];
  const float* bnw    = (const float*)d_in[16];
  const float* bnb    = (const float*)d_in[17];
  const float* bnm    = (const float*)d_in[18];
  const float* bnv    = (const float*)d_in[19];
  const float* w2     = (const float*)d_in[20];
  const float* b2     = (const float*)d_in[21];
  float* out = (float*)d_out;

  char* ws = (char*)d_ws;
  // Footprint ends at 114,843,648 B (< 135,266,304 proven in R2).
  float* xz    = (float*)(ws);              // [B,384,L]     50.3 MB
  float* xcT   = (float*)(ws + 50331648);   // [B,L,192]     25.2 MB (-> u after apply)
  float* ymT2  = (float*)(ws + 75497472);   // [B,L,192]     25.2 MB
  float* projS = (float*)(ws + 100663296);  // [B,K,L,8]      4.2 MB (scan order)
  float* Wgb   = (float*)(ws + 104857600);  // [B,4,L]        0.5 MB
  float* carrP = (float*)(ws + 105381888);  // [B,K,SS,192]   3.0 MB
  float* carrH = (float*)(ws + 108527616);  // [B,K,SS,192]   3.0 MB
  float* h0b   = (float*)(ws + 111673344);  // [B,K,SS,192]   3.0 MB
  float* xpwT  = (float*)(ws + 114819072);  // [K,DIN,8]      24.6 KB (ends 114843648)
  float* ymT   = xz;   // overlay: x_ssm half of xz (dead after convproj)
  float* u     = xcT;  // xcT dead after scan_apply_k

  // 1) in_proj GEMM: [B,96,L] -> [B,384,L]
  gemm_pix_k<CIN><<<dim3(LL / 1024, 384 / 8, BB), 256, 0, stream>>>(x, ipw, xz, 384);
  // 2) prior -> direction gates  (+ weight transpose in block 0)
  p2w_k<<<(BB * LL) / 256, 256, 0, stream>>>(prior, alpha, w1, b1, bnw, bnb, bnm,
                                             bnv, w2, b2, xpw, xpwT, Wgb);
  // 3) fused dwconv+SiLU + x_proj(scan-order) + transpose (64-px, 1024 thr)
  convproj_k<<<dim3(HH, BB), 1024, 0, stream>>>(xz, cw, cb, xpwT, xcT, projS);
  // 4) scan: paired segment carries (both directions per xcT pass)
  scan_part_k<<<dim3(SS, 2, BB), 192, 0, stream>>>(xcT, projS, dtw, dtb, A_logs,
                                                   carrP, carrH);
  // 5) scan: serial carry combine
  scan_fix_k<<<dim3(KK, BB), 192, 0, stream>>>(carrP, carrH, h0b);
  // 6) scan: apply + gate + paired merge (ymT overlaid on xz x_ssm half)
  scan_apply_k<<<dim3(SS, 2, BB), 192, 0, stream>>>(xcT, projS, Wgb, h0b, dtw, dtb,
                                                    A_logs, Ds, ymT, ymT2);
  // 7) LayerNorm(channel) * silu(z)
  ln_silu_k<<<dim3(HH, BB), 256, 0, stream>>>(ymT, ymT2, xz, onw, onb, u);
  // 8) out_proj GEMM
  gemm_pix_k<DIN><<<dim3(LL / 1024, COUT / 8, BB), 256, 0, stream>>>(u, opw, out, COUT);
}

// Round 14
// 219.665 us; speedup vs baseline: 1.2622x; 1.0095x over previous
//
#include <hip/hip_runtime.h>

#define BB   8
#define CIN  96
#define DIN  192
#define HH   64
#define WW   64
#define LL   4096
#define KK   4
#define COUT 96
#define SS   128  // scan segments
#define LC   32   // segment length = LL/SS

#define LOG2E 1.4426950408889634f
#define LN2   0.6931471805599453f

__device__ __forceinline__ float exp2fast(float x) { return __builtin_amdgcn_exp2f(x); }
__device__ __forceinline__ float log2fast(float x) { return __builtin_amdgcn_logf(x); }
__device__ __forceinline__ float sigf(float x) { return 1.0f / (1.0f + __expf(-x)); }
__device__ __forceinline__ int trp(int p) { return ((p & 63) << 6) | (p >> 6); }
__device__ __forceinline__ int pix_of(int k, int l) {
  if (k == 0) return l;
  if (k == 1) return trp(l);
  if (k == 2) return LL - 1 - l;
  return trp(LL - 1 - l);
}

// ---------------------------------------------------------------------------
// Per-pixel GEMM v2: 1 px/thread, 8 outputs; weights via block-uniform
// (scalar s_load) global reads; no LDS, no syncs. Bit-identical c-order.
// ---------------------------------------------------------------------------
template <int C>
__global__ __launch_bounds__(256) void gemm_pix_k(const float* __restrict__ in,
                                                  const float* __restrict__ W,
                                                  float* __restrict__ out, int O) {
  const int tid = threadIdx.x;
  const int b  = blockIdx.z;
  const int o0 = blockIdx.y * 8;
  const int p  = blockIdx.x * 256 + tid;
  const float* inb = in + (size_t)b * C * LL + p;
  const float* Wb  = W + (size_t)o0 * C;   // block-uniform
  float acc[8];
#pragma unroll
  for (int j = 0; j < 8; ++j) acc[j] = 0.0f;
#pragma unroll 2
  for (int c = 0; c < C; c += 4) {
    float4 w[8];
#pragma unroll
    for (int j = 0; j < 8; ++j) w[j] = *(const float4*)&Wb[j * C + c];
    float xv[4];
#pragma unroll
    for (int i = 0; i < 4; ++i) xv[i] = inb[(size_t)(c + i) * LL];
#pragma unroll
    for (int j = 0; j < 8; ++j) {
      acc[j] = fmaf(xv[0], w[j].x, acc[j]);
      acc[j] = fmaf(xv[1], w[j].y, acc[j]);
      acc[j] = fmaf(xv[2], w[j].z, acc[j]);
      acc[j] = fmaf(xv[3], w[j].w, acc[j]);
    }
  }
  float* ob = out + (size_t)b * O * LL + p;
#pragma unroll
  for (int j = 0; j < 8; ++j) ob[(size_t)(o0 + j) * LL] = acc[j];
}

// ---------------------------------------------------------------------------
// PriorToWeights MLP -> Wg[B,4,L].  Block 0: transpose xpw -> xpwT[k][dd][8].
// ---------------------------------------------------------------------------
__global__ __launch_bounds__(256) void p2w_k(const float* __restrict__ prior,
                                             const float* __restrict__ alpha,
                                             const float* __restrict__ w1,
                                             const float* __restrict__ b1,
                                             const float* __restrict__ bnw,
                                             const float* __restrict__ bnb,
                                             const float* __restrict__ bnm,
                                             const float* __restrict__ bnv,
                                             const float* __restrict__ w2,
                                             const float* __restrict__ b2,
                                             const float* __restrict__ xpw,
                                             float* __restrict__ xpwT,
                                             float* __restrict__ Wg) {
  if (blockIdx.x == 0) {
    for (int idx = threadIdx.x; idx < KK * DIN * 8; idx += 256) {
      int kk = idx / (DIN * 8);
      int rem = idx % (DIN * 8);
      int dd = rem >> 3, c = rem & 7;
      xpwT[idx] = xpw[(kk * 8 + c) * DIN + dd];
    }
  }
  int idx = blockIdx.x * 256 + threadIdx.x;
  int p = idx & (LL - 1);
  int b = idx >> 12;
  float pr[4];
#pragma unroll
  for (int c = 0; c < 4; ++c) pr[c] = prior[((size_t)b * 4 + c) * LL + p];
  float s = sigf(alpha[0]);
  float g2[4];
#pragma unroll
  for (int j = 0; j < 4; ++j) g2[j] = b2[j];
  for (int o = 0; o < 32; ++o) {
    float g = b1[o];
#pragma unroll
    for (int c = 0; c < 4; ++c) g = fmaf(pr[c], w1[o * 4 + c], g);
    g = (g - bnm[o]) * rsqrtf(bnv[o] + 1e-5f) * bnw[o] + bnb[o];
    g = fmaxf(g, 0.0f);
#pragma unroll
    for (int j = 0; j < 4; ++j) g2[j] = fmaf(g, w2[j * 32 + o], g2[j]);
  }
#pragma unroll
  for (int j = 0; j < 4; ++j)
    Wg[((size_t)b * 4 + j) * LL + p] = 1.0f + s * (sigf(g2[j]) - 1.0f);
}

// ---------------------------------------------------------------------------
// FUSED conv+proj v5: 64-px row tiles, 1024 threads (32 waves/CU).
// ---------------------------------------------------------------------------
__global__ __launch_bounds__(1024) void convproj_k(const float* __restrict__ xz,
                                                   const float* __restrict__ cw,
                                                   const float* __restrict__ cb,
                                                   const float* __restrict__ xpwT,
                                                   float* __restrict__ xcT,
                                                   float* __restrict__ projS) {
  __shared__ float sX[96 * 65];   // 24.96 KB
  __shared__ float4 sP[512];      // 8 KB q-partials
  const int tid = threadIdx.x;
  const int b = blockIdx.y;
  const int h = blockIdx.x;
  const int px = tid & 63;
  const int ku = __builtin_amdgcn_readfirstlane((tid >> 6) & 3);
  const int hf = __builtin_amdgcn_readfirstlane((tid >> 8) & 1);
  const int q  = __builtin_amdgcn_readfirstlane(tid >> 9);
  float a0 = 0.0f, a1 = 0.0f, a2 = 0.0f, a3 = 0.0f;

#pragma unroll
  for (int half = 0; half < 2; ++half) {
    for (int idx = tid; idx < 96 * 64; idx += 1024) {
      int ddl = idx >> 6, pxx = idx & 63;
      int dd = half * 96 + ddl;
      const float* xp = xz + ((size_t)b * 384 + dd) * LL + h * 64 + pxx;
      const float* wp = cw + dd * 9;
      float s = cb[dd];
#pragma unroll
      for (int dh = -1; dh <= 1; ++dh) {
        int hh = h + dh;
        if (hh < 0 || hh >= HH) continue;
        const float* row = xp + dh * 64;
        float c0 = wp[(dh + 1) * 3], c1 = wp[(dh + 1) * 3 + 1], c2 = wp[(dh + 1) * 3 + 2];
        if (pxx > 0) s = fmaf(row[-1], c0, s);
        s = fmaf(row[0], c1, s);
        if (pxx < 63) s = fmaf(row[1], c2, s);
      }
      sX[ddl * 65 + pxx] = s * sigf(s);
    }
    __syncthreads();
    for (int idx = tid; idx < 64 * 96; idx += 1024) {
      int pp = idx / 96, ddl = idx % 96;
      xcT[((size_t)b * LL + h * 64 + pp) * DIN + half * 96 + ddl] = sX[ddl * 65 + pp];
    }
    {
      const int ddl0 = q * 48;
      const float* wp = xpwT + (size_t)ku * (DIN * 8) + (half * 96 + ddl0) * 8 + hf * 4;
#pragma unroll 8
      for (int d48 = 0; d48 < 48; ++d48) {
        float xv = sX[(ddl0 + d48) * 65 + px];
        const float4 w4 = *(const float4*)(wp + d48 * 8);
        a0 = fmaf(xv, w4.x, a0);
        a1 = fmaf(xv, w4.y, a1);
        a2 = fmaf(xv, w4.z, a2);
        a3 = fmaf(xv, w4.w, a3);
      }
    }
    __syncthreads();
  }
  const int slot = tid & 511;
  if (q == 1) sP[slot] = make_float4(a0, a1, a2, a3);
  __syncthreads();
  if (q == 0) {
    float4 o = sP[slot];
    a0 += o.x; a1 += o.y; a2 += o.z; a3 += o.w;
    const int p = h * 64 + px;
    int l;
    if (ku == 0) l = p;
    else if (ku == 1) l = trp(p);
    else if (ku == 2) l = LL - 1 - p;
    else l = LL - 1 - trp(p);
    float* pb = projS + (((size_t)b * KK + ku) * LL + l) * 8 + hf * 4;
    *(float4*)pb = make_float4(a0, a1, a2, a3);
  }
}

// ---------------------------------------------------------------------------
// Scan pass 1 (PAIRED): one xcT pass computes carries for BOTH opposite
// directions. Forward kA: H=aH+b, P*=a. Reverse kB: H += P*b, P *= a.
// ---------------------------------------------------------------------------
__global__ __launch_bounds__(192) void scan_part_k(const float* __restrict__ xcT,
                                                   const float* __restrict__ projS,
                                                   const float* __restrict__ dtw,
                                                   const float* __restrict__ dtb,
                                                   const float* __restrict__ A_logs,
                                                   float* __restrict__ carrP,
                                                   float* __restrict__ carrH) {
  const int s = blockIdx.x, kp = blockIdx.y, b = blockIdx.z;
  const int d = threadIdx.x;
  const int kA = kp, kB = kp + 2;
  const int s2 = SS - 1 - s;
  const int kdA = kA * DIN + d, kdB = kB * DIN + d;
  float wrA[6], wrB[6];
#pragma unroll
  for (int r = 0; r < 6; ++r) { wrA[r] = dtw[kdA * 6 + r]; wrB[r] = dtw[kdB * 6 + r]; }
  const float biasA = dtb[kdA], biasB = dtb[kdB];
  const float AaA = -__expf(A_logs[kdA]), AaB = -__expf(A_logs[kdB]);
  const int l0 = s * LC;
  const int p0 = pix_of(kA, l0);
  const int dp = pix_of(kA, l0 + 1) - p0;
  const float* xp = xcT + ((size_t)b * LL + p0) * DIN + d;
  const long xstep = (long)dp * DIN;
  const float* prA = projS + (((size_t)b * KK + kA) * LL + l0) * 8;
  const float* prB = projS + (((size_t)b * KK + kB) * LL + s2 * LC + (LC - 1)) * 8;
  float PA = 1.0f, HA = 0.0f, PB = 1.0f, HB = 0.0f;
#pragma unroll 2
  for (int j = 0; j < LC; ++j) {
    float4 a0 = *(const float4*)prA;
    float4 a1 = *(const float4*)(prA + 4);
    prA += 8;
    float4 b0 = *(const float4*)prB;
    float4 b1 = *(const float4*)(prB + 4);
    prB -= 8;
    float xv = *xp;
    xp += xstep;
    {
      float dtr = biasA;
      dtr = fmaf(a0.x, wrA[0], dtr);
      dtr = fmaf(a0.y, wrA[1], dtr);
      dtr = fmaf(a0.z, wrA[2], dtr);
      dtr = fmaf(a0.w, wrA[3], dtr);
      dtr = fmaf(a1.x, wrA[4], dtr);
      dtr = fmaf(a1.y, wrA[5], dtr);
      float e = exp2fast(fminf(dtr, 80.0f) * LOG2E);
      float u = log2fast(1.0f + e);
      float a = exp2fast(u * AaA);
      float dt = u * LN2;
      HA = fmaf(a, HA, dt * a1.z * xv);
      PA *= a;
    }
    {
      float dtr = biasB;
      dtr = fmaf(b0.x, wrB[0], dtr);
      dtr = fmaf(b0.y, wrB[1], dtr);
      dtr = fmaf(b0.z, wrB[2], dtr);
      dtr = fmaf(b0.w, wrB[3], dtr);
      dtr = fmaf(b1.x, wrB[4], dtr);
      dtr = fmaf(b1.y, wrB[5], dtr);
      float e = exp2fast(fminf(dtr, 80.0f) * LOG2E);
      float u = log2fast(1.0f + e);
      float a = exp2fast(u * AaB);
      float dt = u * LN2;
      HB = fmaf(PB, dt * b1.z * xv, HB);
      PB *= a;
    }
  }
  size_t oA = ((size_t)((b * KK + kA) * SS + s)) * DIN + d;
  size_t oB = ((size_t)((b * KK + kB) * SS + s2)) * DIN + d;
  carrP[oA] = PA;
  carrH[oA] = HA;
  carrP[oB] = PB;
  carrH[oB] = HB;
}

// ---------------------------------------------------------------------------
// Scan pass 2: serial combine of SS carries -> per-segment initial state h0
// ---------------------------------------------------------------------------
__global__ __launch_bounds__(192) void scan_fix_k(const float* __restrict__ carrP,
                                                  const float* __restrict__ carrH,
                                                  float* __restrict__ h0) {
  const int k = blockIdx.x, b = blockIdx.y, d = threadIdx.x;
  size_t base = ((size_t)(b * KK + k)) * SS * DIN + d;
  float h = 0.0f;
#pragma unroll 4
  for (int s = 0; s < SS; ++s) {
    h0[base + (size_t)s * DIN] = h;
    h = fmaf(carrP[base + (size_t)s * DIN], h, carrH[base + (size_t)s * DIN]);
  }
}

// ---------------------------------------------------------------------------
// Scan pass 3: apply + gate + paired-direction merge via 24 KB LDS.
// ---------------------------------------------------------------------------
__global__ __launch_bounds__(192) void scan_apply_k(const float* __restrict__ xcT,
                                                    const float* __restrict__ projS,
                                                    const float* __restrict__ Wg,
                                                    const float* __restrict__ h0,
                                                    const float* __restrict__ dtw,
                                                    const float* __restrict__ dtb,
                                                    const float* __restrict__ A_logs,
                                                    const float* __restrict__ Ds,
                                                    float* __restrict__ ymT,
                                                    float* __restrict__ ymT2) {
  const int s = blockIdx.x, kp = blockIdx.y, b = blockIdx.z;
  const int d = threadIdx.x;
  __shared__ float sAcc[LC * DIN];  // 24 KB, column d thread-private
  {
    const int k = kp, kd = k * DIN + d;
    float wr[6];
#pragma unroll
    for (int r = 0; r < 6; ++r) wr[r] = dtw[kd * 6 + r];
    const float bias = dtb[kd];
    const float Aa = -__expf(A_logs[kd]);
    const float Dv = Ds[kd];
    const int l0 = s * LC;
    const int p0 = pix_of(k, l0);
    const int dp = pix_of(k, l0 + 1) - p0;
    const float* xp = xcT + ((size_t)b * LL + p0) * DIN + d;
    const long xstep = (long)dp * DIN;
    const float* pr = projS + (((size_t)b * KK + k) * LL + l0) * 8;
    const float* wg = Wg + ((size_t)b * KK + k) * LL + l0;
    float h = h0[((size_t)((b * KK + k) * SS + s)) * DIN + d];
#pragma unroll 4
    for (int j = 0; j < LC; ++j) {
      float4 q0 = *(const float4*)pr;
      float4 q1 = *(const float4*)(pr + 4);
      pr += 8;
      float xv = *xp;
      xp += xstep;
      float dtr = bias;
      dtr = fmaf(q0.x, wr[0], dtr);
      dtr = fmaf(q0.y, wr[1], dtr);
      dtr = fmaf(q0.z, wr[2], dtr);
      dtr = fmaf(q0.w, wr[3], dtr);
      dtr = fmaf(q1.x, wr[4], dtr);
      dtr = fmaf(q1.y, wr[5], dtr);
      float e = exp2fast(fminf(dtr, 80.0f) * LOG2E);
      float u = log2fast(1.0f + e);
      float a = exp2fast(u * Aa);
      float dt = u * LN2;
      h = fmaf(a, h, dt * q1.z * xv);
      sAcc[j * DIN + d] = fmaf(h, q1.w, Dv * xv) * wg[j];
    }
  }
  {
    const int k = kp + 2, kd = k * DIN + d;
    const int s2 = SS - 1 - s;
    float wr[6];
#pragma unroll
    for (int r = 0; r < 6; ++r) wr[r] = dtw[kd * 6 + r];
    const float bias = dtb[kd];
    const float Aa = -__expf(A_logs[kd]);
    const float Dv = Ds[kd];
    const int l0 = s2 * LC;
    const int p0 = pix_of(k, l0);
    const int dp = pix_of(k, l0 + 1) - p0;
    const float* xp = xcT + ((size_t)b * LL + p0) * DIN + d;
    const long xstep = (long)dp * DIN;
    const float* pr = projS + (((size_t)b * KK + k) * LL + l0) * 8;
    const float* wg = Wg + ((size_t)b * KK + k) * LL + l0;
    float h = h0[((size_t)((b * KK + k) * SS + s2)) * DIN + d];
#pragma unroll 4
    for (int j = 0; j < LC; ++j) {
      float4 q0 = *(const float4*)pr;
      float4 q1 = *(const float4*)(pr + 4);
      pr += 8;
      float xv = *xp;
      xp += xstep;
      float dtr = bias;
      dtr = fmaf(q0.x, wr[0], dtr);
      dtr = fmaf(q0.y, wr[1], dtr);
      dtr = fmaf(q0.z, wr[2], dtr);
      dtr = fmaf(q0.w, wr[3], dtr);
      dtr = fmaf(q1.x, wr[4], dtr);
      dtr = fmaf(q1.y, wr[5], dtr);
      float e = exp2fast(fminf(dtr, 80.0f) * LOG2E);
      float u = log2fast(1.0f + e);
      float a = exp2fast(u * Aa);
      float dt = u * LN2;
      h = fmaf(a, h, dt * q1.z * xv);
      float y = fmaf(h, q1.w, Dv * xv) * wg[j];
      sAcc[(LC - 1 - j) * DIN + d] += y;
    }
  }
  float* dst;
  if (kp == 0)
    dst = ymT + (size_t)b * (384 * (size_t)LL) + (size_t)(s * LC) * DIN + d;  // xz overlay
  else
    dst = ymT2 + ((size_t)b * LL + s * LC) * DIN + d;
#pragma unroll 4
  for (int j = 0; j < LC; ++j) dst[(size_t)j * DIN] = sAcc[j * DIN + d];
}

// ---------------------------------------------------------------------------
// LayerNorm(channel) * silu(z): reads ymT(overlay)[p,:] + ymT2[tr(p),:], writes u
// ---------------------------------------------------------------------------
__global__ __launch_bounds__(256) void ln_silu_k(const float* __restrict__ ymT,
                                                 const float* __restrict__ ymT2,
                                                 const float* __restrict__ xz,
                                                 const float* __restrict__ gamma,
                                                 const float* __restrict__ beta,
                                                 float* __restrict__ u) {
  const int b = blockIdx.y;
  const int h = blockIdx.x;
  const int p0 = h * 64;
  __shared__ float sY[64 * 193];
  __shared__ float sS[4][64], sQ[4][64];
  const int tid = threadIdx.x;
  const float* ymb = ymT + (size_t)b * (384 * (size_t)LL);  // xz overlay
  for (int idx = tid; idx < 64 * DIN; idx += 256) {
    int pp = idx / DIN, dd = idx % DIN;
    float v = ymb[(size_t)(p0 + pp) * DIN + dd] +
              ymT2[((size_t)b * LL + pp * 64 + h) * DIN + dd];
    sY[pp * 193 + dd] = v;
  }
  __syncthreads();
  const int px = tid & 63, g = tid >> 6;
  float sum = 0.0f, ss = 0.0f;
  for (int dd = g * 48; dd < g * 48 + 48; ++dd) {
    float v = sY[px * 193 + dd];
    sum += v;
    ss = fmaf(v, v, ss);
  }
  sS[g][px] = sum;
  sQ[g][px] = ss;
  __syncthreads();
  sum = sS[0][px] + sS[1][px] + sS[2][px] + sS[3][px];
  ss  = sQ[0][px] + sQ[1][px] + sQ[2][px] + sQ[3][px];
  const float mu = sum * (1.0f / DIN);
  float var = ss * (1.0f / DIN) - mu * mu;
  const float rstd = rsqrtf(fmaxf(var, 0.0f) + 1e-5f);
  const float* zb = xz + ((size_t)b * 384 + DIN) * LL + p0 + px;
  float* ub = u + (size_t)b * DIN * LL + p0 + px;
  for (int dd = g * 48; dd < g * 48 + 48; ++dd) {
    float v = sY[px * 193 + dd];
    float z = zb[(size_t)dd * LL];
    float tn = fmaf((v - mu) * rstd, gamma[dd], beta[dd]);
    ub[(size_t)dd * LL] = tn * (z * sigf(z));
  }
}

// ---------------------------------------------------------------------------
extern "C" void kernel_launch(void* const* d_in, const int* in_sizes, int n_in,
                              void* d_out, int out_size, void* d_ws, size_t ws_size,
                              hipStream_t stream) {
  const float* x      = (const float*)d_in[0];
  const float* prior  = (const float*)d_in[1];
  const float* alpha  = (const float*)d_in[2];
  const float* ipw    = (const float*)d_in[3];
  const float* cw     = (const float*)d_in[4];
  const float* cb     = (const float*)d_in[5];
  const float* xpw    = (const float*)d_in[6];
  const float* dtw    = (const float*)d_in[7];
  const float* dtb    = (const float*)d_in[8];
  const float* A_logs = (const float*)d_in[9];
  const float* Ds     = (const float*)d_in[10];
  const float* onw    = (const float*)d_in[11];
  const float* onb    = (const float*)d_in[12];
  const float* opw    = (const float*)d_in[13];
  const float* w1     = (const float*)d_in[14];
  const float* b1     = (const float*)d_in[15];
  const float* bnw    = (const float*)d_in[16];
  const float* bnb    = (const float*)d_in[17];
  const float* bnm    = (const float*)d_in[18];
  const float* bnv    = (const float*)d_in[19];
  const float* w2     = (const float*)d_in[20];
  const float* b2     = (const float*)d_in[21];
  float* out = (float*)d_out;

  char* ws = (char*)d_ws;
  // Footprint ends at 114,843,648 B (< 135,266,304 proven in R2).
  float* xz    = (float*)(ws);              // [B,384,L]     50.3 MB
  float* xcT   = (float*)(ws + 50331648);   // [B,L,192]     25.2 MB (-> u after apply)
  float* ymT2  = (float*)(ws + 75497472);   // [B,L,192]     25.2 MB
  float* projS = (float*)(ws + 100663296);  // [B,K,L,8]      4.2 MB (scan order)
  float* Wgb   = (float*)(ws + 104857600);  // [B,4,L]        0.5 MB
  float* carrP = (float*)(ws + 105381888);  // [B,K,SS,192]   3.0 MB
  float* carrH = (float*)(ws + 108527616);  // [B,K,SS,192]   3.0 MB
  float* h0b   = (float*)(ws + 111673344);  // [B,K,SS,192]   3.0 MB
  float* xpwT  = (float*)(ws + 114819072);  // [K,DIN,8]      24.6 KB (ends 114843648)
  float* ymT   = xz;   // overlay: x_ssm half of xz (dead after convproj)
  float* u     = xcT;  // xcT dead after scan_apply_k

  // 1) in_proj GEMM: [B,96,L] -> [B,384,L]  (256-px blocks, 6144 blocks)
  gemm_pix_k<CIN><<<dim3(LL / 256, 384 / 8, BB), 256, 0, stream>>>(x, ipw, xz, 384);
  // 2) prior -> direction gates  (+ weight transpose in block 0)
  p2w_k<<<(BB * LL) / 256, 256, 0, stream>>>(prior, alpha, w1, b1, bnw, bnb, bnm,
                                             bnv, w2, b2, xpw, xpwT, Wgb);
  // 3) fused dwconv+SiLU + x_proj(scan-order) + transpose (64-px, 1024 thr)
  convproj_k<<<dim3(HH, BB), 1024, 0, stream>>>(xz, cw, cb, xpwT, xcT, projS);
  // 4) scan: paired segment carries (both directions per xcT pass)
  scan_part_k<<<dim3(SS, 2, BB), 192, 0, stream>>>(xcT, projS, dtw, dtb, A_logs,
                                                   carrP, carrH);
  // 5) scan: serial carry combine
  scan_fix_k<<<dim3(KK, BB), 192, 0, stream>>>(carrP, carrH, h0b);
  // 6) scan: apply + gate + paired merge (ymT overlaid on xz x_ssm half)
  scan_apply_k<<<dim3(SS, 2, BB), 192, 0, stream>>>(xcT, projS, Wgb, h0b, dtw, dtb,
                                                    A_logs, Ds, ymT, ymT2);
  // 7) LayerNorm(channel) * silu(z)
  ln_silu_k<<<dim3(HH, BB), 256, 0, stream>>>(ymT, ymT2, xz, onw, onb, u);
  // 8) out_proj GEMM  (256-px blocks, 1536 blocks)
  gemm_pix_k<DIN><<<dim3(LL / 256, COUT / 8, BB), 256, 0, stream>>>(u, opw, out, COUT);
}

// Round 15
// 206.865 us; speedup vs baseline: 1.3403x; 1.0619x over previous
//
#include <hip/hip_runtime.h>

#define BB   8
#define CIN  96
#define DIN  192
#define HH   64
#define WW   64
#define LL   4096
#define KK   4
#define COUT 96
#define SS   128  // scan segments
#define LC   32   // segment length = LL/SS

#define LOG2E 1.4426950408889634f
#define LN2   0.6931471805599453f

__device__ __forceinline__ float exp2fast(float x) { return __builtin_amdgcn_exp2f(x); }
__device__ __forceinline__ float log2fast(float x) { return __builtin_amdgcn_logf(x); }
__device__ __forceinline__ float sigf(float x) { return 1.0f / (1.0f + __expf(-x)); }
__device__ __forceinline__ int trp(int p) { return ((p & 63) << 6) | (p >> 6); }
__device__ __forceinline__ int pix_of(int k, int l) {
  if (k == 0) return l;
  if (k == 1) return trp(l);
  if (k == 2) return LL - 1 - l;
  return trp(LL - 1 - l);
}

// ---------------------------------------------------------------------------
// Per-pixel GEMM v3: PX px/thread, 8 outputs; weights via block-uniform
// global reads (compiler -> SGPR s_load). Bit-identical c-order per output.
// ---------------------------------------------------------------------------
template <int C, int PX>
__global__ __launch_bounds__(256) void gemm_pix_k(const float* __restrict__ in,
                                                  const float* __restrict__ W,
                                                  float* __restrict__ out, int O) {
  const int tid = threadIdx.x;
  const int b  = blockIdx.z;
  const int o0 = blockIdx.y * 8;
  const int p  = blockIdx.x * (256 * PX) + tid;
  const float* inb = in + (size_t)b * C * LL + p;
  const float* Wb  = W + (size_t)o0 * C;   // block-uniform -> scalar loads
  float acc[PX][8];
#pragma unroll
  for (int i = 0; i < PX; ++i)
#pragma unroll
    for (int j = 0; j < 8; ++j) acc[i][j] = 0.0f;
#pragma unroll 2
  for (int c = 0; c < C; c += 4) {
    float4 w[8];
#pragma unroll
    for (int j = 0; j < 8; ++j) w[j] = *(const float4*)&Wb[j * C + c];
    float xv[PX][4];
#pragma unroll
    for (int i = 0; i < PX; ++i)
#pragma unroll
      for (int t = 0; t < 4; ++t) xv[i][t] = inb[(size_t)(c + t) * LL + i * 256];
#pragma unroll
    for (int i = 0; i < PX; ++i)
#pragma unroll
      for (int j = 0; j < 8; ++j) {
        acc[i][j] = fmaf(xv[i][0], w[j].x, acc[i][j]);
        acc[i][j] = fmaf(xv[i][1], w[j].y, acc[i][j]);
        acc[i][j] = fmaf(xv[i][2], w[j].z, acc[i][j]);
        acc[i][j] = fmaf(xv[i][3], w[j].w, acc[i][j]);
      }
  }
  float* ob = out + (size_t)b * O * LL + p;
#pragma unroll
  for (int j = 0; j < 8; ++j)
#pragma unroll
    for (int i = 0; i < PX; ++i) ob[(size_t)(o0 + j) * LL + i * 256] = acc[i][j];
}

// ---------------------------------------------------------------------------
// PriorToWeights MLP -> Wg[B,4,L].  Block 0: transpose xpw -> xpwT[k][dd][8].
// ---------------------------------------------------------------------------
__global__ __launch_bounds__(256) void p2w_k(const float* __restrict__ prior,
                                             const float* __restrict__ alpha,
                                             const float* __restrict__ w1,
                                             const float* __restrict__ b1,
                                             const float* __restrict__ bnw,
                                             const float* __restrict__ bnb,
                                             const float* __restrict__ bnm,
                                             const float* __restrict__ bnv,
                                             const float* __restrict__ w2,
                                             const float* __restrict__ b2,
                                             const float* __restrict__ xpw,
                                             float* __restrict__ xpwT,
                                             float* __restrict__ Wg) {
  if (blockIdx.x == 0) {
    for (int idx = threadIdx.x; idx < KK * DIN * 8; idx += 256) {
      int kk = idx / (DIN * 8);
      int rem = idx % (DIN * 8);
      int dd = rem >> 3, c = rem & 7;
      xpwT[idx] = xpw[(kk * 8 + c) * DIN + dd];
    }
  }
  int idx = blockIdx.x * 256 + threadIdx.x;
  int p = idx & (LL - 1);
  int b = idx >> 12;
  float pr[4];
#pragma unroll
  for (int c = 0; c < 4; ++c) pr[c] = prior[((size_t)b * 4 + c) * LL + p];
  float s = sigf(alpha[0]);
  float g2[4];
#pragma unroll
  for (int j = 0; j < 4; ++j) g2[j] = b2[j];
  for (int o = 0; o < 32; ++o) {
    float g = b1[o];
#pragma unroll
    for (int c = 0; c < 4; ++c) g = fmaf(pr[c], w1[o * 4 + c], g);
    g = (g - bnm[o]) * rsqrtf(bnv[o] + 1e-5f) * bnw[o] + bnb[o];
    g = fmaxf(g, 0.0f);
#pragma unroll
    for (int j = 0; j < 4; ++j) g2[j] = fmaf(g, w2[j * 32 + o], g2[j]);
  }
#pragma unroll
  for (int j = 0; j < 4; ++j)
    Wg[((size_t)b * 4 + j) * LL + p] = 1.0f + s * (sigf(g2[j]) - 1.0f);
}

// ---------------------------------------------------------------------------
// FUSED conv+proj v5: 64-px row tiles, 1024 threads (32 waves/CU).
// ---------------------------------------------------------------------------
__global__ __launch_bounds__(1024) void convproj_k(const float* __restrict__ xz,
                                                   const float* __restrict__ cw,
                                                   const float* __restrict__ cb,
                                                   const float* __restrict__ xpwT,
                                                   float* __restrict__ xcT,
                                                   float* __restrict__ projS) {
  __shared__ float sX[96 * 65];   // 24.96 KB
  __shared__ float4 sP[512];      // 8 KB q-partials
  const int tid = threadIdx.x;
  const int b = blockIdx.y;
  const int h = blockIdx.x;
  const int px = tid & 63;
  const int ku = __builtin_amdgcn_readfirstlane((tid >> 6) & 3);
  const int hf = __builtin_amdgcn_readfirstlane((tid >> 8) & 1);
  const int q  = __builtin_amdgcn_readfirstlane(tid >> 9);
  float a0 = 0.0f, a1 = 0.0f, a2 = 0.0f, a3 = 0.0f;

#pragma unroll
  for (int half = 0; half < 2; ++half) {
    for (int idx = tid; idx < 96 * 64; idx += 1024) {
      int ddl = idx >> 6, pxx = idx & 63;
      int dd = half * 96 + ddl;
      const float* xp = xz + ((size_t)b * 384 + dd) * LL + h * 64 + pxx;
      const float* wp = cw + dd * 9;
      float s = cb[dd];
#pragma unroll
      for (int dh = -1; dh <= 1; ++dh) {
        int hh = h + dh;
        if (hh < 0 || hh >= HH) continue;
        const float* row = xp + dh * 64;
        float c0 = wp[(dh + 1) * 3], c1 = wp[(dh + 1) * 3 + 1], c2 = wp[(dh + 1) * 3 + 2];
        if (pxx > 0) s = fmaf(row[-1], c0, s);
        s = fmaf(row[0], c1, s);
        if (pxx < 63) s = fmaf(row[1], c2, s);
      }
      sX[ddl * 65 + pxx] = s * sigf(s);
    }
    __syncthreads();
    for (int idx = tid; idx < 64 * 96; idx += 1024) {
      int pp = idx / 96, ddl = idx % 96;
      xcT[((size_t)b * LL + h * 64 + pp) * DIN + half * 96 + ddl] = sX[ddl * 65 + pp];
    }
    {
      const int ddl0 = q * 48;
      const float* wp = xpwT + (size_t)ku * (DIN * 8) + (half * 96 + ddl0) * 8 + hf * 4;
#pragma unroll 8
      for (int d48 = 0; d48 < 48; ++d48) {
        float xv = sX[(ddl0 + d48) * 65 + px];
        const float4 w4 = *(const float4*)(wp + d48 * 8);
        a0 = fmaf(xv, w4.x, a0);
        a1 = fmaf(xv, w4.y, a1);
        a2 = fmaf(xv, w4.z, a2);
        a3 = fmaf(xv, w4.w, a3);
      }
    }
    __syncthreads();
  }
  const int slot = tid & 511;
  if (q == 1) sP[slot] = make_float4(a0, a1, a2, a3);
  __syncthreads();
  if (q == 0) {
    float4 o = sP[slot];
    a0 += o.x; a1 += o.y; a2 += o.z; a3 += o.w;
    const int p = h * 64 + px;
    int l;
    if (ku == 0) l = p;
    else if (ku == 1) l = trp(p);
    else if (ku == 2) l = LL - 1 - p;
    else l = LL - 1 - trp(p);
    float* pb = projS + (((size_t)b * KK + ku) * LL + l) * 8 + hf * 4;
    *(float4*)pb = make_float4(a0, a1, a2, a3);
  }
}

// ---------------------------------------------------------------------------
// Scan pass 1 (PAIRED): one xcT pass computes carries for BOTH opposite
// directions. Forward kA: H=aH+b, P*=a. Reverse kB: H += P*b, P *= a.
// ---------------------------------------------------------------------------
__global__ __launch_bounds__(192) void scan_part_k(const float* __restrict__ xcT,
                                                   const float* __restrict__ projS,
                                                   const float* __restrict__ dtw,
                                                   const float* __restrict__ dtb,
                                                   const float* __restrict__ A_logs,
                                                   float* __restrict__ carrP,
                                                   float* __restrict__ carrH) {
  const int s = blockIdx.x, kp = blockIdx.y, b = blockIdx.z;
  const int d = threadIdx.x;
  const int kA = kp, kB = kp + 2;
  const int s2 = SS - 1 - s;
  const int kdA = kA * DIN + d, kdB = kB * DIN + d;
  float wrA[6], wrB[6];
#pragma unroll
  for (int r = 0; r < 6; ++r) { wrA[r] = dtw[kdA * 6 + r]; wrB[r] = dtw[kdB * 6 + r]; }
  const float biasA = dtb[kdA], biasB = dtb[kdB];
  const float AaA = -__expf(A_logs[kdA]), AaB = -__expf(A_logs[kdB]);
  const int l0 = s * LC;
  const int p0 = pix_of(kA, l0);
  const int dp = pix_of(kA, l0 + 1) - p0;
  const float* xp = xcT + ((size_t)b * LL + p0) * DIN + d;
  const long xstep = (long)dp * DIN;
  const float* prA = projS + (((size_t)b * KK + kA) * LL + l0) * 8;
  const float* prB = projS + (((size_t)b * KK + kB) * LL + s2 * LC + (LC - 1)) * 8;
  float PA = 1.0f, HA = 0.0f, PB = 1.0f, HB = 0.0f;
#pragma unroll 2
  for (int j = 0; j < LC; ++j) {
    float4 a0 = *(const float4*)prA;
    float4 a1 = *(const float4*)(prA + 4);
    prA += 8;
    float4 b0 = *(const float4*)prB;
    float4 b1 = *(const float4*)(prB + 4);
    prB -= 8;
    float xv = *xp;
    xp += xstep;
    {
      float dtr = biasA;
      dtr = fmaf(a0.x, wrA[0], dtr);
      dtr = fmaf(a0.y, wrA[1], dtr);
      dtr = fmaf(a0.z, wrA[2], dtr);
      dtr = fmaf(a0.w, wrA[3], dtr);
      dtr = fmaf(a1.x, wrA[4], dtr);
      dtr = fmaf(a1.y, wrA[5], dtr);
      float e = exp2fast(fminf(dtr, 80.0f) * LOG2E);
      float u = log2fast(1.0f + e);
      float a = exp2fast(u * AaA);
      float dt = u * LN2;
      HA = fmaf(a, HA, dt * a1.z * xv);
      PA *= a;
    }
    {
      float dtr = biasB;
      dtr = fmaf(b0.x, wrB[0], dtr);
      dtr = fmaf(b0.y, wrB[1], dtr);
      dtr = fmaf(b0.z, wrB[2], dtr);
      dtr = fmaf(b0.w, wrB[3], dtr);
      dtr = fmaf(b1.x, wrB[4], dtr);
      dtr = fmaf(b1.y, wrB[5], dtr);
      float e = exp2fast(fminf(dtr, 80.0f) * LOG2E);
      float u = log2fast(1.0f + e);
      float a = exp2fast(u * AaB);
      float dt = u * LN2;
      HB = fmaf(PB, dt * b1.z * xv, HB);
      PB *= a;
    }
  }
  size_t oA = ((size_t)((b * KK + kA) * SS + s)) * DIN + d;
  size_t oB = ((size_t)((b * KK + kB) * SS + s2)) * DIN + d;
  carrP[oA] = PA;
  carrH[oA] = HA;
  carrP[oB] = PB;
  carrH[oB] = HB;
}

// ---------------------------------------------------------------------------
// Scan pass 2: serial combine of SS carries -> per-segment initial state h0
// ---------------------------------------------------------------------------
__global__ __launch_bounds__(192) void scan_fix_k(const float* __restrict__ carrP,
                                                  const float* __restrict__ carrH,
                                                  float* __restrict__ h0) {
  const int k = blockIdx.x, b = blockIdx.y, d = threadIdx.x;
  size_t base = ((size_t)(b * KK + k)) * SS * DIN + d;
  float h = 0.0f;
#pragma unroll 4
  for (int s = 0; s < SS; ++s) {
    h0[base + (size_t)s * DIN] = h;
    h = fmaf(carrP[base + (size_t)s * DIN], h, carrH[base + (size_t)s * DIN]);
  }
}

// ---------------------------------------------------------------------------
// Scan pass 3: apply + gate + paired-direction merge via 24 KB LDS.
// ---------------------------------------------------------------------------
__global__ __launch_bounds__(192) void scan_apply_k(const float* __restrict__ xcT,
                                                    const float* __restrict__ projS,
                                                    const float* __restrict__ Wg,
                                                    const float* __restrict__ h0,
                                                    const float* __restrict__ dtw,
                                                    const float* __restrict__ dtb,
                                                    const float* __restrict__ A_logs,
                                                    const float* __restrict__ Ds,
                                                    float* __restrict__ ymT,
                                                    float* __restrict__ ymT2) {
  const int s = blockIdx.x, kp = blockIdx.y, b = blockIdx.z;
  const int d = threadIdx.x;
  __shared__ float sAcc[LC * DIN];  // 24 KB, column d thread-private
  {
    const int k = kp, kd = k * DIN + d;
    float wr[6];
#pragma unroll
    for (int r = 0; r < 6; ++r) wr[r] = dtw[kd * 6 + r];
    const float bias = dtb[kd];
    const float Aa = -__expf(A_logs[kd]);
    const float Dv = Ds[kd];
    const int l0 = s * LC;
    const int p0 = pix_of(k, l0);
    const int dp = pix_of(k, l0 + 1) - p0;
    const float* xp = xcT + ((size_t)b * LL + p0) * DIN + d;
    const long xstep = (long)dp * DIN;
    const float* pr = projS + (((size_t)b * KK + k) * LL + l0) * 8;
    const float* wg = Wg + ((size_t)b * KK + k) * LL + l0;
    float h = h0[((size_t)((b * KK + k) * SS + s)) * DIN + d];
#pragma unroll 4
    for (int j = 0; j < LC; ++j) {
      float4 q0 = *(const float4*)pr;
      float4 q1 = *(const float4*)(pr + 4);
      pr += 8;
      float xv = *xp;
      xp += xstep;
      float dtr = bias;
      dtr = fmaf(q0.x, wr[0], dtr);
      dtr = fmaf(q0.y, wr[1], dtr);
      dtr = fmaf(q0.z, wr[2], dtr);
      dtr = fmaf(q0.w, wr[3], dtr);
      dtr = fmaf(q1.x, wr[4], dtr);
      dtr = fmaf(q1.y, wr[5], dtr);
      float e = exp2fast(fminf(dtr, 80.0f) * LOG2E);
      float u = log2fast(1.0f + e);
      float a = exp2fast(u * Aa);
      float dt = u * LN2;
      h = fmaf(a, h, dt * q1.z * xv);
      sAcc[j * DIN + d] = fmaf(h, q1.w, Dv * xv) * wg[j];
    }
  }
  {
    const int k = kp + 2, kd = k * DIN + d;
    const int s2 = SS - 1 - s;
    float wr[6];
#pragma unroll
    for (int r = 0; r < 6; ++r) wr[r] = dtw[kd * 6 + r];
    const float bias = dtb[kd];
    const float Aa = -__expf(A_logs[kd]);
    const float Dv = Ds[kd];
    const int l0 = s2 * LC;
    const int p0 = pix_of(k, l0);
    const int dp = pix_of(k, l0 + 1) - p0;
    const float* xp = xcT + ((size_t)b * LL + p0) * DIN + d;
    const long xstep = (long)dp * DIN;
    const float* pr = projS + (((size_t)b * KK + k) * LL + l0) * 8;
    const float* wg = Wg + ((size_t)b * KK + k) * LL + l0;
    float h = h0[((size_t)((b * KK + k) * SS + s2)) * DIN + d];
#pragma unroll 4
    for (int j = 0; j < LC; ++j) {
      float4 q0 = *(const float4*)pr;
      float4 q1 = *(const float4*)(pr + 4);
      pr += 8;
      float xv = *xp;
      xp += xstep;
      float dtr = bias;
      dtr = fmaf(q0.x, wr[0], dtr);
      dtr = fmaf(q0.y, wr[1], dtr);
      dtr = fmaf(q0.z, wr[2], dtr);
      dtr = fmaf(q0.w, wr[3], dtr);
      dtr = fmaf(q1.x, wr[4], dtr);
      dtr = fmaf(q1.y, wr[5], dtr);
      float e = exp2fast(fminf(dtr, 80.0f) * LOG2E);
      float u = log2fast(1.0f + e);
      float a = exp2fast(u * Aa);
      float dt = u * LN2;
      h = fmaf(a, h, dt * q1.z * xv);
      float y = fmaf(h, q1.w, Dv * xv) * wg[j];
      sAcc[(LC - 1 - j) * DIN + d] += y;
    }
  }
  float* dst;
  if (kp == 0)
    dst = ymT + (size_t)b * (384 * (size_t)LL) + (size_t)(s * LC) * DIN + d;  // xz overlay
  else
    dst = ymT2 + ((size_t)b * LL + s * LC) * DIN + d;
#pragma unroll 4
  for (int j = 0; j < LC; ++j) dst[(size_t)j * DIN] = sAcc[j * DIN + d];
}

// ---------------------------------------------------------------------------
// LayerNorm(channel) * silu(z): reads ymT(overlay)[p,:] + ymT2[tr(p),:], writes u
// ---------------------------------------------------------------------------
__global__ __launch_bounds__(256) void ln_silu_k(const float* __restrict__ ymT,
                                                 const float* __restrict__ ymT2,
                                                 const float* __restrict__ xz,
                                                 const float* __restrict__ gamma,
                                                 const float* __restrict__ beta,
                                                 float* __restrict__ u) {
  const int b = blockIdx.y;
  const int h = blockIdx.x;
  const int p0 = h * 64;
  __shared__ float sY[64 * 193];
  __shared__ float sS[4][64], sQ[4][64];
  const int tid = threadIdx.x;
  const float* ymb = ymT + (size_t)b * (384 * (size_t)LL);  // xz overlay
  for (int idx = tid; idx < 64 * DIN; idx += 256) {
    int pp = idx / DIN, dd = idx % DIN;
    float v = ymb[(size_t)(p0 + pp) * DIN + dd] +
              ymT2[((size_t)b * LL + pp * 64 + h) * DIN + dd];
    sY[pp * 193 + dd] = v;
  }
  __syncthreads();
  const int px = tid & 63, g = tid >> 6;
  float sum = 0.0f, ss = 0.0f;
  for (int dd = g * 48; dd < g * 48 + 48; ++dd) {
    float v = sY[px * 193 + dd];
    sum += v;
    ss = fmaf(v, v, ss);
  }
  sS[g][px] = sum;
  sQ[g][px] = ss;
  __syncthreads();
  sum = sS[0][px] + sS[1][px] + sS[2][px] + sS[3][px];
  ss  = sQ[0][px] + sQ[1][px] + sQ[2][px] + sQ[3][px];
  const float mu = sum * (1.0f / DIN);
  float var = ss * (1.0f / DIN) - mu * mu;
  const float rstd = rsqrtf(fmaxf(var, 0.0f) + 1e-5f);
  const float* zb = xz + ((size_t)b * 384 + DIN) * LL + p0 + px;
  float* ub = u + (size_t)b * DIN * LL + p0 + px;
  for (int dd = g * 48; dd < g * 48 + 48; ++dd) {
    float v = sY[px * 193 + dd];
    float z = zb[(size_t)dd * LL];
    float tn = fmaf((v - mu) * rstd, gamma[dd], beta[dd]);
    ub[(size_t)dd * LL] = tn * (z * sigf(z));
  }
}

// ---------------------------------------------------------------------------
extern "C" void kernel_launch(void* const* d_in, const int* in_sizes, int n_in,
                              void* d_out, int out_size, void* d_ws, size_t ws_size,
                              hipStream_t stream) {
  const float* x      = (const float*)d_in[0];
  const float* prior  = (const float*)d_in[1];
  const float* alpha  = (const float*)d_in[2];
  const float* ipw    = (const float*)d_in[3];
  const float* cw     = (const float*)d_in[4];
  const float* cb     = (const float*)d_in[5];
  const float* xpw    = (const float*)d_in[6];
  const float* dtw    = (const float*)d_in[7];
  const float* dtb    = (const float*)d_in[8];
  const float* A_logs = (const float*)d_in[9];
  const float* Ds     = (const float*)d_in[10];
  const float* onw    = (const float*)d_in[11];
  const float* onb    = (const float*)d_in[12];
  const float* opw    = (const float*)d_in[13];
  const float* w1     = (const float*)d_in[14];
  const float* b1     = (const float*)d_in[15];
  const float* bnw    = (const float*)d_in[16];
  const float* bnb    = (const float*)d_in[17];
  const float* bnm    = (const float*)d_in[18];
  const float* bnv    = (const float*)d_in[19];
  const float* w2     = (const float*)d_in[20];
  const float* b2     = (const float*)d_in[21];
  float* out = (float*)d_out;

  char* ws = (char*)d_ws;
  // Footprint ends at 114,843,648 B (< 135,266,304 proven in R2).
  float* xz    = (float*)(ws);              // [B,384,L]     50.3 MB
  float* xcT   = (float*)(ws + 50331648);   // [B,L,192]     25.2 MB (-> u after apply)
  float* ymT2  = (float*)(ws + 75497472);   // [B,L,192]     25.2 MB
  float* projS = (float*)(ws + 100663296);  // [B,K,L,8]      4.2 MB (scan order)
  float* Wgb   = (float*)(ws + 104857600);  // [B,4,L]        0.5 MB
  float* carrP = (float*)(ws + 105381888);  // [B,K,SS,192]   3.0 MB
  float* carrH = (float*)(ws + 108527616);  // [B,K,SS,192]   3.0 MB
  float* h0b   = (float*)(ws + 111673344);  // [B,K,SS,192]   3.0 MB
  float* xpwT  = (float*)(ws + 114819072);  // [K,DIN,8]      24.6 KB (ends 114843648)
  float* ymT   = xz;   // overlay: x_ssm half of xz (dead after convproj)
  float* u     = xcT;  // xcT dead after scan_apply_k

  // 1) in_proj GEMM: PX=4 (1024-px blocks, 1536 blocks, 32 acc chains)
  gemm_pix_k<CIN, 4><<<dim3(LL / 1024, 384 / 8, BB), 256, 0, stream>>>(x, ipw, xz, 384);
  // 2) prior -> direction gates  (+ weight transpose in block 0)
  p2w_k<<<(BB * LL) / 256, 256, 0, stream>>>(prior, alpha, w1, b1, bnw, bnb, bnm,
                                             bnv, w2, b2, xpw, xpwT, Wgb);
  // 3) fused dwconv+SiLU + x_proj(scan-order) + transpose (64-px, 1024 thr)
  convproj_k<<<dim3(HH, BB), 1024, 0, stream>>>(xz, cw, cb, xpwT, xcT, projS);
  // 4) scan: paired segment carries (both directions per xcT pass)
  scan_part_k<<<dim3(SS, 2, BB), 192, 0, stream>>>(xcT, projS, dtw, dtb, A_logs,
                                                   carrP, carrH);
  // 5) scan: serial carry combine
  scan_fix_k<<<dim3(KK, BB), 192, 0, stream>>>(carrP, carrH, h0b);
  // 6) scan: apply + gate + paired merge (ymT overlaid on xz x_ssm half)
  scan_apply_k<<<dim3(SS, 2, BB), 192, 0, stream>>>(xcT, projS, Wgb, h0b, dtw, dtb,
                                                    A_logs, Ds, ymT, ymT2);
  // 7) LayerNorm(channel) * silu(z)
  ln_silu_k<<<dim3(HH, BB), 256, 0, stream>>>(ymT, ymT2, xz, onw, onb, u);
  // 8) out_proj GEMM: PX=1 (256-px blocks, 1536 blocks)
  gemm_pix_k<DIN, 1><<<dim3(LL / 256, COUT / 8, BB), 256, 0, stream>>>(u, opw, out, COUT);
}

// Round 16
// 198.559 us; speedup vs baseline: 1.3963x; 1.0418x over previous
//
#include <hip/hip_runtime.h>

#define BB   8
#define CIN  96
#define DIN  192
#define HH   64
#define WW   64
#define LL   4096
#define KK   4
#define COUT 96
#define SS   128  // scan segments
#define LC   32   // segment length = LL/SS

#define LOG2E 1.4426950408889634f
#define LN2   0.6931471805599453f

__device__ __forceinline__ float exp2fast(float x) { return __builtin_amdgcn_exp2f(x); }
__device__ __forceinline__ float log2fast(float x) { return __builtin_amdgcn_logf(x); }
__device__ __forceinline__ float sigf(float x) { return 1.0f / (1.0f + __expf(-x)); }
__device__ __forceinline__ int trp(int p) { return ((p & 63) << 6) | (p >> 6); }
__device__ __forceinline__ int pix_of(int k, int l) {
  if (k == 0) return l;
  if (k == 1) return trp(l);
  if (k == 2) return LL - 1 - l;
  return trp(LL - 1 - l);
}

// ---------------------------------------------------------------------------
// Per-pixel GEMM v4: 4 CONSECUTIVE px/thread via float4 loads/stores; OT
// outputs/thread; weights block-uniform (SGPR s_load). Bit-identical c-order.
// ---------------------------------------------------------------------------
template <int C, int OT>
__global__ __launch_bounds__(256) void gemm_pix_k(const float* __restrict__ in,
                                                  const float* __restrict__ W,
                                                  float* __restrict__ out, int O) {
  const int tid = threadIdx.x;
  const int b  = blockIdx.z;
  const int o0 = blockIdx.y * OT;
  const int p0 = blockIdx.x * 1024 + tid * 4;
  const float* inb = in + (size_t)b * C * LL + p0;
  const float* Wb  = W + (size_t)o0 * C;   // block-uniform -> scalar loads
  float4 acc[OT];
#pragma unroll
  for (int j = 0; j < OT; ++j) acc[j] = make_float4(0.f, 0.f, 0.f, 0.f);
#pragma unroll 2
  for (int c = 0; c < C; c += 4) {
    float4 w[OT];
#pragma unroll
    for (int j = 0; j < OT; ++j) w[j] = *(const float4*)&Wb[j * C + c];
    float4 xv[4];
#pragma unroll
    for (int t = 0; t < 4; ++t) xv[t] = *(const float4*)&inb[(size_t)(c + t) * LL];
#pragma unroll
    for (int j = 0; j < OT; ++j) {
#pragma unroll
      for (int t = 0; t < 4; ++t) {
        const float ws = t == 0 ? w[j].x : t == 1 ? w[j].y : t == 2 ? w[j].z : w[j].w;
        acc[j].x = fmaf(xv[t].x, ws, acc[j].x);
        acc[j].y = fmaf(xv[t].y, ws, acc[j].y);
        acc[j].z = fmaf(xv[t].z, ws, acc[j].z);
        acc[j].w = fmaf(xv[t].w, ws, acc[j].w);
      }
    }
  }
  float* ob = out + (size_t)b * O * LL + p0;
#pragma unroll
  for (int j = 0; j < OT; ++j) *(float4*)&ob[(size_t)(o0 + j) * LL] = acc[j];
}

// ---------------------------------------------------------------------------
// PriorToWeights MLP -> Wg[B,4,L].  Block 0: transpose xpw -> xpwT[k][dd][8].
// ---------------------------------------------------------------------------
__global__ __launch_bounds__(256) void p2w_k(const float* __restrict__ prior,
                                             const float* __restrict__ alpha,
                                             const float* __restrict__ w1,
                                             const float* __restrict__ b1,
                                             const float* __restrict__ bnw,
                                             const float* __restrict__ bnb,
                                             const float* __restrict__ bnm,
                                             const float* __restrict__ bnv,
                                             const float* __restrict__ w2,
                                             const float* __restrict__ b2,
                                             const float* __restrict__ xpw,
                                             float* __restrict__ xpwT,
                                             float* __restrict__ Wg) {
  if (blockIdx.x == 0) {
    for (int idx = threadIdx.x; idx < KK * DIN * 8; idx += 256) {
      int kk = idx / (DIN * 8);
      int rem = idx % (DIN * 8);
      int dd = rem >> 3, c = rem & 7;
      xpwT[idx] = xpw[(kk * 8 + c) * DIN + dd];
    }
  }
  int idx = blockIdx.x * 256 + threadIdx.x;
  int p = idx & (LL - 1);
  int b = idx >> 12;
  float pr[4];
#pragma unroll
  for (int c = 0; c < 4; ++c) pr[c] = prior[((size_t)b * 4 + c) * LL + p];
  float s = sigf(alpha[0]);
  float g2[4];
#pragma unroll
  for (int j = 0; j < 4; ++j) g2[j] = b2[j];
  for (int o = 0; o < 32; ++o) {
    float g = b1[o];
#pragma unroll
    for (int c = 0; c < 4; ++c) g = fmaf(pr[c], w1[o * 4 + c], g);
    g = (g - bnm[o]) * rsqrtf(bnv[o] + 1e-5f) * bnw[o] + bnb[o];
    g = fmaxf(g, 0.0f);
#pragma unroll
    for (int j = 0; j < 4; ++j) g2[j] = fmaf(g, w2[j * 32 + o], g2[j]);
  }
#pragma unroll
  for (int j = 0; j < 4; ++j)
    Wg[((size_t)b * 4 + j) * LL + p] = 1.0f + s * (sigf(g2[j]) - 1.0f);
}

// ---------------------------------------------------------------------------
// FUSED conv+proj v5: 64-px row tiles, 1024 threads (32 waves/CU).
// ---------------------------------------------------------------------------
__global__ __launch_bounds__(1024) void convproj_k(const float* __restrict__ xz,
                                                   const float* __restrict__ cw,
                                                   const float* __restrict__ cb,
                                                   const float* __restrict__ xpwT,
                                                   float* __restrict__ xcT,
                                                   float* __restrict__ projS) {
  __shared__ float sX[96 * 65];   // 24.96 KB
  __shared__ float4 sP[512];      // 8 KB q-partials
  const int tid = threadIdx.x;
  const int b = blockIdx.y;
  const int h = blockIdx.x;
  const int px = tid & 63;
  const int ku = __builtin_amdgcn_readfirstlane((tid >> 6) & 3);
  const int hf = __builtin_amdgcn_readfirstlane((tid >> 8) & 1);
  const int q  = __builtin_amdgcn_readfirstlane(tid >> 9);
  float a0 = 0.0f, a1 = 0.0f, a2 = 0.0f, a3 = 0.0f;

#pragma unroll
  for (int half = 0; half < 2; ++half) {
    for (int idx = tid; idx < 96 * 64; idx += 1024) {
      int ddl = idx >> 6, pxx = idx & 63;
      int dd = half * 96 + ddl;
      const float* xp = xz + ((size_t)b * 384 + dd) * LL + h * 64 + pxx;
      const float* wp = cw + dd * 9;
      float s = cb[dd];
#pragma unroll
      for (int dh = -1; dh <= 1; ++dh) {
        int hh = h + dh;
        if (hh < 0 || hh >= HH) continue;
        const float* row = xp + dh * 64;
        float c0 = wp[(dh + 1) * 3], c1 = wp[(dh + 1) * 3 + 1], c2 = wp[(dh + 1) * 3 + 2];
        if (pxx > 0) s = fmaf(row[-1], c0, s);
        s = fmaf(row[0], c1, s);
        if (pxx < 63) s = fmaf(row[1], c2, s);
      }
      sX[ddl * 65 + pxx] = s * sigf(s);
    }
    __syncthreads();
    for (int idx = tid; idx < 64 * 96; idx += 1024) {
      int pp = idx / 96, ddl = idx % 96;
      xcT[((size_t)b * LL + h * 64 + pp) * DIN + half * 96 + ddl] = sX[ddl * 65 + pp];
    }
    {
      const int ddl0 = q * 48;
      const float* wp = xpwT + (size_t)ku * (DIN * 8) + (half * 96 + ddl0) * 8 + hf * 4;
#pragma unroll 8
      for (int d48 = 0; d48 < 48; ++d48) {
        float xv = sX[(ddl0 + d48) * 65 + px];
        const float4 w4 = *(const float4*)(wp + d48 * 8);
        a0 = fmaf(xv, w4.x, a0);
        a1 = fmaf(xv, w4.y, a1);
        a2 = fmaf(xv, w4.z, a2);
        a3 = fmaf(xv, w4.w, a3);
      }
    }
    __syncthreads();
  }
  const int slot = tid & 511;
  if (q == 1) sP[slot] = make_float4(a0, a1, a2, a3);
  __syncthreads();
  if (q == 0) {
    float4 o = sP[slot];
    a0 += o.x; a1 += o.y; a2 += o.z; a3 += o.w;
    const int p = h * 64 + px;
    int l;
    if (ku == 0) l = p;
    else if (ku == 1) l = trp(p);
    else if (ku == 2) l = LL - 1 - p;
    else l = LL - 1 - trp(p);
    float* pb = projS + (((size_t)b * KK + ku) * LL + l) * 8 + hf * 4;
    *(float4*)pb = make_float4(a0, a1, a2, a3);
  }
}

// ---------------------------------------------------------------------------
// Scan pass 1 (PAIRED): one xcT pass computes carries for BOTH opposite
// directions. Forward kA: H=aH+b, P*=a. Reverse kB: H += P*b, P *= a.
// ---------------------------------------------------------------------------
__global__ __launch_bounds__(192) void scan_part_k(const float* __restrict__ xcT,
                                                   const float* __restrict__ projS,
                                                   const float* __restrict__ dtw,
                                                   const float* __restrict__ dtb,
                                                   const float* __restrict__ A_logs,
                                                   float* __restrict__ carrP,
                                                   float* __restrict__ carrH) {
  const int s = blockIdx.x, kp = blockIdx.y, b = blockIdx.z;
  const int d = threadIdx.x;
  const int kA = kp, kB = kp + 2;
  const int s2 = SS - 1 - s;
  const int kdA = kA * DIN + d, kdB = kB * DIN + d;
  float wrA[6], wrB[6];
#pragma unroll
  for (int r = 0; r < 6; ++r) { wrA[r] = dtw[kdA * 6 + r]; wrB[r] = dtw[kdB * 6 + r]; }
  const float biasA = dtb[kdA], biasB = dtb[kdB];
  const float AaA = -__expf(A_logs[kdA]), AaB = -__expf(A_logs[kdB]);
  const int l0 = s * LC;
  const int p0 = pix_of(kA, l0);
  const int dp = pix_of(kA, l0 + 1) - p0;
  const float* xp = xcT + ((size_t)b * LL + p0) * DIN + d;
  const long xstep = (long)dp * DIN;
  const float* prA = projS + (((size_t)b * KK + kA) * LL + l0) * 8;
  const float* prB = projS + (((size_t)b * KK + kB) * LL + s2 * LC + (LC - 1)) * 8;
  float PA = 1.0f, HA = 0.0f, PB = 1.0f, HB = 0.0f;
#pragma unroll 2
  for (int j = 0; j < LC; ++j) {
    float4 a0 = *(const float4*)prA;
    float4 a1 = *(const float4*)(prA + 4);
    prA += 8;
    float4 b0 = *(const float4*)prB;
    float4 b1 = *(const float4*)(prB + 4);
    prB -= 8;
    float xv = *xp;
    xp += xstep;
    {
      float dtr = biasA;
      dtr = fmaf(a0.x, wrA[0], dtr);
      dtr = fmaf(a0.y, wrA[1], dtr);
      dtr = fmaf(a0.z, wrA[2], dtr);
      dtr = fmaf(a0.w, wrA[3], dtr);
      dtr = fmaf(a1.x, wrA[4], dtr);
      dtr = fmaf(a1.y, wrA[5], dtr);
      float e = exp2fast(fminf(dtr, 80.0f) * LOG2E);
      float u = log2fast(1.0f + e);
      float a = exp2fast(u * AaA);
      float dt = u * LN2;
      HA = fmaf(a, HA, dt * a1.z * xv);
      PA *= a;
    }
    {
      float dtr = biasB;
      dtr = fmaf(b0.x, wrB[0], dtr);
      dtr = fmaf(b0.y, wrB[1], dtr);
      dtr = fmaf(b0.z, wrB[2], dtr);
      dtr = fmaf(b0.w, wrB[3], dtr);
      dtr = fmaf(b1.x, wrB[4], dtr);
      dtr = fmaf(b1.y, wrB[5], dtr);
      float e = exp2fast(fminf(dtr, 80.0f) * LOG2E);
      float u = log2fast(1.0f + e);
      float a = exp2fast(u * AaB);
      float dt = u * LN2;
      HB = fmaf(PB, dt * b1.z * xv, HB);
      PB *= a;
    }
  }
  size_t oA = ((size_t)((b * KK + kA) * SS + s)) * DIN + d;
  size_t oB = ((size_t)((b * KK + kB) * SS + s2)) * DIN + d;
  carrP[oA] = PA;
  carrH[oA] = HA;
  carrP[oB] = PB;
  carrH[oB] = HB;
}

// ---------------------------------------------------------------------------
// Scan pass 2: serial combine of SS carries -> per-segment initial state h0
// ---------------------------------------------------------------------------
__global__ __launch_bounds__(192) void scan_fix_k(const float* __restrict__ carrP,
                                                  const float* __restrict__ carrH,
                                                  float* __restrict__ h0) {
  const int k = blockIdx.x, b = blockIdx.y, d = threadIdx.x;
  size_t base = ((size_t)(b * KK + k)) * SS * DIN + d;
  float h = 0.0f;
#pragma unroll 4
  for (int s = 0; s < SS; ++s) {
    h0[base + (size_t)s * DIN] = h;
    h = fmaf(carrP[base + (size_t)s * DIN], h, carrH[base + (size_t)s * DIN]);
  }
}

// ---------------------------------------------------------------------------
// Scan pass 3: apply + gate + paired-direction merge via 24 KB LDS.
// ---------------------------------------------------------------------------
__global__ __launch_bounds__(192) void scan_apply_k(const float* __restrict__ xcT,
                                                    const float* __restrict__ projS,
                                                    const float* __restrict__ Wg,
                                                    const float* __restrict__ h0,
                                                    const float* __restrict__ dtw,
                                                    const float* __restrict__ dtb,
                                                    const float* __restrict__ A_logs,
                                                    const float* __restrict__ Ds,
                                                    float* __restrict__ ymT,
                                                    float* __restrict__ ymT2) {
  const int s = blockIdx.x, kp = blockIdx.y, b = blockIdx.z;
  const int d = threadIdx.x;
  __shared__ float sAcc[LC * DIN];  // 24 KB, column d thread-private
  {
    const int k = kp, kd = k * DIN + d;
    float wr[6];
#pragma unroll
    for (int r = 0; r < 6; ++r) wr[r] = dtw[kd * 6 + r];
    const float bias = dtb[kd];
    const float Aa = -__expf(A_logs[kd]);
    const float Dv = Ds[kd];
    const int l0 = s * LC;
    const int p0 = pix_of(k, l0);
    const int dp = pix_of(k, l0 + 1) - p0;
    const float* xp = xcT + ((size_t)b * LL + p0) * DIN + d;
    const long xstep = (long)dp * DIN;
    const float* pr = projS + (((size_t)b * KK + k) * LL + l0) * 8;
    const float* wg = Wg + ((size_t)b * KK + k) * LL + l0;
    float h = h0[((size_t)((b * KK + k) * SS + s)) * DIN + d];
#pragma unroll 4
    for (int j = 0; j < LC; ++j) {
      float4 q0 = *(const float4*)pr;
      float4 q1 = *(const float4*)(pr + 4);
      pr += 8;
      float xv = *xp;
      xp += xstep;
      float dtr = bias;
      dtr = fmaf(q0.x, wr[0], dtr);
      dtr = fmaf(q0.y, wr[1], dtr);
      dtr = fmaf(q0.z, wr[2], dtr);
      dtr = fmaf(q0.w, wr[3], dtr);
      dtr = fmaf(q1.x, wr[4], dtr);
      dtr = fmaf(q1.y, wr[5], dtr);
      float e = exp2fast(fminf(dtr, 80.0f) * LOG2E);
      float u = log2fast(1.0f + e);
      float a = exp2fast(u * Aa);
      float dt = u * LN2;
      h = fmaf(a, h, dt * q1.z * xv);
      sAcc[j * DIN + d] = fmaf(h, q1.w, Dv * xv) * wg[j];
    }
  }
  {
    const int k = kp + 2, kd = k * DIN + d;
    const int s2 = SS - 1 - s;
    float wr[6];
#pragma unroll
    for (int r = 0; r < 6; ++r) wr[r] = dtw[kd * 6 + r];
    const float bias = dtb[kd];
    const float Aa = -__expf(A_logs[kd]);
    const float Dv = Ds[kd];
    const int l0 = s2 * LC;
    const int p0 = pix_of(k, l0);
    const int dp = pix_of(k, l0 + 1) - p0;
    const float* xp = xcT + ((size_t)b * LL + p0) * DIN + d;
    const long xstep = (long)dp * DIN;
    const float* pr = projS + (((size_t)b * KK + k) * LL + l0) * 8;
    const float* wg = Wg + ((size_t)b * KK + k) * LL + l0;
    float h = h0[((size_t)((b * KK + k) * SS + s2)) * DIN + d];
#pragma unroll 4
    for (int j = 0; j < LC; ++j) {
      float4 q0 = *(const float4*)pr;
      float4 q1 = *(const float4*)(pr + 4);
      pr += 8;
      float xv = *xp;
      xp += xstep;
      float dtr = bias;
      dtr = fmaf(q0.x, wr[0], dtr);
      dtr = fmaf(q0.y, wr[1], dtr);
      dtr = fmaf(q0.z, wr[2], dtr);
      dtr = fmaf(q0.w, wr[3], dtr);
      dtr = fmaf(q1.x, wr[4], dtr);
      dtr = fmaf(q1.y, wr[5], dtr);
      float e = exp2fast(fminf(dtr, 80.0f) * LOG2E);
      float u = log2fast(1.0f + e);
      float a = exp2fast(u * Aa);
      float dt = u * LN2;
      h = fmaf(a, h, dt * q1.z * xv);
      float y = fmaf(h, q1.w, Dv * xv) * wg[j];
      sAcc[(LC - 1 - j) * DIN + d] += y;
    }
  }
  float* dst;
  if (kp == 0)
    dst = ymT + (size_t)b * (384 * (size_t)LL) + (size_t)(s * LC) * DIN + d;  // xz overlay
  else
    dst = ymT2 + ((size_t)b * LL + s * LC) * DIN + d;
#pragma unroll 4
  for (int j = 0; j < LC; ++j) dst[(size_t)j * DIN] = sAcc[j * DIN + d];
}

// ---------------------------------------------------------------------------
// LayerNorm(channel) * silu(z): reads ymT(overlay)[p,:] + ymT2[tr(p),:], writes u
// ---------------------------------------------------------------------------
__global__ __launch_bounds__(256) void ln_silu_k(const float* __restrict__ ymT,
                                                 const float* __restrict__ ymT2,
                                                 const float* __restrict__ xz,
                                                 const float* __restrict__ gamma,
                                                 const float* __restrict__ beta,
                                                 float* __restrict__ u) {
  const int b = blockIdx.y;
  const int h = blockIdx.x;
  const int p0 = h * 64;
  __shared__ float sY[64 * 193];
  __shared__ float sS[4][64], sQ[4][64];
  const int tid = threadIdx.x;
  const float* ymb = ymT + (size_t)b * (384 * (size_t)LL);  // xz overlay
  for (int idx = tid; idx < 64 * DIN; idx += 256) {
    int pp = idx / DIN, dd = idx % DIN;
    float v = ymb[(size_t)(p0 + pp) * DIN + dd] +
              ymT2[((size_t)b * LL + pp * 64 + h) * DIN + dd];
    sY[pp * 193 + dd] = v;
  }
  __syncthreads();
  const int px = tid & 63, g = tid >> 6;
  float sum = 0.0f, ss = 0.0f;
  for (int dd = g * 48; dd < g * 48 + 48; ++dd) {
    float v = sY[px * 193 + dd];
    sum += v;
    ss = fmaf(v, v, ss);
  }
  sS[g][px] = sum;
  sQ[g][px] = ss;
  __syncthreads();
  sum = sS[0][px] + sS[1][px] + sS[2][px] + sS[3][px];
  ss  = sQ[0][px] + sQ[1][px] + sQ[2][px] + sQ[3][px];
  const float mu = sum * (1.0f / DIN);
  float var = ss * (1.0f / DIN) - mu * mu;
  const float rstd = rsqrtf(fmaxf(var, 0.0f) + 1e-5f);
  const float* zb = xz + ((size_t)b * 384 + DIN) * LL + p0 + px;
  float* ub = u + (size_t)b * DIN * LL + p0 + px;
  for (int dd = g * 48; dd < g * 48 + 48; ++dd) {
    float v = sY[px * 193 + dd];
    float z = zb[(size_t)dd * LL];
    float tn = fmaf((v - mu) * rstd, gamma[dd], beta[dd]);
    ub[(size_t)dd * LL] = tn * (z * sigf(z));
  }
}

// ---------------------------------------------------------------------------
extern "C" void kernel_launch(void* const* d_in, const int* in_sizes, int n_in,
                              void* d_out, int out_size, void* d_ws, size_t ws_size,
                              hipStream_t stream) {
  const float* x      = (const float*)d_in[0];
  const float* prior  = (const float*)d_in[1];
  const float* alpha  = (const float*)d_in[2];
  const float* ipw    = (const float*)d_in[3];
  const float* cw     = (const float*)d_in[4];
  const float* cb     = (const float*)d_in[5];
  const float* xpw    = (const float*)d_in[6];
  const float* dtw    = (const float*)d_in[7];
  const float* dtb    = (const float*)d_in[8];
  const float* A_logs = (const float*)d_in[9];
  const float* Ds     = (const float*)d_in[10];
  const float* onw    = (const float*)d_in[11];
  const float* onb    = (const float*)d_in[12];
  const float* opw    = (const float*)d_in[13];
  const float* w1     = (const float*)d_in[14];
  const float* b1     = (const float*)d_in[15];
  const float* bnw    = (const float*)d_in[16];
  const float* bnb    = (const float*)d_in[17];
  const float* bnm    = (const float*)d_in[18];
  const float* bnv    = (const float*)d_in[19];
  const float* w2     = (const float*)d_in[20];
  const float* b2     = (const float*)d_in[21];
  float* out = (float*)d_out;

  char* ws = (char*)d_ws;
  // Footprint ends at 114,843,648 B (< 135,266,304 proven in R2).
  float* xz    = (float*)(ws);              // [B,384,L]     50.3 MB
  float* xcT   = (float*)(ws + 50331648);   // [B,L,192]     25.2 MB (-> u after apply)
  float* ymT2  = (float*)(ws + 75497472);   // [B,L,192]     25.2 MB
  float* projS = (float*)(ws + 100663296);  // [B,K,L,8]      4.2 MB (scan order)
  float* Wgb   = (float*)(ws + 104857600);  // [B,4,L]        0.5 MB
  float* carrP = (float*)(ws + 105381888);  // [B,K,SS,192]   3.0 MB
  float* carrH = (float*)(ws + 108527616);  // [B,K,SS,192]   3.0 MB
  float* h0b   = (float*)(ws + 111673344);  // [B,K,SS,192]   3.0 MB
  float* xpwT  = (float*)(ws + 114819072);  // [K,DIN,8]      24.6 KB (ends 114843648)
  float* ymT   = xz;   // overlay: x_ssm half of xz (dead after convproj)
  float* u     = xcT;  // xcT dead after scan_apply_k

  // 1) in_proj GEMM: OT=8, float4 px (1536 blocks)
  gemm_pix_k<CIN, 8><<<dim3(LL / 1024, 384 / 8, BB), 256, 0, stream>>>(x, ipw, xz, 384);
  // 2) prior -> direction gates  (+ weight transpose in block 0)
  p2w_k<<<(BB * LL) / 256, 256, 0, stream>>>(prior, alpha, w1, b1, bnw, bnb, bnm,
                                             bnv, w2, b2, xpw, xpwT, Wgb);
  // 3) fused dwconv+SiLU + x_proj(scan-order) + transpose (64-px, 1024 thr)
  convproj_k<<<dim3(HH, BB), 1024, 0, stream>>>(xz, cw, cb, xpwT, xcT, projS);
  // 4) scan: paired segment carries (both directions per xcT pass)
  scan_part_k<<<dim3(SS, 2, BB), 192, 0, stream>>>(xcT, projS, dtw, dtb, A_logs,
                                                   carrP, carrH);
  // 5) scan: serial carry combine
  scan_fix_k<<<dim3(KK, BB), 192, 0, stream>>>(carrP, carrH, h0b);
  // 6) scan: apply + gate + paired merge (ymT overlaid on xz x_ssm half)
  scan_apply_k<<<dim3(SS, 2, BB), 192, 0, stream>>>(xcT, projS, Wgb, h0b, dtw, dtb,
                                                    A_logs, Ds, ymT, ymT2);
  // 7) LayerNorm(channel) * silu(z)
  ln_silu_k<<<dim3(HH, BB), 256, 0, stream>>>(ymT, ymT2, xz, onw, onb, u);
  // 8) out_proj GEMM: OT=4, float4 px (768 blocks)
  gemm_pix_k<DIN, 4><<<dim3(LL / 1024, COUT / 4, BB), 256, 0, stream>>>(u, opw, out, COUT);
}

// Round 17
// 187.021 us; speedup vs baseline: 1.4825x; 1.0617x over previous
//
#include <hip/hip_runtime.h>

#define BB   8
#define CIN  96
#define DIN  192
#define HH   64
#define WW   64
#define LL   4096
#define KK   4
#define COUT 96
#define SS   128  // scan segments
#define LC   32   // segment length = LL/SS

#define LOG2E 1.4426950408889634f
#define LN2   0.6931471805599453f

__device__ __forceinline__ float exp2fast(float x) { return __builtin_amdgcn_exp2f(x); }
__device__ __forceinline__ float log2fast(float x) { return __builtin_amdgcn_logf(x); }
__device__ __forceinline__ float sigf(float x) { return 1.0f / (1.0f + __expf(-x)); }
__device__ __forceinline__ int trp(int p) { return ((p & 63) << 6) | (p >> 6); }
__device__ __forceinline__ int pix_of(int k, int l) {
  if (k == 0) return l;
  if (k == 1) return trp(l);
  if (k == 2) return LL - 1 - l;
  return trp(LL - 1 - l);
}

// ---------------------------------------------------------------------------
// Per-pixel GEMM: 4 consecutive px/thread (float4), OT outputs; weights
// block-uniform (SGPR s_load). Bit-identical c-order per output.
// ---------------------------------------------------------------------------
template <int C, int OT>
__global__ __launch_bounds__(256) void gemm_pix_k(const float* __restrict__ in,
                                                  const float* __restrict__ W,
                                                  float* __restrict__ out, int O) {
  const int tid = threadIdx.x;
  const int b  = blockIdx.z;
  const int o0 = blockIdx.y * OT;
  const int p0 = blockIdx.x * 1024 + tid * 4;
  const float* inb = in + (size_t)b * C * LL + p0;
  const float* Wb  = W + (size_t)o0 * C;   // block-uniform -> scalar loads
  float4 acc[OT];
#pragma unroll
  for (int j = 0; j < OT; ++j) acc[j] = make_float4(0.f, 0.f, 0.f, 0.f);
#pragma unroll 4
  for (int c = 0; c < C; c += 4) {
    float4 w[OT];
#pragma unroll
    for (int j = 0; j < OT; ++j) w[j] = *(const float4*)&Wb[j * C + c];
    float4 xv[4];
#pragma unroll
    for (int t = 0; t < 4; ++t) xv[t] = *(const float4*)&inb[(size_t)(c + t) * LL];
#pragma unroll
    for (int j = 0; j < OT; ++j) {
#pragma unroll
      for (int t = 0; t < 4; ++t) {
        const float ws = t == 0 ? w[j].x : t == 1 ? w[j].y : t == 2 ? w[j].z : w[j].w;
        acc[j].x = fmaf(xv[t].x, ws, acc[j].x);
        acc[j].y = fmaf(xv[t].y, ws, acc[j].y);
        acc[j].z = fmaf(xv[t].z, ws, acc[j].z);
        acc[j].w = fmaf(xv[t].w, ws, acc[j].w);
      }
    }
  }
  float* ob = out + (size_t)b * O * LL + p0;
#pragma unroll
  for (int j = 0; j < OT; ++j) *(float4*)&ob[(size_t)(o0 + j) * LL] = acc[j];
}

// ---------------------------------------------------------------------------
// PriorToWeights MLP -> Wg[B,4,L].  Block 0: transpose xpw -> xpwT[k][dd][8].
// ---------------------------------------------------------------------------
__global__ __launch_bounds__(256) void p2w_k(const float* __restrict__ prior,
                                             const float* __restrict__ alpha,
                                             const float* __restrict__ w1,
                                             const float* __restrict__ b1,
                                             const float* __restrict__ bnw,
                                             const float* __restrict__ bnb,
                                             const float* __restrict__ bnm,
                                             const float* __restrict__ bnv,
                                             const float* __restrict__ w2,
                                             const float* __restrict__ b2,
                                             const float* __restrict__ xpw,
                                             float* __restrict__ xpwT,
                                             float* __restrict__ Wg) {
  if (blockIdx.x == 0) {
    for (int idx = threadIdx.x; idx < KK * DIN * 8; idx += 256) {
      int kk = idx / (DIN * 8);
      int rem = idx % (DIN * 8);
      int dd = rem >> 3, c = rem & 7;
      xpwT[idx] = xpw[(kk * 8 + c) * DIN + dd];
    }
  }
  int idx = blockIdx.x * 256 + threadIdx.x;
  int p = idx & (LL - 1);
  int b = idx >> 12;
  float pr[4];
#pragma unroll
  for (int c = 0; c < 4; ++c) pr[c] = prior[((size_t)b * 4 + c) * LL + p];
  float s = sigf(alpha[0]);
  float g2[4];
#pragma unroll
  for (int j = 0; j < 4; ++j) g2[j] = b2[j];
  for (int o = 0; o < 32; ++o) {
    float g = b1[o];
#pragma unroll
    for (int c = 0; c < 4; ++c) g = fmaf(pr[c], w1[o * 4 + c], g);
    g = (g - bnm[o]) * rsqrtf(bnv[o] + 1e-5f) * bnw[o] + bnb[o];
    g = fmaxf(g, 0.0f);
#pragma unroll
    for (int j = 0; j < 4; ++j) g2[j] = fmaf(g, w2[j * 32 + o], g2[j]);
  }
#pragma unroll
  for (int j = 0; j < 4; ++j)
    Wg[((size_t)b * 4 + j) * LL + p] = 1.0f + s * (sigf(g2[j]) - 1.0f);
}

// ---------------------------------------------------------------------------
// FUSED conv+proj v6: 64-px row tiles, 1024 threads; conv vectorized
// (float4 + 2 edge scalars per row -> 4 px per thread-iteration).
// ---------------------------------------------------------------------------
__global__ __launch_bounds__(1024) void convproj_k(const float* __restrict__ xz,
                                                   const float* __restrict__ cw,
                                                   const float* __restrict__ cb,
                                                   const float* __restrict__ xpwT,
                                                   float* __restrict__ xcT,
                                                   float* __restrict__ projS) {
  __shared__ float sX[96 * 65];   // 24.96 KB
  __shared__ float4 sP[512];      // 8 KB q-partials
  const int tid = threadIdx.x;
  const int b = blockIdx.y;
  const int h = blockIdx.x;
  const int px = tid & 63;
  const int ku = __builtin_amdgcn_readfirstlane((tid >> 6) & 3);
  const int hf = __builtin_amdgcn_readfirstlane((tid >> 8) & 1);
  const int q  = __builtin_amdgcn_readfirstlane(tid >> 9);
  float a0 = 0.0f, a1 = 0.0f, a2 = 0.0f, a3 = 0.0f;

#pragma unroll
  for (int half = 0; half < 2; ++half) {
    // conv + bias + SiLU: 4 consecutive px per thread-iteration, vector loads
    for (int idx = tid; idx < 96 * 16; idx += 1024) {
      int ddl = idx >> 4, pq = idx & 15;
      int w0 = pq * 4;
      int dd = half * 96 + ddl;
      const float* base = xz + ((size_t)b * 384 + dd) * LL + h * 64 + w0;
      const float* wp = cw + dd * 9;
      float bv = cb[dd];
      float s0 = bv, s1 = bv, s2 = bv, s3 = bv;
#pragma unroll
      for (int dh = -1; dh <= 1; ++dh) {
        int hh = h + dh;
        if (hh < 0 || hh >= HH) continue;
        const float* row = base + dh * 64;
        float4 cm = *(const float4*)row;
        float lf = (w0 > 0)  ? row[-1] : 0.0f;   // fmaf(0,c,s)=s == skipped tap
        float rt = (w0 < 60) ? row[4]  : 0.0f;
        float c0 = wp[(dh + 1) * 3], c1 = wp[(dh + 1) * 3 + 1], c2 = wp[(dh + 1) * 3 + 2];
        s0 = fmaf(lf,   c0, s0); s0 = fmaf(cm.x, c1, s0); s0 = fmaf(cm.y, c2, s0);
        s1 = fmaf(cm.x, c0, s1); s1 = fmaf(cm.y, c1, s1); s1 = fmaf(cm.z, c2, s1);
        s2 = fmaf(cm.y, c0, s2); s2 = fmaf(cm.z, c1, s2); s2 = fmaf(cm.w, c2, s2);
        s3 = fmaf(cm.z, c0, s3); s3 = fmaf(cm.w, c1, s3); s3 = fmaf(rt,   c2, s3);
      }
      float* so = &sX[ddl * 65 + w0];
      so[0] = s0 * sigf(s0);
      so[1] = s1 * sigf(s1);
      so[2] = s2 * sigf(s2);
      so[3] = s3 * sigf(s3);
    }
    __syncthreads();
    for (int idx = tid; idx < 64 * 96; idx += 1024) {
      int pp = idx / 96, ddl = idx % 96;
      xcT[((size_t)b * LL + h * 64 + pp) * DIN + half * 96 + ddl] = sX[ddl * 65 + pp];
    }
    {
      const int ddl0 = q * 48;
      const float* wp = xpwT + (size_t)ku * (DIN * 8) + (half * 96 + ddl0) * 8 + hf * 4;
#pragma unroll 8
      for (int d48 = 0; d48 < 48; ++d48) {
        float xv = sX[(ddl0 + d48) * 65 + px];
        const float4 w4 = *(const float4*)(wp + d48 * 8);
        a0 = fmaf(xv, w4.x, a0);
        a1 = fmaf(xv, w4.y, a1);
        a2 = fmaf(xv, w4.z, a2);
        a3 = fmaf(xv, w4.w, a3);
      }
    }
    __syncthreads();
  }
  const int slot = tid & 511;
  if (q == 1) sP[slot] = make_float4(a0, a1, a2, a3);
  __syncthreads();
  if (q == 0) {
    float4 o = sP[slot];
    a0 += o.x; a1 += o.y; a2 += o.z; a3 += o.w;
    const int p = h * 64 + px;
    int l;
    if (ku == 0) l = p;
    else if (ku == 1) l = trp(p);
    else if (ku == 2) l = LL - 1 - p;
    else l = LL - 1 - trp(p);
    float* pb = projS + (((size_t)b * KK + ku) * LL + l) * 8 + hf * 4;
    *(float4*)pb = make_float4(a0, a1, a2, a3);
  }
}

// ---------------------------------------------------------------------------
// Scan pass 1 (PAIRED): one xcT pass computes carries for BOTH opposite
// directions. Forward kA: H=aH+b, P*=a. Reverse kB: H += P*b, P *= a.
// ---------------------------------------------------------------------------
__global__ __launch_bounds__(192) void scan_part_k(const float* __restrict__ xcT,
                                                   const float* __restrict__ projS,
                                                   const float* __restrict__ dtw,
                                                   const float* __restrict__ dtb,
                                                   const float* __restrict__ A_logs,
                                                   float* __restrict__ carrP,
                                                   float* __restrict__ carrH) {
  const int s = blockIdx.x, kp = blockIdx.y, b = blockIdx.z;
  const int d = threadIdx.x;
  const int kA = kp, kB = kp + 2;
  const int s2 = SS - 1 - s;
  const int kdA = kA * DIN + d, kdB = kB * DIN + d;
  float wrA[6], wrB[6];
#pragma unroll
  for (int r = 0; r < 6; ++r) { wrA[r] = dtw[kdA * 6 + r]; wrB[r] = dtw[kdB * 6 + r]; }
  const float biasA = dtb[kdA], biasB = dtb[kdB];
  const float AaA = -__expf(A_logs[kdA]), AaB = -__expf(A_logs[kdB]);
  const int l0 = s * LC;
  const int p0 = pix_of(kA, l0);
  const int dp = pix_of(kA, l0 + 1) - p0;
  const float* xp = xcT + ((size_t)b * LL + p0) * DIN + d;
  const long xstep = (long)dp * DIN;
  const float* prA = projS + (((size_t)b * KK + kA) * LL + l0) * 8;
  const float* prB = projS + (((size_t)b * KK + kB) * LL + s2 * LC + (LC - 1)) * 8;
  float PA = 1.0f, HA = 0.0f, PB = 1.0f, HB = 0.0f;
#pragma unroll 2
  for (int j = 0; j < LC; ++j) {
    float4 a0 = *(const float4*)prA;
    float4 a1 = *(const float4*)(prA + 4);
    prA += 8;
    float4 b0 = *(const float4*)prB;
    float4 b1 = *(const float4*)(prB + 4);
    prB -= 8;
    float xv = *xp;
    xp += xstep;
    {
      float dtr = biasA;
      dtr = fmaf(a0.x, wrA[0], dtr);
      dtr = fmaf(a0.y, wrA[1], dtr);
      dtr = fmaf(a0.z, wrA[2], dtr);
      dtr = fmaf(a0.w, wrA[3], dtr);
      dtr = fmaf(a1.x, wrA[4], dtr);
      dtr = fmaf(a1.y, wrA[5], dtr);
      float e = exp2fast(fminf(dtr, 80.0f) * LOG2E);
      float u = log2fast(1.0f + e);
      float a = exp2fast(u * AaA);
      float dt = u * LN2;
      HA = fmaf(a, HA, dt * a1.z * xv);
      PA *= a;
    }
    {
      float dtr = biasB;
      dtr = fmaf(b0.x, wrB[0], dtr);
      dtr = fmaf(b0.y, wrB[1], dtr);
      dtr = fmaf(b0.z, wrB[2], dtr);
      dtr = fmaf(b0.w, wrB[3], dtr);
      dtr = fmaf(b1.x, wrB[4], dtr);
      dtr = fmaf(b1.y, wrB[5], dtr);
      float e = exp2fast(fminf(dtr, 80.0f) * LOG2E);
      float u = log2fast(1.0f + e);
      float a = exp2fast(u * AaB);
      float dt = u * LN2;
      HB = fmaf(PB, dt * b1.z * xv, HB);
      PB *= a;
    }
  }
  size_t oA = ((size_t)((b * KK + kA) * SS + s)) * DIN + d;
  size_t oB = ((size_t)((b * KK + kB) * SS + s2)) * DIN + d;
  carrP[oA] = PA;
  carrH[oA] = HA;
  carrP[oB] = PB;
  carrH[oB] = HB;
}

// ---------------------------------------------------------------------------
// Scan pass 2: serial combine of SS carries -> per-segment initial state h0
// ---------------------------------------------------------------------------
__global__ __launch_bounds__(192) void scan_fix_k(const float* __restrict__ carrP,
                                                  const float* __restrict__ carrH,
                                                  float* __restrict__ h0) {
  const int k = blockIdx.x, b = blockIdx.y, d = threadIdx.x;
  size_t base = ((size_t)(b * KK + k)) * SS * DIN + d;
  float h = 0.0f;
#pragma unroll 4
  for (int s = 0; s < SS; ++s) {
    h0[base + (size_t)s * DIN] = h;
    h = fmaf(carrP[base + (size_t)s * DIN], h, carrH[base + (size_t)s * DIN]);
  }
}

// ---------------------------------------------------------------------------
// Scan pass 3: apply + gate + paired-direction merge via 24 KB LDS.
// Direction B reuses direction A's xv via register cache (full unroll).
// ---------------------------------------------------------------------------
__global__ __launch_bounds__(192) void scan_apply_k(const float* __restrict__ xcT,
                                                    const float* __restrict__ projS,
                                                    const float* __restrict__ Wg,
                                                    const float* __restrict__ h0,
                                                    const float* __restrict__ dtw,
                                                    const float* __restrict__ dtb,
                                                    const float* __restrict__ A_logs,
                                                    const float* __restrict__ Ds,
                                                    float* __restrict__ ymT,
                                                    float* __restrict__ ymT2) {
  const int s = blockIdx.x, kp = blockIdx.y, b = blockIdx.z;
  const int d = threadIdx.x;
  __shared__ float sAcc[LC * DIN];  // 24 KB, column d thread-private
  float xr[LC];                     // register cache of this segment's xv
  {
    const int k = kp, kd = k * DIN + d;
    float wr[6];
#pragma unroll
    for (int r = 0; r < 6; ++r) wr[r] = dtw[kd * 6 + r];
    const float bias = dtb[kd];
    const float Aa = -__expf(A_logs[kd]);
    const float Dv = Ds[kd];
    const int l0 = s * LC;
    const int p0 = pix_of(k, l0);
    const int dp = pix_of(k, l0 + 1) - p0;
    const float* xp = xcT + ((size_t)b * LL + p0) * DIN + d;
    const long xstep = (long)dp * DIN;
    const float* pr = projS + (((size_t)b * KK + k) * LL + l0) * 8;
    const float* wg = Wg + ((size_t)b * KK + k) * LL + l0;
    float h = h0[((size_t)((b * KK + k) * SS + s)) * DIN + d];
#pragma unroll
    for (int j = 0; j < LC; ++j) {
      float4 q0 = *(const float4*)pr;
      float4 q1 = *(const float4*)(pr + 4);
      pr += 8;
      float xv = *xp;
      xp += xstep;
      xr[j] = xv;
      float dtr = bias;
      dtr = fmaf(q0.x, wr[0], dtr);
      dtr = fmaf(q0.y, wr[1], dtr);
      dtr = fmaf(q0.z, wr[2], dtr);
      dtr = fmaf(q0.w, wr[3], dtr);
      dtr = fmaf(q1.x, wr[4], dtr);
      dtr = fmaf(q1.y, wr[5], dtr);
      float e = exp2fast(fminf(dtr, 80.0f) * LOG2E);
      float u = log2fast(1.0f + e);
      float a = exp2fast(u * Aa);
      float dt = u * LN2;
      h = fmaf(a, h, dt * q1.z * xv);
      sAcc[j * DIN + d] = fmaf(h, q1.w, Dv * xv) * wg[j];
    }
  }
  {
    const int k = kp + 2, kd = k * DIN + d;
    const int s2 = SS - 1 - s;
    float wr[6];
#pragma unroll
    for (int r = 0; r < 6; ++r) wr[r] = dtw[kd * 6 + r];
    const float bias = dtb[kd];
    const float Aa = -__expf(A_logs[kd]);
    const float Dv = Ds[kd];
    const int l0 = s2 * LC;
    const float* pr = projS + (((size_t)b * KK + k) * LL + l0) * 8;
    const float* wg = Wg + ((size_t)b * KK + k) * LL + l0;
    float h = h0[((size_t)((b * KK + k) * SS + s2)) * DIN + d];
#pragma unroll
    for (int j = 0; j < LC; ++j) {
      float4 q0 = *(const float4*)pr;
      float4 q1 = *(const float4*)(pr + 4);
      pr += 8;
      float xv = xr[LC - 1 - j];   // same pixel set, reversed (static index)
      float dtr = bias;
      dtr = fmaf(q0.x, wr[0], dtr);
      dtr = fmaf(q0.y, wr[1], dtr);
      dtr = fmaf(q0.z, wr[2], dtr);
      dtr = fmaf(q0.w, wr[3], dtr);
      dtr = fmaf(q1.x, wr[4], dtr);
      dtr = fmaf(q1.y, wr[5], dtr);
      float e = exp2fast(fminf(dtr, 80.0f) * LOG2E);
      float u = log2fast(1.0f + e);
      float a = exp2fast(u * Aa);
      float dt = u * LN2;
      h = fmaf(a, h, dt * q1.z * xv);
      float y = fmaf(h, q1.w, Dv * xv) * wg[j];
      sAcc[(LC - 1 - j) * DIN + d] += y;
    }
  }
  float* dst;
  if (kp == 0)
    dst = ymT + (size_t)b * (384 * (size_t)LL) + (size_t)(s * LC) * DIN + d;  // xz overlay
  else
    dst = ymT2 + ((size_t)b * LL + s * LC) * DIN + d;
#pragma unroll 4
  for (int j = 0; j < LC; ++j) dst[(size_t)j * DIN] = sAcc[j * DIN + d];
}

// ---------------------------------------------------------------------------
// LayerNorm(channel) * silu(z): reads ymT(overlay)[p,:] + ymT2[tr(p),:], writes u
// ---------------------------------------------------------------------------
__global__ __launch_bounds__(256) void ln_silu_k(const float* __restrict__ ymT,
                                                 const float* __restrict__ ymT2,
                                                 const float* __restrict__ xz,
                                                 const float* __restrict__ gamma,
                                                 const float* __restrict__ beta,
                                                 float* __restrict__ u) {
  const int b = blockIdx.y;
  const int h = blockIdx.x;
  const int p0 = h * 64;
  __shared__ float sY[64 * 193];
  __shared__ float sS[4][64], sQ[4][64];
  const int tid = threadIdx.x;
  const float* ymb = ymT + (size_t)b * (384 * (size_t)LL);  // xz overlay
  for (int idx = tid; idx < 64 * DIN; idx += 256) {
    int pp = idx / DIN, dd = idx % DIN;
    float v = ymb[(size_t)(p0 + pp) * DIN + dd] +
              ymT2[((size_t)b * LL + pp * 64 + h) * DIN + dd];
    sY[pp * 193 + dd] = v;
  }
  __syncthreads();
  const int px = tid & 63, g = tid >> 6;
  float sum = 0.0f, ss = 0.0f;
  for (int dd = g * 48; dd < g * 48 + 48; ++dd) {
    float v = sY[px * 193 + dd];
    sum += v;
    ss = fmaf(v, v, ss);
  }
  sS[g][px] = sum;
  sQ[g][px] = ss;
  __syncthreads();
  sum = sS[0][px] + sS[1][px] + sS[2][px] + sS[3][px];
  ss  = sQ[0][px] + sQ[1][px] + sQ[2][px] + sQ[3][px];
  const float mu = sum * (1.0f / DIN);
  float var = ss * (1.0f / DIN) - mu * mu;
  const float rstd = rsqrtf(fmaxf(var, 0.0f) + 1e-5f);
  const float* zb = xz + ((size_t)b * 384 + DIN) * LL + p0 + px;
  float* ub = u + (size_t)b * DIN * LL + p0 + px;
  for (int dd = g * 48; dd < g * 48 + 48; ++dd) {
    float v = sY[px * 193 + dd];
    float z = zb[(size_t)dd * LL];
    float tn = fmaf((v - mu) * rstd, gamma[dd], beta[dd]);
    ub[(size_t)dd * LL] = tn * (z * sigf(z));
  }
}

// ---------------------------------------------------------------------------
extern "C" void kernel_launch(void* const* d_in, const int* in_sizes, int n_in,
                              void* d_out, int out_size, void* d_ws, size_t ws_size,
                              hipStream_t stream) {
  const float* x      = (const float*)d_in[0];
  const float* prior  = (const float*)d_in[1];
  const float* alpha  = (const float*)d_in[2];
  const float* ipw    = (const float*)d_in[3];
  const float* cw     = (const float*)d_in[4];
  const float* cb     = (const float*)d_in[5];
  const float* xpw    = (const float*)d_in[6];
  const float* dtw    = (const float*)d_in[7];
  const float* dtb    = (const float*)d_in[8];
  const float* A_logs = (const float*)d_in[9];
  const float* Ds     = (const float*)d_in[10];
  const float* onw    = (const float*)d_in[11];
  const float* onb    = (const float*)d_in[12];
  const float* opw    = (const float*)d_in[13];
  const float* w1     = (const float*)d_in[14];
  const float* b1     = (const float*)d_in[15];
  const float* bnw    = (const float*)d_in[16];
  const float* bnb    = (const float*)d_in[17];
  const float* bnm    = (const float*)d_in[18];
  const float* bnv    = (const float*)d_in[19];
  const float* w2     = (const float*)d_in[20];
  const float* b2     = (const float*)d_in[21];
  float* out = (float*)d_out;

  char* ws = (char*)d_ws;
  // Footprint ends at 114,843,648 B (< 135,266,304 proven in R2).
  float* xz    = (float*)(ws);              // [B,384,L]     50.3 MB
  float* xcT   = (float*)(ws + 50331648);   // [B,L,192]     25.2 MB (-> u after apply)
  float* ymT2  = (float*)(ws + 75497472);   // [B,L,192]     25.2 MB
  float* projS = (float*)(ws + 100663296);  // [B,K,L,8]      4.2 MB (scan order)
  float* Wgb   = (float*)(ws + 104857600);  // [B,4,L]        0.5 MB
  float* carrP = (float*)(ws + 105381888);  // [B,K,SS,192]   3.0 MB
  float* carrH = (float*)(ws + 108527616);  // [B,K,SS,192]   3.0 MB
  float* h0b   = (float*)(ws + 111673344);  // [B,K,SS,192]   3.0 MB
  float* xpwT  = (float*)(ws + 114819072);  // [K,DIN,8]      24.6 KB (ends 114843648)
  float* ymT   = xz;   // overlay: x_ssm half of xz (dead after convproj)
  float* u     = xcT;  // xcT dead after scan_apply_k

  // 1) in_proj GEMM: OT=8, float4 px (1536 blocks)
  gemm_pix_k<CIN, 8><<<dim3(LL / 1024, 384 / 8, BB), 256, 0, stream>>>(x, ipw, xz, 384);
  // 2) prior -> direction gates  (+ weight transpose in block 0)
  p2w_k<<<(BB * LL) / 256, 256, 0, stream>>>(prior, alpha, w1, b1, bnw, bnb, bnm,
                                             bnv, w2, b2, xpw, xpwT, Wgb);
  // 3) fused dwconv+SiLU + x_proj(scan-order) + transpose (vectorized conv)
  convproj_k<<<dim3(HH, BB), 1024, 0, stream>>>(xz, cw, cb, xpwT, xcT, projS);
  // 4) scan: paired segment carries (both directions per xcT pass)
  scan_part_k<<<dim3(SS, 2, BB), 192, 0, stream>>>(xcT, projS, dtw, dtb, A_logs,
                                                   carrP, carrH);
  // 5) scan: serial carry combine
  scan_fix_k<<<dim3(KK, BB), 192, 0, stream>>>(carrP, carrH, h0b);
  // 6) scan: apply + gate + paired merge (ymT overlaid on xz x_ssm half)
  scan_apply_k<<<dim3(SS, 2, BB), 192, 0, stream>>>(xcT, projS, Wgb, h0b, dtw, dtb,
                                                    A_logs, Ds, ymT, ymT2);
  // 7) LayerNorm(channel) * silu(z)
  ln_silu_k<<<dim3(HH, BB), 256, 0, stream>>>(ymT, ymT2, xz, onw, onb, u);
  // 8) out_proj GEMM: OT=4, float4 px (768 blocks)
  gemm_pix_k<DIN, 4><<<dim3(LL / 1024, COUT / 4, BB), 256, 0, stream>>>(u, opw, out, COUT);
}

// Round 18
// 182.845 us; speedup vs baseline: 1.5163x; 1.0228x over previous
//
#include <hip/hip_runtime.h>

#define BB   8
#define CIN  96
#define DIN  192
#define HH   64
#define WW   64
#define LL   4096
#define KK   4
#define COUT 96
#define SS   128  // scan segments
#define LC   32   // segment length = LL/SS

#define LOG2E 1.4426950408889634f
#define LN2   0.6931471805599453f

typedef unsigned short bf16t;

__device__ __forceinline__ float exp2fast(float x) { return __builtin_amdgcn_exp2f(x); }
__device__ __forceinline__ float log2fast(float x) { return __builtin_amdgcn_logf(x); }
__device__ __forceinline__ float sigf(float x) { return 1.0f / (1.0f + __expf(-x)); }
__device__ __forceinline__ int trp(int p) { return ((p & 63) << 6) | (p >> 6); }
__device__ __forceinline__ int pix_of(int k, int l) {
  if (k == 0) return l;
  if (k == 1) return trp(l);
  if (k == 2) return LL - 1 - l;
  return trp(LL - 1 - l);
}
__device__ __forceinline__ float b2f(bf16t v) {
  return __uint_as_float((unsigned)v << 16);
}
__device__ __forceinline__ bf16t f2b(float f) {  // round-to-nearest-even
  unsigned u = __float_as_uint(f);
  return (bf16t)((u + 0x7FFFu + ((u >> 16) & 1u)) >> 16);
}

// ---------------------------------------------------------------------------
// in_proj GEMM: x f32 -> xz bf16. 4 consecutive px/thread, 8 outputs.
// Weights block-uniform (SGPR). c-order 0..C-1 preserved.
// ---------------------------------------------------------------------------
__global__ __launch_bounds__(256) void gemm_in_k(const float* __restrict__ in,
                                                 const float* __restrict__ W,
                                                 bf16t* __restrict__ out) {
  const int tid = threadIdx.x;
  const int b  = blockIdx.z;
  const int o0 = blockIdx.y * 8;
  const int p0 = blockIdx.x * 1024 + tid * 4;
  const float* inb = in + (size_t)b * CIN * LL + p0;
  const float* Wb  = W + (size_t)o0 * CIN;
  float4 acc[8];
#pragma unroll
  for (int j = 0; j < 8; ++j) acc[j] = make_float4(0.f, 0.f, 0.f, 0.f);
#pragma unroll 4
  for (int c = 0; c < CIN; c += 4) {
    float4 w[8];
#pragma unroll
    for (int j = 0; j < 8; ++j) w[j] = *(const float4*)&Wb[j * CIN + c];
    float4 xv[4];
#pragma unroll
    for (int t = 0; t < 4; ++t) xv[t] = *(const float4*)&inb[(size_t)(c + t) * LL];
#pragma unroll
    for (int j = 0; j < 8; ++j) {
#pragma unroll
      for (int t = 0; t < 4; ++t) {
        const float ws = t == 0 ? w[j].x : t == 1 ? w[j].y : t == 2 ? w[j].z : w[j].w;
        acc[j].x = fmaf(xv[t].x, ws, acc[j].x);
        acc[j].y = fmaf(xv[t].y, ws, acc[j].y);
        acc[j].z = fmaf(xv[t].z, ws, acc[j].z);
        acc[j].w = fmaf(xv[t].w, ws, acc[j].w);
      }
    }
  }
  bf16t* ob = out + (size_t)b * 384 * LL + p0;
#pragma unroll
  for (int j = 0; j < 8; ++j) {
    ushort4 st;
    st.x = f2b(acc[j].x);
    st.y = f2b(acc[j].y);
    st.z = f2b(acc[j].z);
    st.w = f2b(acc[j].w);
    *(ushort4*)&ob[(size_t)(o0 + j) * LL] = st;
  }
}

// ---------------------------------------------------------------------------
// out_proj GEMM: u bf16 -> out f32. 4 consecutive px/thread, 4 outputs.
// ---------------------------------------------------------------------------
__global__ __launch_bounds__(256) void gemm_out_k(const bf16t* __restrict__ in,
                                                  const float* __restrict__ W,
                                                  float* __restrict__ out) {
  const int tid = threadIdx.x;
  const int b  = blockIdx.z;
  const int o0 = blockIdx.y * 4;
  const int p0 = blockIdx.x * 1024 + tid * 4;
  const bf16t* inb = in + (size_t)b * DIN * LL + p0;
  const float* Wb  = W + (size_t)o0 * DIN;
  float4 acc[4];
#pragma unroll
  for (int j = 0; j < 4; ++j) acc[j] = make_float4(0.f, 0.f, 0.f, 0.f);
#pragma unroll 4
  for (int c = 0; c < DIN; c += 4) {
    float4 w[4];
#pragma unroll
    for (int j = 0; j < 4; ++j) w[j] = *(const float4*)&Wb[j * DIN + c];
    float4 xv[4];
#pragma unroll
    for (int t = 0; t < 4; ++t) {
      ushort4 xu = *(const ushort4*)&inb[(size_t)(c + t) * LL];
      xv[t] = make_float4(b2f(xu.x), b2f(xu.y), b2f(xu.z), b2f(xu.w));
    }
#pragma unroll
    for (int j = 0; j < 4; ++j) {
#pragma unroll
      for (int t = 0; t < 4; ++t) {
        const float ws = t == 0 ? w[j].x : t == 1 ? w[j].y : t == 2 ? w[j].z : w[j].w;
        acc[j].x = fmaf(xv[t].x, ws, acc[j].x);
        acc[j].y = fmaf(xv[t].y, ws, acc[j].y);
        acc[j].z = fmaf(xv[t].z, ws, acc[j].z);
        acc[j].w = fmaf(xv[t].w, ws, acc[j].w);
      }
    }
  }
  float* ob = out + (size_t)b * COUT * LL + p0;
#pragma unroll
  for (int j = 0; j < 4; ++j) *(float4*)&ob[(size_t)(o0 + j) * LL] = acc[j];
}

// ---------------------------------------------------------------------------
// PriorToWeights MLP -> Wg[B,4,L].  Block 0: transpose xpw -> xpwT[k][dd][8].
// ---------------------------------------------------------------------------
__global__ __launch_bounds__(256) void p2w_k(const float* __restrict__ prior,
                                             const float* __restrict__ alpha,
                                             const float* __restrict__ w1,
                                             const float* __restrict__ b1,
                                             const float* __restrict__ bnw,
                                             const float* __restrict__ bnb,
                                             const float* __restrict__ bnm,
                                             const float* __restrict__ bnv,
                                             const float* __restrict__ w2,
                                             const float* __restrict__ b2,
                                             const float* __restrict__ xpw,
                                             float* __restrict__ xpwT,
                                             float* __restrict__ Wg) {
  if (blockIdx.x == 0) {
    for (int idx = threadIdx.x; idx < KK * DIN * 8; idx += 256) {
      int kk = idx / (DIN * 8);
      int rem = idx % (DIN * 8);
      int dd = rem >> 3, c = rem & 7;
      xpwT[idx] = xpw[(kk * 8 + c) * DIN + dd];
    }
  }
  int idx = blockIdx.x * 256 + threadIdx.x;
  int p = idx & (LL - 1);
  int b = idx >> 12;
  float pr[4];
#pragma unroll
  for (int c = 0; c < 4; ++c) pr[c] = prior[((size_t)b * 4 + c) * LL + p];
  float s = sigf(alpha[0]);
  float g2[4];
#pragma unroll
  for (int j = 0; j < 4; ++j) g2[j] = b2[j];
  for (int o = 0; o < 32; ++o) {
    float g = b1[o];
#pragma unroll
    for (int c = 0; c < 4; ++c) g = fmaf(pr[c], w1[o * 4 + c], g);
    g = (g - bnm[o]) * rsqrtf(bnv[o] + 1e-5f) * bnw[o] + bnb[o];
    g = fmaxf(g, 0.0f);
#pragma unroll
    for (int j = 0; j < 4; ++j) g2[j] = fmaf(g, w2[j * 32 + o], g2[j]);
  }
#pragma unroll
  for (int j = 0; j < 4; ++j)
    Wg[((size_t)b * 4 + j) * LL + p] = 1.0f + s * (sigf(g2[j]) - 1.0f);
}

// ---------------------------------------------------------------------------
// FUSED conv+proj: xz bf16 in, xcT bf16 out, projS f32 (scan order).
// 64-px row tiles, 1024 threads; conv vectorized 4 px/thread-iter.
// ---------------------------------------------------------------------------
__global__ __launch_bounds__(1024) void convproj_k(const bf16t* __restrict__ xz,
                                                   const float* __restrict__ cw,
                                                   const float* __restrict__ cb,
                                                   const float* __restrict__ xpwT,
                                                   bf16t* __restrict__ xcT,
                                                   float* __restrict__ projS) {
  __shared__ float sX[96 * 65];   // 24.96 KB
  __shared__ float4 sP[512];      // 8 KB q-partials
  const int tid = threadIdx.x;
  const int b = blockIdx.y;
  const int h = blockIdx.x;
  const int px = tid & 63;
  const int ku = __builtin_amdgcn_readfirstlane((tid >> 6) & 3);
  const int hf = __builtin_amdgcn_readfirstlane((tid >> 8) & 1);
  const int q  = __builtin_amdgcn_readfirstlane(tid >> 9);
  float a0 = 0.0f, a1 = 0.0f, a2 = 0.0f, a3 = 0.0f;

#pragma unroll
  for (int half = 0; half < 2; ++half) {
    // conv + bias + SiLU: 4 consecutive px per thread-iteration
    for (int idx = tid; idx < 96 * 16; idx += 1024) {
      int ddl = idx >> 4, pq = idx & 15;
      int w0 = pq * 4;
      int dd = half * 96 + ddl;
      const bf16t* base = xz + ((size_t)b * 384 + dd) * LL + h * 64 + w0;
      const float* wp = cw + dd * 9;
      float bv = cb[dd];
      float s0 = bv, s1 = bv, s2 = bv, s3 = bv;
#pragma unroll
      for (int dh = -1; dh <= 1; ++dh) {
        int hh = h + dh;
        if (hh < 0 || hh >= HH) continue;
        const bf16t* row = base + dh * 64;
        ushort4 cmu = *(const ushort4*)row;
        float cmx = b2f(cmu.x), cmy = b2f(cmu.y), cmz = b2f(cmu.z), cmw = b2f(cmu.w);
        float lf = (w0 > 0)  ? b2f(row[-1]) : 0.0f;
        float rt = (w0 < 60) ? b2f(row[4])  : 0.0f;
        float c0 = wp[(dh + 1) * 3], c1 = wp[(dh + 1) * 3 + 1], c2 = wp[(dh + 1) * 3 + 2];
        s0 = fmaf(lf,  c0, s0); s0 = fmaf(cmx, c1, s0); s0 = fmaf(cmy, c2, s0);
        s1 = fmaf(cmx, c0, s1); s1 = fmaf(cmy, c1, s1); s1 = fmaf(cmz, c2, s1);
        s2 = fmaf(cmy, c0, s2); s2 = fmaf(cmz, c1, s2); s2 = fmaf(cmw, c2, s2);
        s3 = fmaf(cmz, c0, s3); s3 = fmaf(cmw, c1, s3); s3 = fmaf(rt,  c2, s3);
      }
      float* so = &sX[ddl * 65 + w0];
      so[0] = s0 * sigf(s0);
      so[1] = s1 * sigf(s1);
      so[2] = s2 * sigf(s2);
      so[3] = s3 * sigf(s3);
    }
    __syncthreads();
    // transposed write xcT[b][p][half*96+ddl] (coalesced over ddl, bf16)
    for (int idx = tid; idx < 64 * 96; idx += 1024) {
      int pp = idx / 96, ddl = idx % 96;
      xcT[((size_t)b * LL + h * 64 + pp) * DIN + half * 96 + ddl] =
          f2b(sX[ddl * 65 + pp]);
    }
    // x_proj partial (f32 path, bf16-rounded x from sX? sX holds f32 conv out)
    {
      const int ddl0 = q * 48;
      const float* wp = xpwT + (size_t)ku * (DIN * 8) + (half * 96 + ddl0) * 8 + hf * 4;
#pragma unroll 8
      for (int d48 = 0; d48 < 48; ++d48) {
        float xv = sX[(ddl0 + d48) * 65 + px];
        const float4 w4 = *(const float4*)(wp + d48 * 8);
        a0 = fmaf(xv, w4.x, a0);
        a1 = fmaf(xv, w4.y, a1);
        a2 = fmaf(xv, w4.z, a2);
        a3 = fmaf(xv, w4.w, a3);
      }
    }
    __syncthreads();
  }
  const int slot = tid & 511;
  if (q == 1) sP[slot] = make_float4(a0, a1, a2, a3);
  __syncthreads();
  if (q == 0) {
    float4 o = sP[slot];
    a0 += o.x; a1 += o.y; a2 += o.z; a3 += o.w;
    const int p = h * 64 + px;
    int l;
    if (ku == 0) l = p;
    else if (ku == 1) l = trp(p);
    else if (ku == 2) l = LL - 1 - p;
    else l = LL - 1 - trp(p);
    float* pb = projS + (((size_t)b * KK + ku) * LL + l) * 8 + hf * 4;
    *(float4*)pb = make_float4(a0, a1, a2, a3);
  }
}

// ---------------------------------------------------------------------------
// Scan pass 1 (PAIRED): xcT bf16; carries f32.
// ---------------------------------------------------------------------------
__global__ __launch_bounds__(192) void scan_part_k(const bf16t* __restrict__ xcT,
                                                   const float* __restrict__ projS,
                                                   const float* __restrict__ dtw,
                                                   const float* __restrict__ dtb,
                                                   const float* __restrict__ A_logs,
                                                   float* __restrict__ carrP,
                                                   float* __restrict__ carrH) {
  const int s = blockIdx.x, kp = blockIdx.y, b = blockIdx.z;
  const int d = threadIdx.x;
  const int kA = kp, kB = kp + 2;
  const int s2 = SS - 1 - s;
  const int kdA = kA * DIN + d, kdB = kB * DIN + d;
  float wrA[6], wrB[6];
#pragma unroll
  for (int r = 0; r < 6; ++r) { wrA[r] = dtw[kdA * 6 + r]; wrB[r] = dtw[kdB * 6 + r]; }
  const float biasA = dtb[kdA], biasB = dtb[kdB];
  const float AaA = -__expf(A_logs[kdA]), AaB = -__expf(A_logs[kdB]);
  const int l0 = s * LC;
  const int p0 = pix_of(kA, l0);
  const int dp = pix_of(kA, l0 + 1) - p0;
  const bf16t* xp = xcT + ((size_t)b * LL + p0) * DIN + d;
  const long xstep = (long)dp * DIN;
  const float* prA = projS + (((size_t)b * KK + kA) * LL + l0) * 8;
  const float* prB = projS + (((size_t)b * KK + kB) * LL + s2 * LC + (LC - 1)) * 8;
  float PA = 1.0f, HA = 0.0f, PB = 1.0f, HB = 0.0f;
#pragma unroll 2
  for (int j = 0; j < LC; ++j) {
    float4 a0 = *(const float4*)prA;
    float4 a1 = *(const float4*)(prA + 4);
    prA += 8;
    float4 b0 = *(const float4*)prB;
    float4 b1 = *(const float4*)(prB + 4);
    prB -= 8;
    float xv = b2f(*xp);
    xp += xstep;
    {
      float dtr = biasA;
      dtr = fmaf(a0.x, wrA[0], dtr);
      dtr = fmaf(a0.y, wrA[1], dtr);
      dtr = fmaf(a0.z, wrA[2], dtr);
      dtr = fmaf(a0.w, wrA[3], dtr);
      dtr = fmaf(a1.x, wrA[4], dtr);
      dtr = fmaf(a1.y, wrA[5], dtr);
      float e = exp2fast(fminf(dtr, 80.0f) * LOG2E);
      float u = log2fast(1.0f + e);
      float a = exp2fast(u * AaA);
      float dt = u * LN2;
      HA = fmaf(a, HA, dt * a1.z * xv);
      PA *= a;
    }
    {
      float dtr = biasB;
      dtr = fmaf(b0.x, wrB[0], dtr);
      dtr = fmaf(b0.y, wrB[1], dtr);
      dtr = fmaf(b0.z, wrB[2], dtr);
      dtr = fmaf(b0.w, wrB[3], dtr);
      dtr = fmaf(b1.x, wrB[4], dtr);
      dtr = fmaf(b1.y, wrB[5], dtr);
      float e = exp2fast(fminf(dtr, 80.0f) * LOG2E);
      float u = log2fast(1.0f + e);
      float a = exp2fast(u * AaB);
      float dt = u * LN2;
      HB = fmaf(PB, dt * b1.z * xv, HB);
      PB *= a;
    }
  }
  size_t oA = ((size_t)((b * KK + kA) * SS + s)) * DIN + d;
  size_t oB = ((size_t)((b * KK + kB) * SS + s2)) * DIN + d;
  carrP[oA] = PA;
  carrH[oA] = HA;
  carrP[oB] = PB;
  carrH[oB] = HB;
}

// ---------------------------------------------------------------------------
// Scan pass 2: serial combine of SS carries -> per-segment initial state h0
// ---------------------------------------------------------------------------
__global__ __launch_bounds__(192) void scan_fix_k(const float* __restrict__ carrP,
                                                  const float* __restrict__ carrH,
                                                  float* __restrict__ h0) {
  const int k = blockIdx.x, b = blockIdx.y, d = threadIdx.x;
  size_t base = ((size_t)(b * KK + k)) * SS * DIN + d;
  float h = 0.0f;
#pragma unroll 4
  for (int s = 0; s < SS; ++s) {
    h0[base + (size_t)s * DIN] = h;
    h = fmaf(carrP[base + (size_t)s * DIN], h, carrH[base + (size_t)s * DIN]);
  }
}

// ---------------------------------------------------------------------------
// Scan pass 3: apply + gate + paired merge; xcT bf16 in (reg-cached for dir B),
// ymT/ymT2 bf16 out.
// ---------------------------------------------------------------------------
__global__ __launch_bounds__(192) void scan_apply_k(const bf16t* __restrict__ xcT,
                                                    const float* __restrict__ projS,
                                                    const float* __restrict__ Wg,
                                                    const float* __restrict__ h0,
                                                    const float* __restrict__ dtw,
                                                    const float* __restrict__ dtb,
                                                    const float* __restrict__ A_logs,
                                                    const float* __restrict__ Ds,
                                                    bf16t* __restrict__ ymT,
                                                    bf16t* __restrict__ ymT2) {
  const int s = blockIdx.x, kp = blockIdx.y, b = blockIdx.z;
  const int d = threadIdx.x;
  __shared__ float sAcc[LC * DIN];  // 24 KB, column d thread-private
  float xr[LC];                     // register cache of this segment's xv
  {
    const int k = kp, kd = k * DIN + d;
    float wr[6];
#pragma unroll
    for (int r = 0; r < 6; ++r) wr[r] = dtw[kd * 6 + r];
    const float bias = dtb[kd];
    const float Aa = -__expf(A_logs[kd]);
    const float Dv = Ds[kd];
    const int l0 = s * LC;
    const int p0 = pix_of(k, l0);
    const int dp = pix_of(k, l0 + 1) - p0;
    const bf16t* xp = xcT + ((size_t)b * LL + p0) * DIN + d;
    const long xstep = (long)dp * DIN;
    const float* pr = projS + (((size_t)b * KK + k) * LL + l0) * 8;
    const float* wg = Wg + ((size_t)b * KK + k) * LL + l0;
    float h = h0[((size_t)((b * KK + k) * SS + s)) * DIN + d];
#pragma unroll
    for (int j = 0; j < LC; ++j) {
      float4 q0 = *(const float4*)pr;
      float4 q1 = *(const float4*)(pr + 4);
      pr += 8;
      float xv = b2f(*xp);
      xp += xstep;
      xr[j] = xv;
      float dtr = bias;
      dtr = fmaf(q0.x, wr[0], dtr);
      dtr = fmaf(q0.y, wr[1], dtr);
      dtr = fmaf(q0.z, wr[2], dtr);
      dtr = fmaf(q0.w, wr[3], dtr);
      dtr = fmaf(q1.x, wr[4], dtr);
      dtr = fmaf(q1.y, wr[5], dtr);
      float e = exp2fast(fminf(dtr, 80.0f) * LOG2E);
      float u = log2fast(1.0f + e);
      float a = exp2fast(u * Aa);
      float dt = u * LN2;
      h = fmaf(a, h, dt * q1.z * xv);
      sAcc[j * DIN + d] = fmaf(h, q1.w, Dv * xv) * wg[j];
    }
  }
  {
    const int k = kp + 2, kd = k * DIN + d;
    const int s2 = SS - 1 - s;
    float wr[6];
#pragma unroll
    for (int r = 0; r < 6; ++r) wr[r] = dtw[kd * 6 + r];
    const float bias = dtb[kd];
    const float Aa = -__expf(A_logs[kd]);
    const float Dv = Ds[kd];
    const int l0 = s2 * LC;
    const float* pr = projS + (((size_t)b * KK + k) * LL + l0) * 8;
    const float* wg = Wg + ((size_t)b * KK + k) * LL + l0;
    float h = h0[((size_t)((b * KK + k) * SS + s2)) * DIN + d];
#pragma unroll
    for (int j = 0; j < LC; ++j) {
      float4 q0 = *(const float4*)pr;
      float4 q1 = *(const float4*)(pr + 4);
      pr += 8;
      float xv = xr[LC - 1 - j];   // same pixels, reversed (static index)
      float dtr = bias;
      dtr = fmaf(q0.x, wr[0], dtr);
      dtr = fmaf(q0.y, wr[1], dtr);
      dtr = fmaf(q0.z, wr[2], dtr);
      dtr = fmaf(q0.w, wr[3], dtr);
      dtr = fmaf(q1.x, wr[4], dtr);
      dtr = fmaf(q1.y, wr[5], dtr);
      float e = exp2fast(fminf(dtr, 80.0f) * LOG2E);
      float u = log2fast(1.0f + e);
      float a = exp2fast(u * Aa);
      float dt = u * LN2;
      h = fmaf(a, h, dt * q1.z * xv);
      float y = fmaf(h, q1.w, Dv * xv) * wg[j];
      sAcc[(LC - 1 - j) * DIN + d] += y;
    }
  }
  bf16t* dst;
  if (kp == 0)
    dst = ymT + (size_t)b * (384 * (size_t)LL) + (size_t)(s * LC) * DIN + d;  // xz overlay
  else
    dst = ymT2 + ((size_t)b * LL + s * LC) * DIN + d;
#pragma unroll 4
  for (int j = 0; j < LC; ++j) dst[(size_t)j * DIN] = f2b(sAcc[j * DIN + d]);
}

// ---------------------------------------------------------------------------
// LayerNorm(channel) * silu(z): ym bf16 + z bf16 -> u bf16.
// ---------------------------------------------------------------------------
__global__ __launch_bounds__(256) void ln_silu_k(const bf16t* __restrict__ ymT,
                                                 const bf16t* __restrict__ ymT2,
                                                 const bf16t* __restrict__ xz,
                                                 const float* __restrict__ gamma,
                                                 const float* __restrict__ beta,
                                                 bf16t* __restrict__ u) {
  const int b = blockIdx.y;
  const int h = blockIdx.x;
  const int p0 = h * 64;
  __shared__ float sY[64 * 193];
  __shared__ float sS[4][64], sQ[4][64];
  const int tid = threadIdx.x;
  const bf16t* ymb = ymT + (size_t)b * (384 * (size_t)LL);  // xz overlay
  for (int idx = tid; idx < 64 * DIN; idx += 256) {
    int pp = idx / DIN, dd = idx % DIN;
    float v = b2f(ymb[(size_t)(p0 + pp) * DIN + dd]) +
              b2f(ymT2[((size_t)b * LL + pp * 64 + h) * DIN + dd]);
    sY[pp * 193 + dd] = v;
  }
  __syncthreads();
  const int px = tid & 63, g = tid >> 6;
  float sum = 0.0f, ss = 0.0f;
  for (int dd = g * 48; dd < g * 48 + 48; ++dd) {
    float v = sY[px * 193 + dd];
    sum += v;
    ss = fmaf(v, v, ss);
  }
  sS[g][px] = sum;
  sQ[g][px] = ss;
  __syncthreads();
  sum = sS[0][px] + sS[1][px] + sS[2][px] + sS[3][px];
  ss  = sQ[0][px] + sQ[1][px] + sQ[2][px] + sQ[3][px];
  const float mu = sum * (1.0f / DIN);
  float var = ss * (1.0f / DIN) - mu * mu;
  const float rstd = rsqrtf(fmaxf(var, 0.0f) + 1e-5f);
  const bf16t* zb = xz + ((size_t)b * 384 + DIN) * LL + p0 + px;
  bf16t* ub = u + (size_t)b * DIN * LL + p0 + px;
  for (int dd = g * 48; dd < g * 48 + 48; ++dd) {
    float v = sY[px * 193 + dd];
    float z = b2f(zb[(size_t)dd * LL]);
    float tn = fmaf((v - mu) * rstd, gamma[dd], beta[dd]);
    ub[(size_t)dd * LL] = f2b(tn * (z * sigf(z)));
  }
}

// ---------------------------------------------------------------------------
extern "C" void kernel_launch(void* const* d_in, const int* in_sizes, int n_in,
                              void* d_out, int out_size, void* d_ws, size_t ws_size,
                              hipStream_t stream) {
  const float* x      = (const float*)d_in[0];
  const float* prior  = (const float*)d_in[1];
  const float* alpha  = (const float*)d_in[2];
  const float* ipw    = (const float*)d_in[3];
  const float* cw     = (const float*)d_in[4];
  const float* cb     = (const float*)d_in[5];
  const float* xpw    = (const float*)d_in[6];
  const float* dtw    = (const float*)d_in[7];
  const float* dtb    = (const float*)d_in[8];
  const float* A_logs = (const float*)d_in[9];
  const float* Ds     = (const float*)d_in[10];
  const float* onw    = (const float*)d_in[11];
  const float* onb    = (const float*)d_in[12];
  const float* opw    = (const float*)d_in[13];
  const float* w1     = (const float*)d_in[14];
  const float* b1     = (const float*)d_in[15];
  const float* bnw    = (const float*)d_in[16];
  const float* bnb    = (const float*)d_in[17];
  const float* bnm    = (const float*)d_in[18];
  const float* bnv    = (const float*)d_in[19];
  const float* w2     = (const float*)d_in[20];
  const float* b2     = (const float*)d_in[21];
  float* out = (float*)d_out;

  char* ws = (char*)d_ws;
  // bf16 intermediates; footprint ends at 64,512,000 B.
  bf16t* xz    = (bf16t*)(ws);              // [B,384,L] bf16  25.2 MB
  bf16t* xcT   = (bf16t*)(ws + 25165824);   // [B,L,192] bf16  12.6 MB (-> u)
  bf16t* ymT2  = (bf16t*)(ws + 37748736);   // [B,L,192] bf16  12.6 MB
  float* projS = (float*)(ws + 50331648);   // [B,K,L,8] f32    4.2 MB
  float* Wgb   = (float*)(ws + 54525952);   // [B,4,L]          0.5 MB
  float* carrP = (float*)(ws + 55050240);   // [B,K,SS,192]     3.0 MB
  float* carrH = (float*)(ws + 58195968);   // [B,K,SS,192]     3.0 MB
  float* h0b   = (float*)(ws + 61341696);   // [B,K,SS,192]     3.0 MB
  float* xpwT  = (float*)(ws + 64487424);   // [K,DIN,8]       24.6 KB (ends 64512000)
  bf16t* ymT   = xz;   // overlay: x_ssm half of xz (dead after convproj)
  bf16t* u     = xcT;  // xcT dead after scan_apply_k

  // 1) in_proj GEMM -> xz bf16
  gemm_in_k<<<dim3(LL / 1024, 384 / 8, BB), 256, 0, stream>>>(x, ipw, xz);
  // 2) prior -> direction gates (+ weight transpose in block 0)
  p2w_k<<<(BB * LL) / 256, 256, 0, stream>>>(prior, alpha, w1, b1, bnw, bnb, bnm,
                                             bnv, w2, b2, xpw, xpwT, Wgb);
  // 3) fused dwconv+SiLU + x_proj(scan-order) + transpose
  convproj_k<<<dim3(HH, BB), 1024, 0, stream>>>(xz, cw, cb, xpwT, xcT, projS);
  // 4) scan: paired segment carries
  scan_part_k<<<dim3(SS, 2, BB), 192, 0, stream>>>(xcT, projS, dtw, dtb, A_logs,
                                                   carrP, carrH);
  // 5) scan: serial carry combine
  scan_fix_k<<<dim3(KK, BB), 192, 0, stream>>>(carrP, carrH, h0b);
  // 6) scan: apply + gate + paired merge (ymT overlaid on xz x_ssm half)
  scan_apply_k<<<dim3(SS, 2, BB), 192, 0, stream>>>(xcT, projS, Wgb, h0b, dtw, dtb,
                                                    A_logs, Ds, ymT, ymT2);
  // 7) LayerNorm(channel) * silu(z) -> u bf16
  ln_silu_k<<<dim3(HH, BB), 256, 0, stream>>>(ymT, ymT2, xz, onw, onb, u);
  // 8) out_proj GEMM: u bf16 -> out f32
  gemm_out_k<<<dim3(LL / 1024, COUT / 4, BB), 256, 0, stream>>>(u, opw, out);
}

// Round 19
// 181.105 us; speedup vs baseline: 1.5309x; 1.0096x over previous
//
#include <hip/hip_runtime.h>

#define BB   8
#define CIN  96
#define DIN  192
#define HH   64
#define WW   64
#define LL   4096
#define KK   4
#define COUT 96
#define SS   128  // scan segments
#define LC   32   // segment length = LL/SS

#define LOG2E 1.4426950408889634f
#define LN2   0.6931471805599453f

typedef unsigned short bf16t;
typedef float f32x2 __attribute__((ext_vector_type(2)));

__device__ __forceinline__ f32x2 pkfma(f32x2 a, f32x2 b, f32x2 c) {
#if __has_builtin(__builtin_elementwise_fma)
  return __builtin_elementwise_fma(a, b, c);
#else
  f32x2 r;
  r[0] = fmaf(a[0], b[0], c[0]);
  r[1] = fmaf(a[1], b[1], c[1]);
  return r;
#endif
}

__device__ __forceinline__ float exp2fast(float x) { return __builtin_amdgcn_exp2f(x); }
__device__ __forceinline__ float log2fast(float x) { return __builtin_amdgcn_logf(x); }
__device__ __forceinline__ float sigf(float x) { return 1.0f / (1.0f + __expf(-x)); }
__device__ __forceinline__ int trp(int p) { return ((p & 63) << 6) | (p >> 6); }
__device__ __forceinline__ int pix_of(int k, int l) {
  if (k == 0) return l;
  if (k == 1) return trp(l);
  if (k == 2) return LL - 1 - l;
  return trp(LL - 1 - l);
}
__device__ __forceinline__ float b2f(bf16t v) {
  return __uint_as_float((unsigned)v << 16);
}
__device__ __forceinline__ bf16t f2b(float f) {  // round-to-nearest-even
  unsigned u = __float_as_uint(f);
  return (bf16t)((u + 0x7FFFu + ((u >> 16) & 1u)) >> 16);
}

// ---------------------------------------------------------------------------
// in_proj GEMM: x f32 -> xz bf16. 4 consecutive px/thread (as 2x f32x2),
// 8 outputs; weights block-uniform (SGPR). Packed v_pk_fma_f32 path.
// ---------------------------------------------------------------------------
__global__ __launch_bounds__(256) void gemm_in_k(const float* __restrict__ in,
                                                 const float* __restrict__ W,
                                                 bf16t* __restrict__ out) {
  const int tid = threadIdx.x;
  const int b  = blockIdx.z;
  const int o0 = blockIdx.y * 8;
  const int p0 = blockIdx.x * 1024 + tid * 4;
  const float* inb = in + (size_t)b * CIN * LL + p0;
  const float* Wb  = W + (size_t)o0 * CIN;
  f32x2 accL[8], accH[8];
#pragma unroll
  for (int j = 0; j < 8; ++j) { accL[j] = (f32x2){0.f, 0.f}; accH[j] = (f32x2){0.f, 0.f}; }
#pragma unroll 4
  for (int c = 0; c < CIN; c += 4) {
    float4 w[8];
#pragma unroll
    for (int j = 0; j < 8; ++j) w[j] = *(const float4*)&Wb[j * CIN + c];
    float4 xv[4];
#pragma unroll
    for (int t = 0; t < 4; ++t) xv[t] = *(const float4*)&inb[(size_t)(c + t) * LL];
#pragma unroll
    for (int j = 0; j < 8; ++j) {
#pragma unroll
      for (int t = 0; t < 4; ++t) {
        const float ws = t == 0 ? w[j].x : t == 1 ? w[j].y : t == 2 ? w[j].z : w[j].w;
        const f32x2 wv = {ws, ws};
        accL[j] = pkfma((f32x2){xv[t].x, xv[t].y}, wv, accL[j]);
        accH[j] = pkfma((f32x2){xv[t].z, xv[t].w}, wv, accH[j]);
      }
    }
  }
  bf16t* ob = out + (size_t)b * 384 * LL + p0;
#pragma unroll
  for (int j = 0; j < 8; ++j) {
    ushort4 st;
    st.x = f2b(accL[j][0]);
    st.y = f2b(accL[j][1]);
    st.z = f2b(accH[j][0]);
    st.w = f2b(accH[j][1]);
    *(ushort4*)&ob[(size_t)(o0 + j) * LL] = st;
  }
}

// ---------------------------------------------------------------------------
// out_proj GEMM: u bf16 -> out f32. 4 px/thread (2x f32x2), 4 outputs.
// ---------------------------------------------------------------------------
__global__ __launch_bounds__(256) void gemm_out_k(const bf16t* __restrict__ in,
                                                  const float* __restrict__ W,
                                                  float* __restrict__ out) {
  const int tid = threadIdx.x;
  const int b  = blockIdx.z;
  const int o0 = blockIdx.y * 4;
  const int p0 = blockIdx.x * 1024 + tid * 4;
  const bf16t* inb = in + (size_t)b * DIN * LL + p0;
  const float* Wb  = W + (size_t)o0 * DIN;
  f32x2 accL[4], accH[4];
#pragma unroll
  for (int j = 0; j < 4; ++j) { accL[j] = (f32x2){0.f, 0.f}; accH[j] = (f32x2){0.f, 0.f}; }
#pragma unroll 4
  for (int c = 0; c < DIN; c += 4) {
    float4 w[4];
#pragma unroll
    for (int j = 0; j < 4; ++j) w[j] = *(const float4*)&Wb[j * DIN + c];
    f32x2 xlo[4], xhi[4];
#pragma unroll
    for (int t = 0; t < 4; ++t) {
      ushort4 xu = *(const ushort4*)&inb[(size_t)(c + t) * LL];
      xlo[t] = (f32x2){b2f(xu.x), b2f(xu.y)};
      xhi[t] = (f32x2){b2f(xu.z), b2f(xu.w)};
    }
#pragma unroll
    for (int j = 0; j < 4; ++j) {
#pragma unroll
      for (int t = 0; t < 4; ++t) {
        const float ws = t == 0 ? w[j].x : t == 1 ? w[j].y : t == 2 ? w[j].z : w[j].w;
        const f32x2 wv = {ws, ws};
        accL[j] = pkfma(xlo[t], wv, accL[j]);
        accH[j] = pkfma(xhi[t], wv, accH[j]);
      }
    }
  }
  float* ob = out + (size_t)b * COUT * LL + p0;
#pragma unroll
  for (int j = 0; j < 4; ++j) {
    float4 st = make_float4(accL[j][0], accL[j][1], accH[j][0], accH[j][1]);
    *(float4*)&ob[(size_t)(o0 + j) * LL] = st;
  }
}

// ---------------------------------------------------------------------------
// PriorToWeights MLP -> Wg[B,4,L].  Block 0: transpose xpw -> xpwT[k][dd][8].
// ---------------------------------------------------------------------------
__global__ __launch_bounds__(256) void p2w_k(const float* __restrict__ prior,
                                             const float* __restrict__ alpha,
                                             const float* __restrict__ w1,
                                             const float* __restrict__ b1,
                                             const float* __restrict__ bnw,
                                             const float* __restrict__ bnb,
                                             const float* __restrict__ bnm,
                                             const float* __restrict__ bnv,
                                             const float* __restrict__ w2,
                                             const float* __restrict__ b2,
                                             const float* __restrict__ xpw,
                                             float* __restrict__ xpwT,
                                             float* __restrict__ Wg) {
  if (blockIdx.x == 0) {
    for (int idx = threadIdx.x; idx < KK * DIN * 8; idx += 256) {
      int kk = idx / (DIN * 8);
      int rem = idx % (DIN * 8);
      int dd = rem >> 3, c = rem & 7;
      xpwT[idx] = xpw[(kk * 8 + c) * DIN + dd];
    }
  }
  int idx = blockIdx.x * 256 + threadIdx.x;
  int p = idx & (LL - 1);
  int b = idx >> 12;
  float pr[4];
#pragma unroll
  for (int c = 0; c < 4; ++c) pr[c] = prior[((size_t)b * 4 + c) * LL + p];
  float s = sigf(alpha[0]);
  float g2[4];
#pragma unroll
  for (int j = 0; j < 4; ++j) g2[j] = b2[j];
  for (int o = 0; o < 32; ++o) {
    float g = b1[o];
#pragma unroll
    for (int c = 0; c < 4; ++c) g = fmaf(pr[c], w1[o * 4 + c], g);
    g = (g - bnm[o]) * rsqrtf(bnv[o] + 1e-5f) * bnw[o] + bnb[o];
    g = fmaxf(g, 0.0f);
#pragma unroll
    for (int j = 0; j < 4; ++j) g2[j] = fmaf(g, w2[j * 32 + o], g2[j]);
  }
#pragma unroll
  for (int j = 0; j < 4; ++j)
    Wg[((size_t)b * 4 + j) * LL + p] = 1.0f + s * (sigf(g2[j]) - 1.0f);
}

// ---------------------------------------------------------------------------
// FUSED conv+proj: xz bf16 in, xcT bf16 out, projS f32 (scan order).
// Conv taps packed as (s0,s1)/(s2,s3); x_proj packed as (a0,a1)/(a2,a3).
// ---------------------------------------------------------------------------
__global__ __launch_bounds__(1024) void convproj_k(const bf16t* __restrict__ xz,
                                                   const float* __restrict__ cw,
                                                   const float* __restrict__ cb,
                                                   const float* __restrict__ xpwT,
                                                   bf16t* __restrict__ xcT,
                                                   float* __restrict__ projS) {
  __shared__ float sX[96 * 65];   // 24.96 KB
  __shared__ float4 sP[512];      // 8 KB q-partials
  const int tid = threadIdx.x;
  const int b = blockIdx.y;
  const int h = blockIdx.x;
  const int px = tid & 63;
  const int ku = __builtin_amdgcn_readfirstlane((tid >> 6) & 3);
  const int hf = __builtin_amdgcn_readfirstlane((tid >> 8) & 1);
  const int q  = __builtin_amdgcn_readfirstlane(tid >> 9);
  f32x2 a01 = {0.f, 0.f}, a23 = {0.f, 0.f};

#pragma unroll
  for (int half = 0; half < 2; ++half) {
    // conv + bias + SiLU: 4 consecutive px per thread-iteration, pk-fma pairs
    for (int idx = tid; idx < 96 * 16; idx += 1024) {
      int ddl = idx >> 4, pq = idx & 15;
      int w0 = pq * 4;
      int dd = half * 96 + ddl;
      const bf16t* base = xz + ((size_t)b * 384 + dd) * LL + h * 64 + w0;
      const float* wp = cw + dd * 9;
      float bv = cb[dd];
      f32x2 s01 = {bv, bv}, s23 = {bv, bv};
#pragma unroll
      for (int dh = -1; dh <= 1; ++dh) {
        int hh = h + dh;
        if (hh < 0 || hh >= HH) continue;
        const bf16t* row = base + dh * 64;
        ushort4 cmu = *(const ushort4*)row;
        float cmx = b2f(cmu.x), cmy = b2f(cmu.y), cmz = b2f(cmu.z), cmw = b2f(cmu.w);
        float lf = (w0 > 0)  ? b2f(row[-1]) : 0.0f;
        float rt = (w0 < 60) ? b2f(row[4])  : 0.0f;
        float c0 = wp[(dh + 1) * 3], c1 = wp[(dh + 1) * 3 + 1], c2 = wp[(dh + 1) * 3 + 2];
        s01 = pkfma((f32x2){lf,  cmx}, (f32x2){c0, c0}, s01);
        s01 = pkfma((f32x2){cmx, cmy}, (f32x2){c1, c1}, s01);
        s01 = pkfma((f32x2){cmy, cmz}, (f32x2){c2, c2}, s01);
        s23 = pkfma((f32x2){cmy, cmz}, (f32x2){c0, c0}, s23);
        s23 = pkfma((f32x2){cmz, cmw}, (f32x2){c1, c1}, s23);
        s23 = pkfma((f32x2){cmw, rt},  (f32x2){c2, c2}, s23);
      }
      float* so = &sX[ddl * 65 + w0];
      float v0 = s01[0], v1 = s01[1], v2 = s23[0], v3 = s23[1];
      so[0] = v0 * sigf(v0);
      so[1] = v1 * sigf(v1);
      so[2] = v2 * sigf(v2);
      so[3] = v3 * sigf(v3);
    }
    __syncthreads();
    // transposed write xcT[b][p][half*96+ddl] (coalesced over ddl, bf16)
    for (int idx = tid; idx < 64 * 96; idx += 1024) {
      int pp = idx / 96, ddl = idx % 96;
      xcT[((size_t)b * LL + h * 64 + pp) * DIN + half * 96 + ddl] =
          f2b(sX[ddl * 65 + pp]);
    }
    // x_proj partial: packed accumulator pairs
    {
      const int ddl0 = q * 48;
      const float* wp = xpwT + (size_t)ku * (DIN * 8) + (half * 96 + ddl0) * 8 + hf * 4;
#pragma unroll 8
      for (int d48 = 0; d48 < 48; ++d48) {
        float xv = sX[(ddl0 + d48) * 65 + px];
        const float4 w4 = *(const float4*)(wp + d48 * 8);
        const f32x2 xv2 = {xv, xv};
        a01 = pkfma(xv2, (f32x2){w4.x, w4.y}, a01);
        a23 = pkfma(xv2, (f32x2){w4.z, w4.w}, a23);
      }
    }
    __syncthreads();
  }
  const int slot = tid & 511;
  if (q == 1) sP[slot] = make_float4(a01[0], a01[1], a23[0], a23[1]);
  __syncthreads();
  if (q == 0) {
    float4 o = sP[slot];
    float r0 = a01[0] + o.x, r1 = a01[1] + o.y, r2 = a23[0] + o.z, r3 = a23[1] + o.w;
    const int p = h * 64 + px;
    int l;
    if (ku == 0) l = p;
    else if (ku == 1) l = trp(p);
    else if (ku == 2) l = LL - 1 - p;
    else l = LL - 1 - trp(p);
    float* pb = projS + (((size_t)b * KK + ku) * LL + l) * 8 + hf * 4;
    *(float4*)pb = make_float4(r0, r1, r2, r3);
  }
}

// ---------------------------------------------------------------------------
// Scan pass 1 (PAIRED): xcT bf16; carries f32.
// ---------------------------------------------------------------------------
__global__ __launch_bounds__(192) void scan_part_k(const bf16t* __restrict__ xcT,
                                                   const float* __restrict__ projS,
                                                   const float* __restrict__ dtw,
                                                   const float* __restrict__ dtb,
                                                   const float* __restrict__ A_logs,
                                                   float* __restrict__ carrP,
                                                   float* __restrict__ carrH) {
  const int s = blockIdx.x, kp = blockIdx.y, b = blockIdx.z;
  const int d = threadIdx.x;
  const int kA = kp, kB = kp + 2;
  const int s2 = SS - 1 - s;
  const int kdA = kA * DIN + d, kdB = kB * DIN + d;
  float wrA[6], wrB[6];
#pragma unroll
  for (int r = 0; r < 6; ++r) { wrA[r] = dtw[kdA * 6 + r]; wrB[r] = dtw[kdB * 6 + r]; }
  const float biasA = dtb[kdA], biasB = dtb[kdB];
  const float AaA = -__expf(A_logs[kdA]), AaB = -__expf(A_logs[kdB]);
  const int l0 = s * LC;
  const int p0 = pix_of(kA, l0);
  const int dp = pix_of(kA, l0 + 1) - p0;
  const bf16t* xp = xcT + ((size_t)b * LL + p0) * DIN + d;
  const long xstep = (long)dp * DIN;
  const float* prA = projS + (((size_t)b * KK + kA) * LL + l0) * 8;
  const float* prB = projS + (((size_t)b * KK + kB) * LL + s2 * LC + (LC - 1)) * 8;
  float PA = 1.0f, HA = 0.0f, PB = 1.0f, HB = 0.0f;
#pragma unroll 2
  for (int j = 0; j < LC; ++j) {
    float4 a0 = *(const float4*)prA;
    float4 a1 = *(const float4*)(prA + 4);
    prA += 8;
    float4 b0 = *(const float4*)prB;
    float4 b1 = *(const float4*)(prB + 4);
    prB -= 8;
    float xv = b2f(*xp);
    xp += xstep;
    {
      float dtr = biasA;
      dtr = fmaf(a0.x, wrA[0], dtr);
      dtr = fmaf(a0.y, wrA[1], dtr);
      dtr = fmaf(a0.z, wrA[2], dtr);
      dtr = fmaf(a0.w, wrA[3], dtr);
      dtr = fmaf(a1.x, wrA[4], dtr);
      dtr = fmaf(a1.y, wrA[5], dtr);
      float e = exp2fast(fminf(dtr, 80.0f) * LOG2E);
      float u = log2fast(1.0f + e);
      float a = exp2fast(u * AaA);
      float dt = u * LN2;
      HA = fmaf(a, HA, dt * a1.z * xv);
      PA *= a;
    }
    {
      float dtr = biasB;
      dtr = fmaf(b0.x, wrB[0], dtr);
      dtr = fmaf(b0.y, wrB[1], dtr);
      dtr = fmaf(b0.z, wrB[2], dtr);
      dtr = fmaf(b0.w, wrB[3], dtr);
      dtr = fmaf(b1.x, wrB[4], dtr);
      dtr = fmaf(b1.y, wrB[5], dtr);
      float e = exp2fast(fminf(dtr, 80.0f) * LOG2E);
      float u = log2fast(1.0f + e);
      float a = exp2fast(u * AaB);
      float dt = u * LN2;
      HB = fmaf(PB, dt * b1.z * xv, HB);
      PB *= a;
    }
  }
  size_t oA = ((size_t)((b * KK + kA) * SS + s)) * DIN + d;
  size_t oB = ((size_t)((b * KK + kB) * SS + s2)) * DIN + d;
  carrP[oA] = PA;
  carrH[oA] = HA;
  carrP[oB] = PB;
  carrH[oB] = HB;
}

// ---------------------------------------------------------------------------
// Scan pass 2: serial combine of SS carries -> per-segment initial state h0
// ---------------------------------------------------------------------------
__global__ __launch_bounds__(192) void scan_fix_k(const float* __restrict__ carrP,
                                                  const float* __restrict__ carrH,
                                                  float* __restrict__ h0) {
  const int k = blockIdx.x, b = blockIdx.y, d = threadIdx.x;
  size_t base = ((size_t)(b * KK + k)) * SS * DIN + d;
  float h = 0.0f;
#pragma unroll 4
  for (int s = 0; s < SS; ++s) {
    h0[base + (size_t)s * DIN] = h;
    h = fmaf(carrP[base + (size_t)s * DIN], h, carrH[base + (size_t)s * DIN]);
  }
}

// ---------------------------------------------------------------------------
// Scan pass 3: apply + gate + paired merge; xcT bf16 in (reg-cached for dir B),
// ymT/ymT2 bf16 out.
// ---------------------------------------------------------------------------
__global__ __launch_bounds__(192) void scan_apply_k(const bf16t* __restrict__ xcT,
                                                    const float* __restrict__ projS,
                                                    const float* __restrict__ Wg,
                                                    const float* __restrict__ h0,
                                                    const float* __restrict__ dtw,
                                                    const float* __restrict__ dtb,
                                                    const float* __restrict__ A_logs,
                                                    const float* __restrict__ Ds,
                                                    bf16t* __restrict__ ymT,
                                                    bf16t* __restrict__ ymT2) {
  const int s = blockIdx.x, kp = blockIdx.y, b = blockIdx.z;
  const int d = threadIdx.x;
  __shared__ float sAcc[LC * DIN];  // 24 KB, column d thread-private
  float xr[LC];                     // register cache of this segment's xv
  {
    const int k = kp, kd = k * DIN + d;
    float wr[6];
#pragma unroll
    for (int r = 0; r < 6; ++r) wr[r] = dtw[kd * 6 + r];
    const float bias = dtb[kd];
    const float Aa = -__expf(A_logs[kd]);
    const float Dv = Ds[kd];
    const int l0 = s * LC;
    const int p0 = pix_of(k, l0);
    const int dp = pix_of(k, l0 + 1) - p0;
    const bf16t* xp = xcT + ((size_t)b * LL + p0) * DIN + d;
    const long xstep = (long)dp * DIN;
    const float* pr = projS + (((size_t)b * KK + k) * LL + l0) * 8;
    const float* wg = Wg + ((size_t)b * KK + k) * LL + l0;
    float h = h0[((size_t)((b * KK + k) * SS + s)) * DIN + d];
#pragma unroll
    for (int j = 0; j < LC; ++j) {
      float4 q0 = *(const float4*)pr;
      float4 q1 = *(const float4*)(pr + 4);
      pr += 8;
      float xv = b2f(*xp);
      xp += xstep;
      xr[j] = xv;
      float dtr = bias;
      dtr = fmaf(q0.x, wr[0], dtr);
      dtr = fmaf(q0.y, wr[1], dtr);
      dtr = fmaf(q0.z, wr[2], dtr);
      dtr = fmaf(q0.w, wr[3], dtr);
      dtr = fmaf(q1.x, wr[4], dtr);
      dtr = fmaf(q1.y, wr[5], dtr);
      float e = exp2fast(fminf(dtr, 80.0f) * LOG2E);
      float u = log2fast(1.0f + e);
      float a = exp2fast(u * Aa);
      float dt = u * LN2;
      h = fmaf(a, h, dt * q1.z * xv);
      sAcc[j * DIN + d] = fmaf(h, q1.w, Dv * xv) * wg[j];
    }
  }
  {
    const int k = kp + 2, kd = k * DIN + d;
    const int s2 = SS - 1 - s;
    float wr[6];
#pragma unroll
    for (int r = 0; r < 6; ++r) wr[r] = dtw[kd * 6 + r];
    const float bias = dtb[kd];
    const float Aa = -__expf(A_logs[kd]);
    const float Dv = Ds[kd];
    const int l0 = s2 * LC;
    const float* pr = projS + (((size_t)b * KK + k) * LL + l0) * 8;
    const float* wg = Wg + ((size_t)b * KK + k) * LL + l0;
    float h = h0[((size_t)((b * KK + k) * SS + s2)) * DIN + d];
#pragma unroll
    for (int j = 0; j < LC; ++j) {
      float4 q0 = *(const float4*)pr;
      float4 q1 = *(const float4*)(pr + 4);
      pr += 8;
      float xv = xr[LC - 1 - j];   // same pixels, reversed (static index)
      float dtr = bias;
      dtr = fmaf(q0.x, wr[0], dtr);
      dtr = fmaf(q0.y, wr[1], dtr);
      dtr = fmaf(q0.z, wr[2], dtr);
      dtr = fmaf(q0.w, wr[3], dtr);
      dtr = fmaf(q1.x, wr[4], dtr);
      dtr = fmaf(q1.y, wr[5], dtr);
      float e = exp2fast(fminf(dtr, 80.0f) * LOG2E);
      float u = log2fast(1.0f + e);
      float a = exp2fast(u * Aa);
      float dt = u * LN2;
      h = fmaf(a, h, dt * q1.z * xv);
      float y = fmaf(h, q1.w, Dv * xv) * wg[j];
      sAcc[(LC - 1 - j) * DIN + d] += y;
    }
  }
  bf16t* dst;
  if (kp == 0)
    dst = ymT + (size_t)b * (384 * (size_t)LL) + (size_t)(s * LC) * DIN + d;  // xz overlay
  else
    dst = ymT2 + ((size_t)b * LL + s * LC) * DIN + d;
#pragma unroll 4
  for (int j = 0; j < LC; ++j) dst[(size_t)j * DIN] = f2b(sAcc[j * DIN + d]);
}

// ---------------------------------------------------------------------------
// LayerNorm(channel) * silu(z): ym bf16 + z bf16 -> u bf16.
// ---------------------------------------------------------------------------
__global__ __launch_bounds__(256) void ln_silu_k(const bf16t* __restrict__ ymT,
                                                 const bf16t* __restrict__ ymT2,
                                                 const bf16t* __restrict__ xz,
                                                 const float* __restrict__ gamma,
                                                 const float* __restrict__ beta,
                                                 bf16t* __restrict__ u) {
  const int b = blockIdx.y;
  const int h = blockIdx.x;
  const int p0 = h * 64;
  __shared__ float sY[64 * 193];
  __shared__ float sS[4][64], sQ[4][64];
  const int tid = threadIdx.x;
  const bf16t* ymb = ymT + (size_t)b * (384 * (size_t)LL);  // xz overlay
  for (int idx = tid; idx < 64 * DIN; idx += 256) {
    int pp = idx / DIN, dd = idx % DIN;
    float v = b2f(ymb[(size_t)(p0 + pp) * DIN + dd]) +
              b2f(ymT2[((size_t)b * LL + pp * 64 + h) * DIN + dd]);
    sY[pp * 193 + dd] = v;
  }
  __syncthreads();
  const int px = tid & 63, g = tid >> 6;
  float sum = 0.0f, ss = 0.0f;
  for (int dd = g * 48; dd < g * 48 + 48; ++dd) {
    float v = sY[px * 193 + dd];
    sum += v;
    ss = fmaf(v, v, ss);
  }
  sS[g][px] = sum;
  sQ[g][px] = ss;
  __syncthreads();
  sum = sS[0][px] + sS[1][px] + sS[2][px] + sS[3][px];
  ss  = sQ[0][px] + sQ[1][px] + sQ[2][px] + sQ[3][px];
  const float mu = sum * (1.0f / DIN);
  float var = ss * (1.0f / DIN) - mu * mu;
  const float rstd = rsqrtf(fmaxf(var, 0.0f) + 1e-5f);
  const bf16t* zb = xz + ((size_t)b * 384 + DIN) * LL + p0 + px;
  bf16t* ub = u + (size_t)b * DIN * LL + p0 + px;
  for (int dd = g * 48; dd < g * 48 + 48; ++dd) {
    float v = sY[px * 193 + dd];
    float z = b2f(zb[(size_t)dd * LL]);
    float tn = fmaf((v - mu) * rstd, gamma[dd], beta[dd]);
    ub[(size_t)dd * LL] = f2b(tn * (z * sigf(z)));
  }
}

// ---------------------------------------------------------------------------
extern "C" void kernel_launch(void* const* d_in, const int* in_sizes, int n_in,
                              void* d_out, int out_size, void* d_ws, size_t ws_size,
                              hipStream_t stream) {
  const float* x      = (const float*)d_in[0];
  const float* prior  = (const float*)d_in[1];
  const float* alpha  = (const float*)d_in[2];
  const float* ipw    = (const float*)d_in[3];
  const float* cw     = (const float*)d_in[4];
  const float* cb     = (const float*)d_in[5];
  const float* xpw    = (const float*)d_in[6];
  const float* dtw    = (const float*)d_in[7];
  const float* dtb    = (const float*)d_in[8];
  const float* A_logs = (const float*)d_in[9];
  const float* Ds     = (const float*)d_in[10];
  const float* onw    = (const float*)d_in[11];
  const float* onb    = (const float*)d_in[12];
  const float* opw    = (const float*)d_in[13];
  const float* w1     = (const float*)d_in[14];
  const float* b1     = (const float*)d_in[15];
  const float* bnw    = (const float*)d_in[16];
  const float* bnb    = (const float*)d_in[17];
  const float* bnm    = (const float*)d_in[18];
  const float* bnv    = (const float*)d_in[19];
  const float* w2     = (const float*)d_in[20];
  const float* b2     = (const float*)d_in[21];
  float* out = (float*)d_out;

  char* ws = (char*)d_ws;
  // bf16 intermediates; footprint ends at 64,512,000 B.
  bf16t* xz    = (bf16t*)(ws);              // [B,384,L] bf16  25.2 MB
  bf16t* xcT   = (bf16t*)(ws + 25165824);   // [B,L,192] bf16  12.6 MB (-> u)
  bf16t* ymT2  = (bf16t*)(ws + 37748736);   // [B,L,192] bf16  12.6 MB
  float* projS = (float*)(ws + 50331648);   // [B,K,L,8] f32    4.2 MB
  float* Wgb   = (float*)(ws + 54525952);   // [B,4,L]          0.5 MB
  float* carrP = (float*)(ws + 55050240);   // [B,K,SS,192]     3.0 MB
  float* carrH = (float*)(ws + 58195968);   // [B,K,SS,192]     3.0 MB
  float* h0b   = (float*)(ws + 61341696);   // [B,K,SS,192]     3.0 MB
  float* xpwT  = (float*)(ws + 64487424);   // [K,DIN,8]       24.6 KB (ends 64512000)
  bf16t* ymT   = xz;   // overlay: x_ssm half of xz (dead after convproj)
  bf16t* u     = xcT;  // xcT dead after scan_apply_k

  // 1) in_proj GEMM -> xz bf16 (packed fp32)
  gemm_in_k<<<dim3(LL / 1024, 384 / 8, BB), 256, 0, stream>>>(x, ipw, xz);
  // 2) prior -> direction gates (+ weight transpose in block 0)
  p2w_k<<<(BB * LL) / 256, 256, 0, stream>>>(prior, alpha, w1, b1, bnw, bnb, bnm,
                                             bnv, w2, b2, xpw, xpwT, Wgb);
  // 3) fused dwconv+SiLU + x_proj(scan-order) + transpose (packed fp32)
  convproj_k<<<dim3(HH, BB), 1024, 0, stream>>>(xz, cw, cb, xpwT, xcT, projS);
  // 4) scan: paired segment carries
  scan_part_k<<<dim3(SS, 2, BB), 192, 0, stream>>>(xcT, projS, dtw, dtb, A_logs,
                                                   carrP, carrH);
  // 5) scan: serial carry combine
  scan_fix_k<<<dim3(KK, BB), 192, 0, stream>>>(carrP, carrH, h0b);
  // 6) scan: apply + gate + paired merge (ymT overlaid on xz x_ssm half)
  scan_apply_k<<<dim3(SS, 2, BB), 192, 0, stream>>>(xcT, projS, Wgb, h0b, dtw, dtb,
                                                    A_logs, Ds, ymT, ymT2);
  // 7) LayerNorm(channel) * silu(z) -> u bf16
  ln_silu_k<<<dim3(HH, BB), 256, 0, stream>>>(ymT, ymT2, xz, onw, onb, u);
  // 8) out_proj GEMM: u bf16 -> out f32 (packed fp32)
  gemm_out_k<<<dim3(LL / 1024, COUT / 4, BB), 256, 0, stream>>>(u, opw, out);
}

// Round 20
// 174.569 us; speedup vs baseline: 1.5882x; 1.0374x over previous
//
#include <hip/hip_runtime.h>

#define BB   8
#define CIN  96
#define DIN  192
#define HH   64
#define WW   64
#define LL   4096
#define KK   4
#define COUT 96
#define SS   128  // scan segments
#define LC   32   // segment length = LL/SS

#define LOG2E 1.4426950408889634f
#define LN2   0.6931471805599453f

typedef unsigned short bf16t;
typedef float f32x2 __attribute__((ext_vector_type(2)));
typedef float f32x4 __attribute__((ext_vector_type(4)));
typedef short bf16x8s __attribute__((ext_vector_type(8)));

__device__ __forceinline__ f32x2 pkfma(f32x2 a, f32x2 b, f32x2 c) {
#if __has_builtin(__builtin_elementwise_fma)
  return __builtin_elementwise_fma(a, b, c);
#else
  f32x2 r;
  r[0] = fmaf(a[0], b[0], c[0]);
  r[1] = fmaf(a[1], b[1], c[1]);
  return r;
#endif
}

__device__ __forceinline__ float exp2fast(float x) { return __builtin_amdgcn_exp2f(x); }
__device__ __forceinline__ float log2fast(float x) { return __builtin_amdgcn_logf(x); }
__device__ __forceinline__ float sigf(float x) { return 1.0f / (1.0f + __expf(-x)); }
__device__ __forceinline__ int trp(int p) { return ((p & 63) << 6) | (p >> 6); }
__device__ __forceinline__ int pix_of(int k, int l) {
  if (k == 0) return l;
  if (k == 1) return trp(l);
  if (k == 2) return LL - 1 - l;
  return trp(LL - 1 - l);
}
__device__ __forceinline__ float b2f(bf16t v) {
  return __uint_as_float((unsigned)v << 16);
}
__device__ __forceinline__ bf16t f2b(float f) {  // round-to-nearest-even
  unsigned u = __float_as_uint(f);
  return (bf16t)((u + 0x7FFFu + ((u >> 16) & 1u)) >> 16);
}

// ---------------------------------------------------------------------------
// in_proj via MFMA bf16: xz[o,p] = sum_c W[o,c] x[c,p].
// A=W (m=o,k=c), B=x (k=c,n=px). Block: 4 waves x 6 m-tiles x 32 px.
// ---------------------------------------------------------------------------
__global__ __launch_bounds__(256) void gemm_in_mfma_k(const float* __restrict__ x,
                                                      const bf16t* __restrict__ Wb,
                                                      bf16t* __restrict__ out) {
  __shared__ bf16t ldsB[32 * 104];  // [px][c] bf16, pad 104
  const int tid = threadIdx.x;
  const int b = blockIdx.z;
  const int p0 = blockIdx.x * 32;
  // stage x tile (f32 -> bf16), coalesced over px
  for (int idx = tid; idx < CIN * 32; idx += 256) {
    int c = idx >> 5, px = idx & 31;
    ldsB[px * 104 + c] = f2b(x[((size_t)b * CIN + c) * LL + p0 + px]);
  }
  __syncthreads();
  const int wave = tid >> 6, lane = tid & 63;
  const int lm = lane & 15, kc = lane >> 4;
  // B fragments [nf][ks]: n = nf*16+lm, k = ks*32 + kc*8 + i  (one b128 each)
  bf16x8s bfrag[2][3];
#pragma unroll
  for (int nf = 0; nf < 2; ++nf)
#pragma unroll
    for (int ks = 0; ks < 3; ++ks)
      bfrag[nf][ks] = *(const bf16x8s*)&ldsB[(nf * 16 + lm) * 104 + ks * 32 + kc * 8];
  bf16t* ob = out + (size_t)b * 384 * LL + p0;
#pragma unroll
  for (int mti = 0; mti < 6; ++mti) {
    const int o0 = (wave * 6 + mti) * 16;
    bf16x8s afrag[3];
#pragma unroll
    for (int ks = 0; ks < 3; ++ks)
      afrag[ks] = *(const bf16x8s*)&Wb[(size_t)(o0 + lm) * CIN + ks * 32 + kc * 8];
    f32x4 acc0 = {0.f, 0.f, 0.f, 0.f};
    f32x4 acc1 = {0.f, 0.f, 0.f, 0.f};
#pragma unroll
    for (int ks = 0; ks < 3; ++ks) {
      acc0 = __builtin_amdgcn_mfma_f32_16x16x32_bf16(afrag[ks], bfrag[0][ks], acc0, 0, 0, 0);
      acc1 = __builtin_amdgcn_mfma_f32_16x16x32_bf16(afrag[ks], bfrag[1][ks], acc1, 0, 0, 0);
    }
    // D: col(n)=lane&15, row(m)=(lane>>4)*4+r   (verified mapping)
#pragma unroll
    for (int r = 0; r < 4; ++r) {
      ob[(size_t)(o0 + kc * 4 + r) * LL + lm]      = f2b(acc0[r]);
      ob[(size_t)(o0 + kc * 4 + r) * LL + 16 + lm] = f2b(acc1[r]);
    }
  }
}

// ---------------------------------------------------------------------------
// out_proj GEMM: u bf16 -> out f32. 4 px/thread (2x f32x2), 4 outputs.
// ---------------------------------------------------------------------------
__global__ __launch_bounds__(256) void gemm_out_k(const bf16t* __restrict__ in,
                                                  const float* __restrict__ W,
                                                  float* __restrict__ out) {
  const int tid = threadIdx.x;
  const int b  = blockIdx.z;
  const int o0 = blockIdx.y * 4;
  const int p0 = blockIdx.x * 1024 + tid * 4;
  const bf16t* inb = in + (size_t)b * DIN * LL + p0;
  const float* Wb  = W + (size_t)o0 * DIN;
  f32x2 accL[4], accH[4];
#pragma unroll
  for (int j = 0; j < 4; ++j) { accL[j] = (f32x2){0.f, 0.f}; accH[j] = (f32x2){0.f, 0.f}; }
#pragma unroll 4
  for (int c = 0; c < DIN; c += 4) {
    float4 w[4];
#pragma unroll
    for (int j = 0; j < 4; ++j) w[j] = *(const float4*)&Wb[j * DIN + c];
    f32x2 xlo[4], xhi[4];
#pragma unroll
    for (int t = 0; t < 4; ++t) {
      ushort4 xu = *(const ushort4*)&inb[(size_t)(c + t) * LL];
      xlo[t] = (f32x2){b2f(xu.x), b2f(xu.y)};
      xhi[t] = (f32x2){b2f(xu.z), b2f(xu.w)};
    }
#pragma unroll
    for (int j = 0; j < 4; ++j) {
#pragma unroll
      for (int t = 0; t < 4; ++t) {
        const float ws = t == 0 ? w[j].x : t == 1 ? w[j].y : t == 2 ? w[j].z : w[j].w;
        const f32x2 wv = {ws, ws};
        accL[j] = pkfma(xlo[t], wv, accL[j]);
        accH[j] = pkfma(xhi[t], wv, accH[j]);
      }
    }
  }
  float* ob = out + (size_t)b * COUT * LL + p0;
#pragma unroll
  for (int j = 0; j < 4; ++j) {
    float4 st = make_float4(accL[j][0], accL[j][1], accH[j][0], accH[j][1]);
    *(float4*)&ob[(size_t)(o0 + j) * LL] = st;
  }
}

// ---------------------------------------------------------------------------
// PriorToWeights MLP -> Wg[B,4,L].  Block 0: transpose xpw -> xpwT[k][dd][8].
// Block 1: convert in_proj weights to bf16 (ipwb[o][c]).
// ---------------------------------------------------------------------------
__global__ __launch_bounds__(256) void p2w_k(const float* __restrict__ prior,
                                             const float* __restrict__ alpha,
                                             const float* __restrict__ w1,
                                             const float* __restrict__ b1,
                                             const float* __restrict__ bnw,
                                             const float* __restrict__ bnb,
                                             const float* __restrict__ bnm,
                                             const float* __restrict__ bnv,
                                             const float* __restrict__ w2,
                                             const float* __restrict__ b2,
                                             const float* __restrict__ xpw,
                                             const float* __restrict__ ipw,
                                             float* __restrict__ xpwT,
                                             bf16t* __restrict__ ipwb,
                                             float* __restrict__ Wg) {
  if (blockIdx.x == 0) {
    for (int idx = threadIdx.x; idx < KK * DIN * 8; idx += 256) {
      int kk = idx / (DIN * 8);
      int rem = idx % (DIN * 8);
      int dd = rem >> 3, c = rem & 7;
      xpwT[idx] = xpw[(kk * 8 + c) * DIN + dd];
    }
  }
  if (blockIdx.x == 1) {
    for (int idx = threadIdx.x; idx < 384 * CIN; idx += 256)
      ipwb[idx] = f2b(ipw[idx]);
  }
  int idx = blockIdx.x * 256 + threadIdx.x;
  int p = idx & (LL - 1);
  int b = idx >> 12;
  float pr[4];
#pragma unroll
  for (int c = 0; c < 4; ++c) pr[c] = prior[((size_t)b * 4 + c) * LL + p];
  float s = sigf(alpha[0]);
  float g2[4];
#pragma unroll
  for (int j = 0; j < 4; ++j) g2[j] = b2[j];
  for (int o = 0; o < 32; ++o) {
    float g = b1[o];
#pragma unroll
    for (int c = 0; c < 4; ++c) g = fmaf(pr[c], w1[o * 4 + c], g);
    g = (g - bnm[o]) * rsqrtf(bnv[o] + 1e-5f) * bnw[o] + bnb[o];
    g = fmaxf(g, 0.0f);
#pragma unroll
    for (int j = 0; j < 4; ++j) g2[j] = fmaf(g, w2[j * 32 + o], g2[j]);
  }
#pragma unroll
  for (int j = 0; j < 4; ++j)
    Wg[((size_t)b * 4 + j) * LL + p] = 1.0f + s * (sigf(g2[j]) - 1.0f);
}

// ---------------------------------------------------------------------------
// FUSED conv+proj: xz bf16 in, xcT bf16 out, projS f32 (scan order).
// ---------------------------------------------------------------------------
__global__ __launch_bounds__(1024) void convproj_k(const bf16t* __restrict__ xz,
                                                   const float* __restrict__ cw,
                                                   const float* __restrict__ cb,
                                                   const float* __restrict__ xpwT,
                                                   bf16t* __restrict__ xcT,
                                                   float* __restrict__ projS) {
  __shared__ float sX[96 * 65];   // 24.96 KB
  __shared__ float4 sP[512];      // 8 KB q-partials
  const int tid = threadIdx.x;
  const int b = blockIdx.y;
  const int h = blockIdx.x;
  const int px = tid & 63;
  const int ku = __builtin_amdgcn_readfirstlane((tid >> 6) & 3);
  const int hf = __builtin_amdgcn_readfirstlane((tid >> 8) & 1);
  const int q  = __builtin_amdgcn_readfirstlane(tid >> 9);
  f32x2 a01 = {0.f, 0.f}, a23 = {0.f, 0.f};

#pragma unroll
  for (int half = 0; half < 2; ++half) {
    for (int idx = tid; idx < 96 * 16; idx += 1024) {
      int ddl = idx >> 4, pq = idx & 15;
      int w0 = pq * 4;
      int dd = half * 96 + ddl;
      const bf16t* base = xz + ((size_t)b * 384 + dd) * LL + h * 64 + w0;
      const float* wp = cw + dd * 9;
      float bv = cb[dd];
      f32x2 s01 = {bv, bv}, s23 = {bv, bv};
#pragma unroll
      for (int dh = -1; dh <= 1; ++dh) {
        int hh = h + dh;
        if (hh < 0 || hh >= HH) continue;
        const bf16t* row = base + dh * 64;
        ushort4 cmu = *(const ushort4*)row;
        float cmx = b2f(cmu.x), cmy = b2f(cmu.y), cmz = b2f(cmu.z), cmw = b2f(cmu.w);
        float lf = (w0 > 0)  ? b2f(row[-1]) : 0.0f;
        float rt = (w0 < 60) ? b2f(row[4])  : 0.0f;
        float c0 = wp[(dh + 1) * 3], c1 = wp[(dh + 1) * 3 + 1], c2 = wp[(dh + 1) * 3 + 2];
        s01 = pkfma((f32x2){lf,  cmx}, (f32x2){c0, c0}, s01);
        s01 = pkfma((f32x2){cmx, cmy}, (f32x2){c1, c1}, s01);
        s01 = pkfma((f32x2){cmy, cmz}, (f32x2){c2, c2}, s01);
        s23 = pkfma((f32x2){cmy, cmz}, (f32x2){c0, c0}, s23);
        s23 = pkfma((f32x2){cmz, cmw}, (f32x2){c1, c1}, s23);
        s23 = pkfma((f32x2){cmw, rt},  (f32x2){c2, c2}, s23);
      }
      float* so = &sX[ddl * 65 + w0];
      float v0 = s01[0], v1 = s01[1], v2 = s23[0], v3 = s23[1];
      so[0] = v0 * sigf(v0);
      so[1] = v1 * sigf(v1);
      so[2] = v2 * sigf(v2);
      so[3] = v3 * sigf(v3);
    }
    __syncthreads();
    for (int idx = tid; idx < 64 * 96; idx += 1024) {
      int pp = idx / 96, ddl = idx % 96;
      xcT[((size_t)b * LL + h * 64 + pp) * DIN + half * 96 + ddl] =
          f2b(sX[ddl * 65 + pp]);
    }
    {
      const int ddl0 = q * 48;
      const float* wp = xpwT + (size_t)ku * (DIN * 8) + (half * 96 + ddl0) * 8 + hf * 4;
#pragma unroll 8
      for (int d48 = 0; d48 < 48; ++d48) {
        float xv = sX[(ddl0 + d48) * 65 + px];
        const float4 w4 = *(const float4*)(wp + d48 * 8);
        const f32x2 xv2 = {xv, xv};
        a01 = pkfma(xv2, (f32x2){w4.x, w4.y}, a01);
        a23 = pkfma(xv2, (f32x2){w4.z, w4.w}, a23);
      }
    }
    __syncthreads();
  }
  const int slot = tid & 511;
  if (q == 1) sP[slot] = make_float4(a01[0], a01[1], a23[0], a23[1]);
  __syncthreads();
  if (q == 0) {
    float4 o = sP[slot];
    float r0 = a01[0] + o.x, r1 = a01[1] + o.y, r2 = a23[0] + o.z, r3 = a23[1] + o.w;
    const int p = h * 64 + px;
    int l;
    if (ku == 0) l = p;
    else if (ku == 1) l = trp(p);
    else if (ku == 2) l = LL - 1 - p;
    else l = LL - 1 - trp(p);
    float* pb = projS + (((size_t)b * KK + ku) * LL + l) * 8 + hf * 4;
    *(float4*)pb = make_float4(r0, r1, r2, r3);
  }
}

// ---------------------------------------------------------------------------
// Scan pass 1 (PAIRED): xcT bf16; carries f32.
// ---------------------------------------------------------------------------
__global__ __launch_bounds__(192) void scan_part_k(const bf16t* __restrict__ xcT,
                                                   const float* __restrict__ projS,
                                                   const float* __restrict__ dtw,
                                                   const float* __restrict__ dtb,
                                                   const float* __restrict__ A_logs,
                                                   float* __restrict__ carrP,
                                                   float* __restrict__ carrH) {
  const int s = blockIdx.x, kp = blockIdx.y, b = blockIdx.z;
  const int d = threadIdx.x;
  const int kA = kp, kB = kp + 2;
  const int s2 = SS - 1 - s;
  const int kdA = kA * DIN + d, kdB = kB * DIN + d;
  float wrA[6], wrB[6];
#pragma unroll
  for (int r = 0; r < 6; ++r) { wrA[r] = dtw[kdA * 6 + r]; wrB[r] = dtw[kdB * 6 + r]; }
  const float biasA = dtb[kdA], biasB = dtb[kdB];
  const float AaA = -__expf(A_logs[kdA]), AaB = -__expf(A_logs[kdB]);
  const int l0 = s * LC;
  const int p0 = pix_of(kA, l0);
  const int dp = pix_of(kA, l0 + 1) - p0;
  const bf16t* xp = xcT + ((size_t)b * LL + p0) * DIN + d;
  const long xstep = (long)dp * DIN;
  const float* prA = projS + (((size_t)b * KK + kA) * LL + l0) * 8;
  const float* prB = projS + (((size_t)b * KK + kB) * LL + s2 * LC + (LC - 1)) * 8;
  float PA = 1.0f, HA = 0.0f, PB = 1.0f, HB = 0.0f;
#pragma unroll 2
  for (int j = 0; j < LC; ++j) {
    float4 a0 = *(const float4*)prA;
    float4 a1 = *(const float4*)(prA + 4);
    prA += 8;
    float4 b0 = *(const float4*)prB;
    float4 b1 = *(const float4*)(prB + 4);
    prB -= 8;
    float xv = b2f(*xp);
    xp += xstep;
    {
      float dtr = biasA;
      dtr = fmaf(a0.x, wrA[0], dtr);
      dtr = fmaf(a0.y, wrA[1], dtr);
      dtr = fmaf(a0.z, wrA[2], dtr);
      dtr = fmaf(a0.w, wrA[3], dtr);
      dtr = fmaf(a1.x, wrA[4], dtr);
      dtr = fmaf(a1.y, wrA[5], dtr);
      float e = exp2fast(fminf(dtr, 80.0f) * LOG2E);
      float u = log2fast(1.0f + e);
      float a = exp2fast(u * AaA);
      float dt = u * LN2;
      HA = fmaf(a, HA, dt * a1.z * xv);
      PA *= a;
    }
    {
      float dtr = biasB;
      dtr = fmaf(b0.x, wrB[0], dtr);
      dtr = fmaf(b0.y, wrB[1], dtr);
      dtr = fmaf(b0.z, wrB[2], dtr);
      dtr = fmaf(b0.w, wrB[3], dtr);
      dtr = fmaf(b1.x, wrB[4], dtr);
      dtr = fmaf(b1.y, wrB[5], dtr);
      float e = exp2fast(fminf(dtr, 80.0f) * LOG2E);
      float u = log2fast(1.0f + e);
      float a = exp2fast(u * AaB);
      float dt = u * LN2;
      HB = fmaf(PB, dt * b1.z * xv, HB);
      PB *= a;
    }
  }
  size_t oA = ((size_t)((b * KK + kA) * SS + s)) * DIN + d;
  size_t oB = ((size_t)((b * KK + kB) * SS + s2)) * DIN + d;
  carrP[oA] = PA;
  carrH[oA] = HA;
  carrP[oB] = PB;
  carrH[oB] = HB;
}

// ---------------------------------------------------------------------------
// Scan pass 2: serial combine of SS carries -> per-segment initial state h0
// ---------------------------------------------------------------------------
__global__ __launch_bounds__(192) void scan_fix_k(const float* __restrict__ carrP,
                                                  const float* __restrict__ carrH,
                                                  float* __restrict__ h0) {
  const int k = blockIdx.x, b = blockIdx.y, d = threadIdx.x;
  size_t base = ((size_t)(b * KK + k)) * SS * DIN + d;
  float h = 0.0f;
#pragma unroll 4
  for (int s = 0; s < SS; ++s) {
    h0[base + (size_t)s * DIN] = h;
    h = fmaf(carrP[base + (size_t)s * DIN], h, carrH[base + (size_t)s * DIN]);
  }
}

// ---------------------------------------------------------------------------
// Scan pass 3: apply + gate + paired merge; xcT bf16 in (reg-cached for dir B),
// ymT/ymT2 bf16 out.
// ---------------------------------------------------------------------------
__global__ __launch_bounds__(192) void scan_apply_k(const bf16t* __restrict__ xcT,
                                                    const float* __restrict__ projS,
                                                    const float* __restrict__ Wg,
                                                    const float* __restrict__ h0,
                                                    const float* __restrict__ dtw,
                                                    const float* __restrict__ dtb,
                                                    const float* __restrict__ A_logs,
                                                    const float* __restrict__ Ds,
                                                    bf16t* __restrict__ ymT,
                                                    bf16t* __restrict__ ymT2) {
  const int s = blockIdx.x, kp = blockIdx.y, b = blockIdx.z;
  const int d = threadIdx.x;
  __shared__ float sAcc[LC * DIN];  // 24 KB, column d thread-private
  float xr[LC];                     // register cache of this segment's xv
  {
    const int k = kp, kd = k * DIN + d;
    float wr[6];
#pragma unroll
    for (int r = 0; r < 6; ++r) wr[r] = dtw[kd * 6 + r];
    const float bias = dtb[kd];
    const float Aa = -__expf(A_logs[kd]);
    const float Dv = Ds[kd];
    const int l0 = s * LC;
    const int p0 = pix_of(k, l0);
    const int dp = pix_of(k, l0 + 1) - p0;
    const bf16t* xp = xcT + ((size_t)b * LL + p0) * DIN + d;
    const long xstep = (long)dp * DIN;
    const float* pr = projS + (((size_t)b * KK + k) * LL + l0) * 8;
    const float* wg = Wg + ((size_t)b * KK + k) * LL + l0;
    float h = h0[((size_t)((b * KK + k) * SS + s)) * DIN + d];
#pragma unroll
    for (int j = 0; j < LC; ++j) {
      float4 q0 = *(const float4*)pr;
      float4 q1 = *(const float4*)(pr + 4);
      pr += 8;
      float xv = b2f(*xp);
      xp += xstep;
      xr[j] = xv;
      float dtr = bias;
      dtr = fmaf(q0.x, wr[0], dtr);
      dtr = fmaf(q0.y, wr[1], dtr);
      dtr = fmaf(q0.z, wr[2], dtr);
      dtr = fmaf(q0.w, wr[3], dtr);
      dtr = fmaf(q1.x, wr[4], dtr);
      dtr = fmaf(q1.y, wr[5], dtr);
      float e = exp2fast(fminf(dtr, 80.0f) * LOG2E);
      float u = log2fast(1.0f + e);
      float a = exp2fast(u * Aa);
      float dt = u * LN2;
      h = fmaf(a, h, dt * q1.z * xv);
      sAcc[j * DIN + d] = fmaf(h, q1.w, Dv * xv) * wg[j];
    }
  }
  {
    const int k = kp + 2, kd = k * DIN + d;
    const int s2 = SS - 1 - s;
    float wr[6];
#pragma unroll
    for (int r = 0; r < 6; ++r) wr[r] = dtw[kd * 6 + r];
    const float bias = dtb[kd];
    const float Aa = -__expf(A_logs[kd]);
    const float Dv = Ds[kd];
    const int l0 = s2 * LC;
    const float* pr = projS + (((size_t)b * KK + k) * LL + l0) * 8;
    const float* wg = Wg + ((size_t)b * KK + k) * LL + l0;
    float h = h0[((size_t)((b * KK + k) * SS + s2)) * DIN + d];
#pragma unroll
    for (int j = 0; j < LC; ++j) {
      float4 q0 = *(const float4*)pr;
      float4 q1 = *(const float4*)(pr + 4);
      pr += 8;
      float xv = xr[LC - 1 - j];   // same pixels, reversed (static index)
      float dtr = bias;
      dtr = fmaf(q0.x, wr[0], dtr);
      dtr = fmaf(q0.y, wr[1], dtr);
      dtr = fmaf(q0.z, wr[2], dtr);
      dtr = fmaf(q0.w, wr[3], dtr);
      dtr = fmaf(q1.x, wr[4], dtr);
      dtr = fmaf(q1.y, wr[5], dtr);
      float e = exp2fast(fminf(dtr, 80.0f) * LOG2E);
      float u = log2fast(1.0f + e);
      float a = exp2fast(u * Aa);
      float dt = u * LN2;
      h = fmaf(a, h, dt * q1.z * xv);
      float y = fmaf(h, q1.w, Dv * xv) * wg[j];
      sAcc[(LC - 1 - j) * DIN + d] += y;
    }
  }
  bf16t* dst;
  if (kp == 0)
    dst = ymT + (size_t)b * (384 * (size_t)LL) + (size_t)(s * LC) * DIN + d;  // xz overlay
  else
    dst = ymT2 + ((size_t)b * LL + s * LC) * DIN + d;
#pragma unroll 4
  for (int j = 0; j < LC; ++j) dst[(size_t)j * DIN] = f2b(sAcc[j * DIN + d]);
}

// ---------------------------------------------------------------------------
// LayerNorm(channel) * silu(z): ym bf16 + z bf16 -> u bf16.
// ---------------------------------------------------------------------------
__global__ __launch_bounds__(256) void ln_silu_k(const bf16t* __restrict__ ymT,
                                                 const bf16t* __restrict__ ymT2,
                                                 const bf16t* __restrict__ xz,
                                                 const float* __restrict__ gamma,
                                                 const float* __restrict__ beta,
                                                 bf16t* __restrict__ u) {
  const int b = blockIdx.y;
  const int h = blockIdx.x;
  const int p0 = h * 64;
  __shared__ float sY[64 * 193];
  __shared__ float sS[4][64], sQ[4][64];
  const int tid = threadIdx.x;
  const bf16t* ymb = ymT + (size_t)b * (384 * (size_t)LL);  // xz overlay
  for (int idx = tid; idx < 64 * DIN; idx += 256) {
    int pp = idx / DIN, dd = idx % DIN;
    float v = b2f(ymb[(size_t)(p0 + pp) * DIN + dd]) +
              b2f(ymT2[((size_t)b * LL + pp * 64 + h) * DIN + dd]);
    sY[pp * 193 + dd] = v;
  }
  __syncthreads();
  const int px = tid & 63, g = tid >> 6;
  float sum = 0.0f, ss = 0.0f;
  for (int dd = g * 48; dd < g * 48 + 48; ++dd) {
    float v = sY[px * 193 + dd];
    sum += v;
    ss = fmaf(v, v, ss);
  }
  sS[g][px] = sum;
  sQ[g][px] = ss;
  __syncthreads();
  sum = sS[0][px] + sS[1][px] + sS[2][px] + sS[3][px];
  ss  = sQ[0][px] + sQ[1][px] + sQ[2][px] + sQ[3][px];
  const float mu = sum * (1.0f / DIN);
  float var = ss * (1.0f / DIN) - mu * mu;
  const float rstd = rsqrtf(fmaxf(var, 0.0f) + 1e-5f);
  const bf16t* zb = xz + ((size_t)b * 384 + DIN) * LL + p0 + px;
  bf16t* ub = u + (size_t)b * DIN * LL + p0 + px;
  for (int dd = g * 48; dd < g * 48 + 48; ++dd) {
    float v = sY[px * 193 + dd];
    float z = b2f(zb[(size_t)dd * LL]);
    float tn = fmaf((v - mu) * rstd, gamma[dd], beta[dd]);
    ub[(size_t)dd * LL] = f2b(tn * (z * sigf(z)));
  }
}

// ---------------------------------------------------------------------------
extern "C" void kernel_launch(void* const* d_in, const int* in_sizes, int n_in,
                              void* d_out, int out_size, void* d_ws, size_t ws_size,
                              hipStream_t stream) {
  const float* x      = (const float*)d_in[0];
  const float* prior  = (const float*)d_in[1];
  const float* alpha  = (const float*)d_in[2];
  const float* ipw    = (const float*)d_in[3];
  const float* cw     = (const float*)d_in[4];
  const float* cb     = (const float*)d_in[5];
  const float* xpw    = (const float*)d_in[6];
  const float* dtw    = (const float*)d_in[7];
  const float* dtb    = (const float*)d_in[8];
  const float* A_logs = (const float*)d_in[9];
  const float* Ds     = (const float*)d_in[10];
  const float* onw    = (const float*)d_in[11];
  const float* onb    = (const float*)d_in[12];
  const float* opw    = (const float*)d_in[13];
  const float* w1     = (const float*)d_in[14];
  const float* b1     = (const float*)d_in[15];
  const float* bnw    = (const float*)d_in[16];
  const float* bnb    = (const float*)d_in[17];
  const float* bnm    = (const float*)d_in[18];
  const float* bnv    = (const float*)d_in[19];
  const float* w2     = (const float*)d_in[20];
  const float* b2     = (const float*)d_in[21];
  float* out = (float*)d_out;

  char* ws = (char*)d_ws;
  // bf16 intermediates; footprint ends at 64,585,728 B.
  bf16t* xz    = (bf16t*)(ws);              // [B,384,L] bf16  25.2 MB
  bf16t* xcT   = (bf16t*)(ws + 25165824);   // [B,L,192] bf16  12.6 MB (-> u)
  bf16t* ymT2  = (bf16t*)(ws + 37748736);   // [B,L,192] bf16  12.6 MB
  float* projS = (float*)(ws + 50331648);   // [B,K,L,8] f32    4.2 MB
  float* Wgb   = (float*)(ws + 54525952);   // [B,4,L]          0.5 MB
  float* carrP = (float*)(ws + 55050240);   // [B,K,SS,192]     3.0 MB
  float* carrH = (float*)(ws + 58195968);   // [B,K,SS,192]     3.0 MB
  float* h0b   = (float*)(ws + 61341696);   // [B,K,SS,192]     3.0 MB
  float* xpwT  = (float*)(ws + 64487424);   // [K,DIN,8]       24.6 KB
  bf16t* ipwb  = (bf16t*)(ws + 64512000);   // [384,96] bf16   73.7 KB (ends 64585728)
  bf16t* ymT   = xz;   // overlay: x_ssm half of xz (dead after convproj)
  bf16t* u     = xcT;  // xcT dead after scan_apply_k

  // 1) prior -> direction gates (+ xpwT transpose, ipw->bf16)
  p2w_k<<<(BB * LL) / 256, 256, 0, stream>>>(prior, alpha, w1, b1, bnw, bnb, bnm,
                                             bnv, w2, b2, xpw, ipw, xpwT, ipwb, Wgb);
  // 2) in_proj via MFMA bf16 -> xz bf16
  gemm_in_mfma_k<<<dim3(LL / 32, 1, BB), 256, 0, stream>>>(x, ipwb, xz);
  // 3) fused dwconv+SiLU + x_proj(scan-order) + transpose
  convproj_k<<<dim3(HH, BB), 1024, 0, stream>>>(xz, cw, cb, xpwT, xcT, projS);
  // 4) scan: paired segment carries
  scan_part_k<<<dim3(SS, 2, BB), 192, 0, stream>>>(xcT, projS, dtw, dtb, A_logs,
                                                   carrP, carrH);
  // 5) scan: serial carry combine
  scan_fix_k<<<dim3(KK, BB), 192, 0, stream>>>(carrP, carrH, h0b);
  // 6) scan: apply + gate + paired merge (ymT overlaid on xz x_ssm half)
  scan_apply_k<<<dim3(SS, 2, BB), 192, 0, stream>>>(xcT, projS, Wgb, h0b, dtw, dtb,
                                                    A_logs, Ds, ymT, ymT2);
  // 7) LayerNorm(channel) * silu(z) -> u bf16
  ln_silu_k<<<dim3(HH, BB), 256, 0, stream>>>(ymT, ymT2, xz, onw, onb, u);
  // 8) out_proj GEMM: u bf16 -> out f32
  gemm_out_k<<<dim3(LL / 1024, COUT / 4, BB), 256, 0, stream>>>(u, opw, out);
}

// Round 21
// 162.398 us; speedup vs baseline: 1.7072x; 1.0749x over previous
//
#include <hip/hip_runtime.h>

#define BB   8
#define CIN  96
#define DIN  192
#define HH   64
#define WW   64
#define LL   4096
#define KK   4
#define COUT 96
#define SS   128  // scan segments
#define LC   32   // segment length = LL/SS

#define LOG2E 1.4426950408889634f
#define LN2   0.6931471805599453f

typedef unsigned short bf16t;
typedef float f32x2 __attribute__((ext_vector_type(2)));
typedef float f32x4 __attribute__((ext_vector_type(4)));
typedef short bf16x8s __attribute__((ext_vector_type(8)));

__device__ __forceinline__ f32x2 pkfma(f32x2 a, f32x2 b, f32x2 c) {
#if __has_builtin(__builtin_elementwise_fma)
  return __builtin_elementwise_fma(a, b, c);
#else
  f32x2 r;
  r[0] = fmaf(a[0], b[0], c[0]);
  r[1] = fmaf(a[1], b[1], c[1]);
  return r;
#endif
}

__device__ __forceinline__ float exp2fast(float x) { return __builtin_amdgcn_exp2f(x); }
__device__ __forceinline__ float log2fast(float x) { return __builtin_amdgcn_logf(x); }
__device__ __forceinline__ float sigf(float x) { return 1.0f / (1.0f + __expf(-x)); }
__device__ __forceinline__ int trp(int p) { return ((p & 63) << 6) | (p >> 6); }
__device__ __forceinline__ int pix_of(int k, int l) {
  if (k == 0) return l;
  if (k == 1) return trp(l);
  if (k == 2) return LL - 1 - l;
  return trp(LL - 1 - l);
}
__device__ __forceinline__ float b2f(bf16t v) {
  return __uint_as_float((unsigned)v << 16);
}
__device__ __forceinline__ bf16t f2b(float f) {  // round-to-nearest-even
  unsigned u = __float_as_uint(f);
  return (bf16t)((u + 0x7FFFu + ((u >> 16) & 1u)) >> 16);
}

// ---------------------------------------------------------------------------
// in_proj via MFMA bf16: xz[o,p] = sum_c W[o,c] x[c,p].
// A=W (m=o,k=c), B=x (k=c,n=px). Block: 4 waves x 6 m-tiles x 32 px.
// ---------------------------------------------------------------------------
__global__ __launch_bounds__(256) void gemm_in_mfma_k(const float* __restrict__ x,
                                                      const bf16t* __restrict__ Wb,
                                                      bf16t* __restrict__ out) {
  __shared__ bf16t ldsB[32 * 104];  // [px][c] bf16, pad 104
  const int tid = threadIdx.x;
  const int b = blockIdx.z;
  const int p0 = blockIdx.x * 32;
  for (int idx = tid; idx < CIN * 32; idx += 256) {
    int c = idx >> 5, px = idx & 31;
    ldsB[px * 104 + c] = f2b(x[((size_t)b * CIN + c) * LL + p0 + px]);
  }
  __syncthreads();
  const int wave = tid >> 6, lane = tid & 63;
  const int lm = lane & 15, kc = lane >> 4;
  bf16x8s bfrag[2][3];
#pragma unroll
  for (int nf = 0; nf < 2; ++nf)
#pragma unroll
    for (int ks = 0; ks < 3; ++ks)
      bfrag[nf][ks] = *(const bf16x8s*)&ldsB[(nf * 16 + lm) * 104 + ks * 32 + kc * 8];
  bf16t* ob = out + (size_t)b * 384 * LL + p0;
#pragma unroll
  for (int mti = 0; mti < 6; ++mti) {
    const int o0 = (wave * 6 + mti) * 16;
    bf16x8s afrag[3];
#pragma unroll
    for (int ks = 0; ks < 3; ++ks)
      afrag[ks] = *(const bf16x8s*)&Wb[(size_t)(o0 + lm) * CIN + ks * 32 + kc * 8];
    f32x4 acc0 = {0.f, 0.f, 0.f, 0.f};
    f32x4 acc1 = {0.f, 0.f, 0.f, 0.f};
#pragma unroll
    for (int ks = 0; ks < 3; ++ks) {
      acc0 = __builtin_amdgcn_mfma_f32_16x16x32_bf16(afrag[ks], bfrag[0][ks], acc0, 0, 0, 0);
      acc1 = __builtin_amdgcn_mfma_f32_16x16x32_bf16(afrag[ks], bfrag[1][ks], acc1, 0, 0, 0);
    }
#pragma unroll
    for (int r = 0; r < 4; ++r) {
      ob[(size_t)(o0 + kc * 4 + r) * LL + lm]      = f2b(acc0[r]);
      ob[(size_t)(o0 + kc * 4 + r) * LL + 16 + lm] = f2b(acc1[r]);
    }
  }
}

// ---------------------------------------------------------------------------
// out_proj via MFMA bf16, split-precision weights (W = Wh + Wl):
// out[o,p] = sum_c W[o,c] u[c,p], f32 accumulate, f32 store.
// Block: 6 waves (one 16-ch m-tile each) x 64 px (4 n-tiles).
// ---------------------------------------------------------------------------
__global__ __launch_bounds__(384) void gemm_out_mfma_k(const bf16t* __restrict__ u,
                                                       const bf16t* __restrict__ Wh,
                                                       const bf16t* __restrict__ Wl,
                                                       float* __restrict__ out) {
  __shared__ bf16t ldsB[64 * 200];  // [px][c] bf16, pad 200 -> 25.6 KB
  const int tid = threadIdx.x;
  const int b = blockIdx.z;
  const int p0 = blockIdx.x * 64;
  for (int idx = tid; idx < DIN * 64; idx += 384) {
    int c = idx >> 6, px = idx & 63;
    ldsB[px * 200 + c] = u[((size_t)b * DIN + c) * LL + p0 + px];
  }
  __syncthreads();
  const int wave = tid / 64, lane = tid & 63;
  const int lm = lane & 15, kc = lane >> 4;
  const int o0 = wave * 16;
  bf16x8s ah[6], al[6];
#pragma unroll
  for (int ks = 0; ks < 6; ++ks) {
    ah[ks] = *(const bf16x8s*)&Wh[(size_t)(o0 + lm) * DIN + ks * 32 + kc * 8];
    al[ks] = *(const bf16x8s*)&Wl[(size_t)(o0 + lm) * DIN + ks * 32 + kc * 8];
  }
  float* ob = out + (size_t)b * COUT * LL + p0;
#pragma unroll
  for (int nf = 0; nf < 4; ++nf) {
    f32x4 acc = {0.f, 0.f, 0.f, 0.f};
#pragma unroll
    for (int ks = 0; ks < 6; ++ks) {
      bf16x8s bfr = *(const bf16x8s*)&ldsB[(nf * 16 + lm) * 200 + ks * 32 + kc * 8];
      acc = __builtin_amdgcn_mfma_f32_16x16x32_bf16(ah[ks], bfr, acc, 0, 0, 0);
      acc = __builtin_amdgcn_mfma_f32_16x16x32_bf16(al[ks], bfr, acc, 0, 0, 0);
    }
#pragma unroll
    for (int r = 0; r < 4; ++r)
      ob[(size_t)(o0 + kc * 4 + r) * LL + nf * 16 + lm] = acc[r];
  }
}

// ---------------------------------------------------------------------------
// PriorToWeights MLP -> Wg[B,4,L].  Block 0: xpw -> xpwT. Block 1: ipw -> bf16.
// Block 2: opw -> split-precision bf16 pair (hi, lo).
// ---------------------------------------------------------------------------
__global__ __launch_bounds__(256) void p2w_k(const float* __restrict__ prior,
                                             const float* __restrict__ alpha,
                                             const float* __restrict__ w1,
                                             const float* __restrict__ b1,
                                             const float* __restrict__ bnw,
                                             const float* __restrict__ bnb,
                                             const float* __restrict__ bnm,
                                             const float* __restrict__ bnv,
                                             const float* __restrict__ w2,
                                             const float* __restrict__ b2,
                                             const float* __restrict__ xpw,
                                             const float* __restrict__ ipw,
                                             const float* __restrict__ opw,
                                             float* __restrict__ xpwT,
                                             bf16t* __restrict__ ipwb,
                                             bf16t* __restrict__ opwbh,
                                             bf16t* __restrict__ opwbl,
                                             float* __restrict__ Wg) {
  if (blockIdx.x == 0) {
    for (int idx = threadIdx.x; idx < KK * DIN * 8; idx += 256) {
      int kk = idx / (DIN * 8);
      int rem = idx % (DIN * 8);
      int dd = rem >> 3, c = rem & 7;
      xpwT[idx] = xpw[(kk * 8 + c) * DIN + dd];
    }
  }
  if (blockIdx.x == 1) {
    for (int idx = threadIdx.x; idx < 384 * CIN; idx += 256)
      ipwb[idx] = f2b(ipw[idx]);
  }
  if (blockIdx.x == 2) {
    for (int idx = threadIdx.x; idx < COUT * DIN; idx += 256) {
      float w = opw[idx];
      bf16t hi = f2b(w);
      opwbh[idx] = hi;
      opwbl[idx] = f2b(w - b2f(hi));
    }
  }
  int idx = blockIdx.x * 256 + threadIdx.x;
  int p = idx & (LL - 1);
  int b = idx >> 12;
  float pr[4];
#pragma unroll
  for (int c = 0; c < 4; ++c) pr[c] = prior[((size_t)b * 4 + c) * LL + p];
  float s = sigf(alpha[0]);
  float g2[4];
#pragma unroll
  for (int j = 0; j < 4; ++j) g2[j] = b2[j];
  for (int o = 0; o < 32; ++o) {
    float g = b1[o];
#pragma unroll
    for (int c = 0; c < 4; ++c) g = fmaf(pr[c], w1[o * 4 + c], g);
    g = (g - bnm[o]) * rsqrtf(bnv[o] + 1e-5f) * bnw[o] + bnb[o];
    g = fmaxf(g, 0.0f);
#pragma unroll
    for (int j = 0; j < 4; ++j) g2[j] = fmaf(g, w2[j * 32 + o], g2[j]);
  }
#pragma unroll
  for (int j = 0; j < 4; ++j)
    Wg[((size_t)b * 4 + j) * LL + p] = 1.0f + s * (sigf(g2[j]) - 1.0f);
}

// ---------------------------------------------------------------------------
// FUSED conv+proj: xz bf16 in, xcT bf16 out, projS f32 (scan order).
// ---------------------------------------------------------------------------
__global__ __launch_bounds__(1024) void convproj_k(const bf16t* __restrict__ xz,
                                                   const float* __restrict__ cw,
                                                   const float* __restrict__ cb,
                                                   const float* __restrict__ xpwT,
                                                   bf16t* __restrict__ xcT,
                                                   float* __restrict__ projS) {
  __shared__ float sX[96 * 65];   // 24.96 KB
  __shared__ float4 sP[512];      // 8 KB q-partials
  const int tid = threadIdx.x;
  const int b = blockIdx.y;
  const int h = blockIdx.x;
  const int px = tid & 63;
  const int ku = __builtin_amdgcn_readfirstlane((tid >> 6) & 3);
  const int hf = __builtin_amdgcn_readfirstlane((tid >> 8) & 1);
  const int q  = __builtin_amdgcn_readfirstlane(tid >> 9);
  f32x2 a01 = {0.f, 0.f}, a23 = {0.f, 0.f};

#pragma unroll
  for (int half = 0; half < 2; ++half) {
    for (int idx = tid; idx < 96 * 16; idx += 1024) {
      int ddl = idx >> 4, pq = idx & 15;
      int w0 = pq * 4;
      int dd = half * 96 + ddl;
      const bf16t* base = xz + ((size_t)b * 384 + dd) * LL + h * 64 + w0;
      const float* wp = cw + dd * 9;
      float bv = cb[dd];
      f32x2 s01 = {bv, bv}, s23 = {bv, bv};
#pragma unroll
      for (int dh = -1; dh <= 1; ++dh) {
        int hh = h + dh;
        if (hh < 0 || hh >= HH) continue;
        const bf16t* row = base + dh * 64;
        ushort4 cmu = *(const ushort4*)row;
        float cmx = b2f(cmu.x), cmy = b2f(cmu.y), cmz = b2f(cmu.z), cmw = b2f(cmu.w);
        float lf = (w0 > 0)  ? b2f(row[-1]) : 0.0f;
        float rt = (w0 < 60) ? b2f(row[4])  : 0.0f;
        float c0 = wp[(dh + 1) * 3], c1 = wp[(dh + 1) * 3 + 1], c2 = wp[(dh + 1) * 3 + 2];
        s01 = pkfma((f32x2){lf,  cmx}, (f32x2){c0, c0}, s01);
        s01 = pkfma((f32x2){cmx, cmy}, (f32x2){c1, c1}, s01);
        s01 = pkfma((f32x2){cmy, cmz}, (f32x2){c2, c2}, s01);
        s23 = pkfma((f32x2){cmy, cmz}, (f32x2){c0, c0}, s23);
        s23 = pkfma((f32x2){cmz, cmw}, (f32x2){c1, c1}, s23);
        s23 = pkfma((f32x2){cmw, rt},  (f32x2){c2, c2}, s23);
      }
      float* so = &sX[ddl * 65 + w0];
      float v0 = s01[0], v1 = s01[1], v2 = s23[0], v3 = s23[1];
      so[0] = v0 * sigf(v0);
      so[1] = v1 * sigf(v1);
      so[2] = v2 * sigf(v2);
      so[3] = v3 * sigf(v3);
    }
    __syncthreads();
    for (int idx = tid; idx < 64 * 96; idx += 1024) {
      int pp = idx / 96, ddl = idx % 96;
      xcT[((size_t)b * LL + h * 64 + pp) * DIN + half * 96 + ddl] =
          f2b(sX[ddl * 65 + pp]);
    }
    {
      const int ddl0 = q * 48;
      const float* wp = xpwT + (size_t)ku * (DIN * 8) + (half * 96 + ddl0) * 8 + hf * 4;
#pragma unroll 8
      for (int d48 = 0; d48 < 48; ++d48) {
        float xv = sX[(ddl0 + d48) * 65 + px];
        const float4 w4 = *(const float4*)(wp + d48 * 8);
        const f32x2 xv2 = {xv, xv};
        a01 = pkfma(xv2, (f32x2){w4.x, w4.y}, a01);
        a23 = pkfma(xv2, (f32x2){w4.z, w4.w}, a23);
      }
    }
    __syncthreads();
  }
  const int slot = tid & 511;
  if (q == 1) sP[slot] = make_float4(a01[0], a01[1], a23[0], a23[1]);
  __syncthreads();
  if (q == 0) {
    float4 o = sP[slot];
    float r0 = a01[0] + o.x, r1 = a01[1] + o.y, r2 = a23[0] + o.z, r3 = a23[1] + o.w;
    const int p = h * 64 + px;
    int l;
    if (ku == 0) l = p;
    else if (ku == 1) l = trp(p);
    else if (ku == 2) l = LL - 1 - p;
    else l = LL - 1 - trp(p);
    float* pb = projS + (((size_t)b * KK + ku) * LL + l) * 8 + hf * 4;
    *(float4*)pb = make_float4(r0, r1, r2, r3);
  }
}

// ---------------------------------------------------------------------------
// Scan pass 1 (PAIRED): xcT bf16; carries f32.
// ---------------------------------------------------------------------------
__global__ __launch_bounds__(192) void scan_part_k(const bf16t* __restrict__ xcT,
                                                   const float* __restrict__ projS,
                                                   const float* __restrict__ dtw,
                                                   const float* __restrict__ dtb,
                                                   const float* __restrict__ A_logs,
                                                   float* __restrict__ carrP,
                                                   float* __restrict__ carrH) {
  const int s = blockIdx.x, kp = blockIdx.y, b = blockIdx.z;
  const int d = threadIdx.x;
  const int kA = kp, kB = kp + 2;
  const int s2 = SS - 1 - s;
  const int kdA = kA * DIN + d, kdB = kB * DIN + d;
  float wrA[6], wrB[6];
#pragma unroll
  for (int r = 0; r < 6; ++r) { wrA[r] = dtw[kdA * 6 + r]; wrB[r] = dtw[kdB * 6 + r]; }
  const float biasA = dtb[kdA], biasB = dtb[kdB];
  const float AaA = -__expf(A_logs[kdA]), AaB = -__expf(A_logs[kdB]);
  const int l0 = s * LC;
  const int p0 = pix_of(kA, l0);
  const int dp = pix_of(kA, l0 + 1) - p0;
  const bf16t* xp = xcT + ((size_t)b * LL + p0) * DIN + d;
  const long xstep = (long)dp * DIN;
  const float* prA = projS + (((size_t)b * KK + kA) * LL + l0) * 8;
  const float* prB = projS + (((size_t)b * KK + kB) * LL + s2 * LC + (LC - 1)) * 8;
  float PA = 1.0f, HA = 0.0f, PB = 1.0f, HB = 0.0f;
#pragma unroll 2
  for (int j = 0; j < LC; ++j) {
    float4 a0 = *(const float4*)prA;
    float4 a1 = *(const float4*)(prA + 4);
    prA += 8;
    float4 b0 = *(const float4*)prB;
    float4 b1 = *(const float4*)(prB + 4);
    prB -= 8;
    float xv = b2f(*xp);
    xp += xstep;
    {
      float dtr = biasA;
      dtr = fmaf(a0.x, wrA[0], dtr);
      dtr = fmaf(a0.y, wrA[1], dtr);
      dtr = fmaf(a0.z, wrA[2], dtr);
      dtr = fmaf(a0.w, wrA[3], dtr);
      dtr = fmaf(a1.x, wrA[4], dtr);
      dtr = fmaf(a1.y, wrA[5], dtr);
      float e = exp2fast(fminf(dtr, 80.0f) * LOG2E);
      float u = log2fast(1.0f + e);
      float a = exp2fast(u * AaA);
      float dt = u * LN2;
      HA = fmaf(a, HA, dt * a1.z * xv);
      PA *= a;
    }
    {
      float dtr = biasB;
      dtr = fmaf(b0.x, wrB[0], dtr);
      dtr = fmaf(b0.y, wrB[1], dtr);
      dtr = fmaf(b0.z, wrB[2], dtr);
      dtr = fmaf(b0.w, wrB[3], dtr);
      dtr = fmaf(b1.x, wrB[4], dtr);
      dtr = fmaf(b1.y, wrB[5], dtr);
      float e = exp2fast(fminf(dtr, 80.0f) * LOG2E);
      float u = log2fast(1.0f + e);
      float a = exp2fast(u * AaB);
      float dt = u * LN2;
      HB = fmaf(PB, dt * b1.z * xv, HB);
      PB *= a;
    }
  }
  size_t oA = ((size_t)((b * KK + kA) * SS + s)) * DIN + d;
  size_t oB = ((size_t)((b * KK + kB) * SS + s2)) * DIN + d;
  carrP[oA] = PA;
  carrH[oA] = HA;
  carrP[oB] = PB;
  carrH[oB] = HB;
}

// ---------------------------------------------------------------------------
// Scan pass 2: serial combine of SS carries -> per-segment initial state h0
// ---------------------------------------------------------------------------
__global__ __launch_bounds__(192) void scan_fix_k(const float* __restrict__ carrP,
                                                  const float* __restrict__ carrH,
                                                  float* __restrict__ h0) {
  const int k = blockIdx.x, b = blockIdx.y, d = threadIdx.x;
  size_t base = ((size_t)(b * KK + k)) * SS * DIN + d;
  float h = 0.0f;
#pragma unroll 4
  for (int s = 0; s < SS; ++s) {
    h0[base + (size_t)s * DIN] = h;
    h = fmaf(carrP[base + (size_t)s * DIN], h, carrH[base + (size_t)s * DIN]);
  }
}

// ---------------------------------------------------------------------------
// Scan pass 3: apply + gate + paired merge; xcT bf16 in (reg-cached for dir B),
// ymT/ymT2 bf16 out.
// ---------------------------------------------------------------------------
__global__ __launch_bounds__(192) void scan_apply_k(const bf16t* __restrict__ xcT,
                                                    const float* __restrict__ projS,
                                                    const float* __restrict__ Wg,
                                                    const float* __restrict__ h0,
                                                    const float* __restrict__ dtw,
                                                    const float* __restrict__ dtb,
                                                    const float* __restrict__ A_logs,
                                                    const float* __restrict__ Ds,
                                                    bf16t* __restrict__ ymT,
                                                    bf16t* __restrict__ ymT2) {
  const int s = blockIdx.x, kp = blockIdx.y, b = blockIdx.z;
  const int d = threadIdx.x;
  __shared__ float sAcc[LC * DIN];  // 24 KB, column d thread-private
  float xr[LC];                     // register cache of this segment's xv
  {
    const int k = kp, kd = k * DIN + d;
    float wr[6];
#pragma unroll
    for (int r = 0; r < 6; ++r) wr[r] = dtw[kd * 6 + r];
    const float bias = dtb[kd];
    const float Aa = -__expf(A_logs[kd]);
    const float Dv = Ds[kd];
    const int l0 = s * LC;
    const int p0 = pix_of(k, l0);
    const int dp = pix_of(k, l0 + 1) - p0;
    const bf16t* xp = xcT + ((size_t)b * LL + p0) * DIN + d;
    const long xstep = (long)dp * DIN;
    const float* pr = projS + (((size_t)b * KK + k) * LL + l0) * 8;
    const float* wg = Wg + ((size_t)b * KK + k) * LL + l0;
    float h = h0[((size_t)((b * KK + k) * SS + s)) * DIN + d];
#pragma unroll
    for (int j = 0; j < LC; ++j) {
      float4 q0 = *(const float4*)pr;
      float4 q1 = *(const float4*)(pr + 4);
      pr += 8;
      float xv = b2f(*xp);
      xp += xstep;
      xr[j] = xv;
      float dtr = bias;
      dtr = fmaf(q0.x, wr[0], dtr);
      dtr = fmaf(q0.y, wr[1], dtr);
      dtr = fmaf(q0.z, wr[2], dtr);
      dtr = fmaf(q0.w, wr[3], dtr);
      dtr = fmaf(q1.x, wr[4], dtr);
      dtr = fmaf(q1.y, wr[5], dtr);
      float e = exp2fast(fminf(dtr, 80.0f) * LOG2E);
      float u = log2fast(1.0f + e);
      float a = exp2fast(u * Aa);
      float dt = u * LN2;
      h = fmaf(a, h, dt * q1.z * xv);
      sAcc[j * DIN + d] = fmaf(h, q1.w, Dv * xv) * wg[j];
    }
  }
  {
    const int k = kp + 2, kd = k * DIN + d;
    const int s2 = SS - 1 - s;
    float wr[6];
#pragma unroll
    for (int r = 0; r < 6; ++r) wr[r] = dtw[kd * 6 + r];
    const float bias = dtb[kd];
    const float Aa = -__expf(A_logs[kd]);
    const float Dv = Ds[kd];
    const int l0 = s2 * LC;
    const float* pr = projS + (((size_t)b * KK + k) * LL + l0) * 8;
    const float* wg = Wg + ((size_t)b * KK + k) * LL + l0;
    float h = h0[((size_t)((b * KK + k) * SS + s2)) * DIN + d];
#pragma unroll
    for (int j = 0; j < LC; ++j) {
      float4 q0 = *(const float4*)pr;
      float4 q1 = *(const float4*)(pr + 4);
      pr += 8;
      float xv = xr[LC - 1 - j];   // same pixels, reversed (static index)
      float dtr = bias;
      dtr = fmaf(q0.x, wr[0], dtr);
      dtr = fmaf(q0.y, wr[1], dtr);
      dtr = fmaf(q0.z, wr[2], dtr);
      dtr = fmaf(q0.w, wr[3], dtr);
      dtr = fmaf(q1.x, wr[4], dtr);
      dtr = fmaf(q1.y, wr[5], dtr);
      float e = exp2fast(fminf(dtr, 80.0f) * LOG2E);
      float u = log2fast(1.0f + e);
      float a = exp2fast(u * Aa);
      float dt = u * LN2;
      h = fmaf(a, h, dt * q1.z * xv);
      float y = fmaf(h, q1.w, Dv * xv) * wg[j];
      sAcc[(LC - 1 - j) * DIN + d] += y;
    }
  }
  bf16t* dst;
  if (kp == 0)
    dst = ymT + (size_t)b * (384 * (size_t)LL) + (size_t)(s * LC) * DIN + d;  // xz overlay
  else
    dst = ymT2 + ((size_t)b * LL + s * LC) * DIN + d;
#pragma unroll 4
  for (int j = 0; j < LC; ++j) dst[(size_t)j * DIN] = f2b(sAcc[j * DIN + d]);
}

// ---------------------------------------------------------------------------
// LayerNorm(channel) * silu(z): ym bf16 + z bf16 -> u bf16.
// ---------------------------------------------------------------------------
__global__ __launch_bounds__(256) void ln_silu_k(const bf16t* __restrict__ ymT,
                                                 const bf16t* __restrict__ ymT2,
                                                 const bf16t* __restrict__ xz,
                                                 const float* __restrict__ gamma,
                                                 const float* __restrict__ beta,
                                                 bf16t* __restrict__ u) {
  const int b = blockIdx.y;
  const int h = blockIdx.x;
  const int p0 = h * 64;
  __shared__ float sY[64 * 193];
  __shared__ float sS[4][64], sQ[4][64];
  const int tid = threadIdx.x;
  const bf16t* ymb = ymT + (size_t)b * (384 * (size_t)LL);  // xz overlay
  for (int idx = tid; idx < 64 * DIN; idx += 256) {
    int pp = idx / DIN, dd = idx % DIN;
    float v = b2f(ymb[(size_t)(p0 + pp) * DIN + dd]) +
              b2f(ymT2[((size_t)b * LL + pp * 64 + h) * DIN + dd]);
    sY[pp * 193 + dd] = v;
  }
  __syncthreads();
  const int px = tid & 63, g = tid >> 6;
  float sum = 0.0f, ss = 0.0f;
  for (int dd = g * 48; dd < g * 48 + 48; ++dd) {
    float v = sY[px * 193 + dd];
    sum += v;
    ss = fmaf(v, v, ss);
  }
  sS[g][px] = sum;
  sQ[g][px] = ss;
  __syncthreads();
  sum = sS[0][px] + sS[1][px] + sS[2][px] + sS[3][px];
  ss  = sQ[0][px] + sQ[1][px] + sQ[2][px] + sQ[3][px];
  const float mu = sum * (1.0f / DIN);
  float var = ss * (1.0f / DIN) - mu * mu;
  const float rstd = rsqrtf(fmaxf(var, 0.0f) + 1e-5f);
  const bf16t* zb = xz + ((size_t)b * 384 + DIN) * LL + p0 + px;
  bf16t* ub = u + (size_t)b * DIN * LL + p0 + px;
  for (int dd = g * 48; dd < g * 48 + 48; ++dd) {
    float v = sY[px * 193 + dd];
    float z = b2f(zb[(size_t)dd * LL]);
    float tn = fmaf((v - mu) * rstd, gamma[dd], beta[dd]);
    ub[(size_t)dd * LL] = f2b(tn * (z * sigf(z)));
  }
}

// ---------------------------------------------------------------------------
extern "C" void kernel_launch(void* const* d_in, const int* in_sizes, int n_in,
                              void* d_out, int out_size, void* d_ws, size_t ws_size,
                              hipStream_t stream) {
  const float* x      = (const float*)d_in[0];
  const float* prior  = (const float*)d_in[1];
  const float* alpha  = (const float*)d_in[2];
  const float* ipw    = (const float*)d_in[3];
  const float* cw     = (const float*)d_in[4];
  const float* cb     = (const float*)d_in[5];
  const float* xpw    = (const float*)d_in[6];
  const float* dtw    = (const float*)d_in[7];
  const float* dtb    = (const float*)d_in[8];
  const float* A_logs = (const float*)d_in[9];
  const float* Ds     = (const float*)d_in[10];
  const float* onw    = (const float*)d_in[11];
  const float* onb    = (const float*)d_in[12];
  const float* opw    = (const float*)d_in[13];
  const float* w1     = (const float*)d_in[14];
  const float* b1     = (const float*)d_in[15];
  const float* bnw    = (const float*)d_in[16];
  const float* bnb    = (const float*)d_in[17];
  const float* bnm    = (const float*)d_in[18];
  const float* bnv    = (const float*)d_in[19];
  const float* w2     = (const float*)d_in[20];
  const float* b2     = (const float*)d_in[21];
  float* out = (float*)d_out;

  char* ws = (char*)d_ws;
  // bf16 intermediates; footprint ends at 64,659,456 B.
  bf16t* xz    = (bf16t*)(ws);              // [B,384,L] bf16  25.2 MB
  bf16t* xcT   = (bf16t*)(ws + 25165824);   // [B,L,192] bf16  12.6 MB (-> u)
  bf16t* ymT2  = (bf16t*)(ws + 37748736);   // [B,L,192] bf16  12.6 MB
  float* projS = (float*)(ws + 50331648);   // [B,K,L,8] f32    4.2 MB
  float* Wgb   = (float*)(ws + 54525952);   // [B,4,L]          0.5 MB
  float* carrP = (float*)(ws + 55050240);   // [B,K,SS,192]     3.0 MB
  float* carrH = (float*)(ws + 58195968);   // [B,K,SS,192]     3.0 MB
  float* h0b   = (float*)(ws + 61341696);   // [B,K,SS,192]     3.0 MB
  float* xpwT  = (float*)(ws + 64487424);   // [K,DIN,8]       24.6 KB
  bf16t* ipwb  = (bf16t*)(ws + 64512000);   // [384,96] bf16   73.7 KB
  bf16t* opwbh = (bf16t*)(ws + 64585728);   // [96,192] bf16   36.9 KB
  bf16t* opwbl = (bf16t*)(ws + 64622592);   // [96,192] bf16   36.9 KB (ends 64659456)
  bf16t* ymT   = xz;   // overlay: x_ssm half of xz (dead after convproj)
  bf16t* u     = xcT;  // xcT dead after scan_apply_k

  // 1) prior -> direction gates (+ weight preps in blocks 0,1,2)
  p2w_k<<<(BB * LL) / 256, 256, 0, stream>>>(prior, alpha, w1, b1, bnw, bnb, bnm,
                                             bnv, w2, b2, xpw, ipw, opw, xpwT,
                                             ipwb, opwbh, opwbl, Wgb);
  // 2) in_proj via MFMA bf16 -> xz bf16
  gemm_in_mfma_k<<<dim3(LL / 32, 1, BB), 256, 0, stream>>>(x, ipwb, xz);
  // 3) fused dwconv+SiLU + x_proj(scan-order) + transpose
  convproj_k<<<dim3(HH, BB), 1024, 0, stream>>>(xz, cw, cb, xpwT, xcT, projS);
  // 4) scan: paired segment carries
  scan_part_k<<<dim3(SS, 2, BB), 192, 0, stream>>>(xcT, projS, dtw, dtb, A_logs,
                                                   carrP, carrH);
  // 5) scan: serial carry combine
  scan_fix_k<<<dim3(KK, BB), 192, 0, stream>>>(carrP, carrH, h0b);
  // 6) scan: apply + gate + paired merge (ymT overlaid on xz x_ssm half)
  scan_apply_k<<<dim3(SS, 2, BB), 192, 0, stream>>>(xcT, projS, Wgb, h0b, dtw, dtb,
                                                    A_logs, Ds, ymT, ymT2);
  // 7) LayerNorm(channel) * silu(z) -> u bf16
  ln_silu_k<<<dim3(HH, BB), 256, 0, stream>>>(ymT, ymT2, xz, onw, onb, u);
  // 8) out_proj via MFMA bf16 (split-precision weights) -> out f32
  gemm_out_mfma_k<<<dim3(LL / 64, 1, BB), 384, 0, stream>>>(u, opwbh, opwbl, out);
}

// Round 22
// 154.162 us; speedup vs baseline: 1.7984x; 1.0534x over previous
//
#include <hip/hip_runtime.h>

#define BB   8
#define CIN  96
#define DIN  192
#define HH   64
#define WW   64
#define LL   4096
#define KK   4
#define COUT 96
#define SS   128  // scan segments
#define LC   32   // segment length = LL/SS

#define LOG2E 1.4426950408889634f
#define LN2   0.6931471805599453f

typedef unsigned short bf16t;
typedef float f32x2 __attribute__((ext_vector_type(2)));
typedef float f32x4 __attribute__((ext_vector_type(4)));
typedef short bf16x8s __attribute__((ext_vector_type(8)));

__device__ __forceinline__ f32x2 pkfma(f32x2 a, f32x2 b, f32x2 c) {
#if __has_builtin(__builtin_elementwise_fma)
  return __builtin_elementwise_fma(a, b, c);
#else
  f32x2 r;
  r[0] = fmaf(a[0], b[0], c[0]);
  r[1] = fmaf(a[1], b[1], c[1]);
  return r;
#endif
}

__device__ __forceinline__ float exp2fast(float x) { return __builtin_amdgcn_exp2f(x); }
__device__ __forceinline__ float log2fast(float x) { return __builtin_amdgcn_logf(x); }
__device__ __forceinline__ float sigf(float x) { return 1.0f / (1.0f + __expf(-x)); }
__device__ __forceinline__ int trp(int p) { return ((p & 63) << 6) | (p >> 6); }
__device__ __forceinline__ int pix_of(int k, int l) {
  if (k == 0) return l;
  if (k == 1) return trp(l);
  if (k == 2) return LL - 1 - l;
  return trp(LL - 1 - l);
}
__device__ __forceinline__ float b2f(bf16t v) {
  return __uint_as_float((unsigned)v << 16);
}
__device__ __forceinline__ bf16t f2b(float f) {  // round-to-nearest-even
  unsigned u = __float_as_uint(f);
  return (bf16t)((u + 0x7FFFu + ((u >> 16) & 1u)) >> 16);
}

// ---------------------------------------------------------------------------
// in_proj via MFMA bf16: xz[o,p] = sum_c W[o,c] x[c,p].
// ---------------------------------------------------------------------------
__global__ __launch_bounds__(256) void gemm_in_mfma_k(const float* __restrict__ x,
                                                      const bf16t* __restrict__ Wb,
                                                      bf16t* __restrict__ out) {
  __shared__ bf16t ldsB[32 * 104];  // [px][c] bf16, pad 104
  const int tid = threadIdx.x;
  const int b = blockIdx.z;
  const int p0 = blockIdx.x * 32;
  for (int idx = tid; idx < CIN * 32; idx += 256) {
    int c = idx >> 5, px = idx & 31;
    ldsB[px * 104 + c] = f2b(x[((size_t)b * CIN + c) * LL + p0 + px]);
  }
  __syncthreads();
  const int wave = tid >> 6, lane = tid & 63;
  const int lm = lane & 15, kc = lane >> 4;
  bf16x8s bfrag[2][3];
#pragma unroll
  for (int nf = 0; nf < 2; ++nf)
#pragma unroll
    for (int ks = 0; ks < 3; ++ks)
      bfrag[nf][ks] = *(const bf16x8s*)&ldsB[(nf * 16 + lm) * 104 + ks * 32 + kc * 8];
  bf16t* ob = out + (size_t)b * 384 * LL + p0;
#pragma unroll
  for (int mti = 0; mti < 6; ++mti) {
    const int o0 = (wave * 6 + mti) * 16;
    bf16x8s afrag[3];
#pragma unroll
    for (int ks = 0; ks < 3; ++ks)
      afrag[ks] = *(const bf16x8s*)&Wb[(size_t)(o0 + lm) * CIN + ks * 32 + kc * 8];
    f32x4 acc0 = {0.f, 0.f, 0.f, 0.f};
    f32x4 acc1 = {0.f, 0.f, 0.f, 0.f};
#pragma unroll
    for (int ks = 0; ks < 3; ++ks) {
      acc0 = __builtin_amdgcn_mfma_f32_16x16x32_bf16(afrag[ks], bfrag[0][ks], acc0, 0, 0, 0);
      acc1 = __builtin_amdgcn_mfma_f32_16x16x32_bf16(afrag[ks], bfrag[1][ks], acc1, 0, 0, 0);
    }
#pragma unroll
    for (int r = 0; r < 4; ++r) {
      ob[(size_t)(o0 + kc * 4 + r) * LL + lm]      = f2b(acc0[r]);
      ob[(size_t)(o0 + kc * 4 + r) * LL + 16 + lm] = f2b(acc1[r]);
    }
  }
}

// ---------------------------------------------------------------------------
// FUSED LayerNorm*silu(z) + out_proj MFMA (split-precision weights).
// Block = 64-px row tile, 384 threads (6 waves). Stages y into the MFMA
// B-tile LDS, LN-stats from LDS, normalize in place, then MFMA.
// ---------------------------------------------------------------------------
__global__ __launch_bounds__(384) void ln_gemm_out_k(const bf16t* __restrict__ ymT,
                                                     const bf16t* __restrict__ ymT2,
                                                     const bf16t* __restrict__ xz,
                                                     const float* __restrict__ gamma,
                                                     const float* __restrict__ beta,
                                                     const bf16t* __restrict__ Wh,
                                                     const bf16t* __restrict__ Wl,
                                                     float* __restrict__ out) {
  __shared__ bf16t ldsB[64 * 200];  // [px][c] bf16, 25.6 KB
  __shared__ float sS[6][64], sQ[6][64];
  const int tid = threadIdx.x;
  const int b = blockIdx.z;
  const int h = blockIdx.x;       // row tile
  const int p0 = h * 64;
  const bf16t* ymb = ymT + (size_t)b * (384 * (size_t)LL);  // xz overlay
  // Phase A: stage y = ymT + ymT2 (bf16), coalesced over dd
  for (int idx = tid; idx < 64 * DIN; idx += 384) {
    int pp = idx / DIN, dd = idx % DIN;
    float v = b2f(ymb[(size_t)(p0 + pp) * DIN + dd]) +
              b2f(ymT2[((size_t)b * LL + pp * 64 + h) * DIN + dd]);
    ldsB[pp * 200 + dd] = f2b(v);
  }
  __syncthreads();
  // Phase B: per-px LN stats (thread = px x 6 dd-groups of 32)
  const int px = tid & 63, g = tid >> 6;  // g in [0,6)
  float sum = 0.0f, ss = 0.0f;
  for (int dd = g * 32; dd < g * 32 + 32; ++dd) {
    float v = b2f(ldsB[px * 200 + dd]);
    sum += v;
    ss = fmaf(v, v, ss);
  }
  sS[g][px] = sum;
  sQ[g][px] = ss;
  __syncthreads();
  sum = 0.0f; ss = 0.0f;
#pragma unroll
  for (int gg = 0; gg < 6; ++gg) { sum += sS[gg][px]; ss += sQ[gg][px]; }
  const float mu = sum * (1.0f / DIN);
  float var = ss * (1.0f / DIN) - mu * mu;
  const float rstd = rsqrtf(fmaxf(var, 0.0f) + 1e-5f);
  // Phase C: normalize * silu(z) in place
  const bf16t* zb = xz + ((size_t)b * 384 + DIN) * LL + p0 + px;
  for (int dd = g * 32; dd < g * 32 + 32; ++dd) {
    float v = b2f(ldsB[px * 200 + dd]);
    float z = b2f(zb[(size_t)dd * LL]);
    float tn = fmaf((v - mu) * rstd, gamma[dd], beta[dd]);
    ldsB[px * 200 + dd] = f2b(tn * (z * sigf(z)));
  }
  __syncthreads();
  // Phase D: MFMA out_proj; wave = 16-ch m-tile, 4 n-tiles of 16 px
  const int wave = tid / 64, lane = tid & 63;
  const int lm = lane & 15, kc = lane >> 4;
  const int o0 = wave * 16;
  bf16x8s ah[6], al[6];
#pragma unroll
  for (int ks = 0; ks < 6; ++ks) {
    ah[ks] = *(const bf16x8s*)&Wh[(size_t)(o0 + lm) * DIN + ks * 32 + kc * 8];
    al[ks] = *(const bf16x8s*)&Wl[(size_t)(o0 + lm) * DIN + ks * 32 + kc * 8];
  }
  float* ob = out + (size_t)b * COUT * LL + p0;
#pragma unroll
  for (int nf = 0; nf < 4; ++nf) {
    f32x4 acc = {0.f, 0.f, 0.f, 0.f};
#pragma unroll
    for (int ks = 0; ks < 6; ++ks) {
      bf16x8s bfr = *(const bf16x8s*)&ldsB[(nf * 16 + lm) * 200 + ks * 32 + kc * 8];
      acc = __builtin_amdgcn_mfma_f32_16x16x32_bf16(ah[ks], bfr, acc, 0, 0, 0);
      acc = __builtin_amdgcn_mfma_f32_16x16x32_bf16(al[ks], bfr, acc, 0, 0, 0);
    }
#pragma unroll
    for (int r = 0; r < 4; ++r)
      ob[(size_t)(o0 + kc * 4 + r) * LL + nf * 16 + lm] = acc[r];
  }
}

// ---------------------------------------------------------------------------
// PriorToWeights MLP -> Wg[B,4,L].  Block 0: xpw -> xpwT. Block 1: ipw -> bf16.
// Block 2: opw -> split-precision bf16 pair (hi, lo).
// ---------------------------------------------------------------------------
__global__ __launch_bounds__(256) void p2w_k(const float* __restrict__ prior,
                                             const float* __restrict__ alpha,
                                             const float* __restrict__ w1,
                                             const float* __restrict__ b1,
                                             const float* __restrict__ bnw,
                                             const float* __restrict__ bnb,
                                             const float* __restrict__ bnm,
                                             const float* __restrict__ bnv,
                                             const float* __restrict__ w2,
                                             const float* __restrict__ b2,
                                             const float* __restrict__ xpw,
                                             const float* __restrict__ ipw,
                                             const float* __restrict__ opw,
                                             float* __restrict__ xpwT,
                                             bf16t* __restrict__ ipwb,
                                             bf16t* __restrict__ opwbh,
                                             bf16t* __restrict__ opwbl,
                                             float* __restrict__ Wg) {
  if (blockIdx.x == 0) {
    for (int idx = threadIdx.x; idx < KK * DIN * 8; idx += 256) {
      int kk = idx / (DIN * 8);
      int rem = idx % (DIN * 8);
      int dd = rem >> 3, c = rem & 7;
      xpwT[idx] = xpw[(kk * 8 + c) * DIN + dd];
    }
  }
  if (blockIdx.x == 1) {
    for (int idx = threadIdx.x; idx < 384 * CIN; idx += 256)
      ipwb[idx] = f2b(ipw[idx]);
  }
  if (blockIdx.x == 2) {
    for (int idx = threadIdx.x; idx < COUT * DIN; idx += 256) {
      float w = opw[idx];
      bf16t hi = f2b(w);
      opwbh[idx] = hi;
      opwbl[idx] = f2b(w - b2f(hi));
    }
  }
  int idx = blockIdx.x * 256 + threadIdx.x;
  int p = idx & (LL - 1);
  int b = idx >> 12;
  float pr[4];
#pragma unroll
  for (int c = 0; c < 4; ++c) pr[c] = prior[((size_t)b * 4 + c) * LL + p];
  float s = sigf(alpha[0]);
  float g2[4];
#pragma unroll
  for (int j = 0; j < 4; ++j) g2[j] = b2[j];
  for (int o = 0; o < 32; ++o) {
    float g = b1[o];
#pragma unroll
    for (int c = 0; c < 4; ++c) g = fmaf(pr[c], w1[o * 4 + c], g);
    g = (g - bnm[o]) * rsqrtf(bnv[o] + 1e-5f) * bnw[o] + bnb[o];
    g = fmaxf(g, 0.0f);
#pragma unroll
    for (int j = 0; j < 4; ++j) g2[j] = fmaf(g, w2[j * 32 + o], g2[j]);
  }
#pragma unroll
  for (int j = 0; j < 4; ++j)
    Wg[((size_t)b * 4 + j) * LL + p] = 1.0f + s * (sigf(g2[j]) - 1.0f);
}

// ---------------------------------------------------------------------------
// FUSED conv+proj: xz bf16 in, xcT bf16 out, projS f32 (scan order).
// ---------------------------------------------------------------------------
__global__ __launch_bounds__(1024) void convproj_k(const bf16t* __restrict__ xz,
                                                   const float* __restrict__ cw,
                                                   const float* __restrict__ cb,
                                                   const float* __restrict__ xpwT,
                                                   bf16t* __restrict__ xcT,
                                                   float* __restrict__ projS) {
  __shared__ float sX[96 * 65];   // 24.96 KB
  __shared__ float4 sP[512];      // 8 KB q-partials
  const int tid = threadIdx.x;
  const int b = blockIdx.y;
  const int h = blockIdx.x;
  const int px = tid & 63;
  const int ku = __builtin_amdgcn_readfirstlane((tid >> 6) & 3);
  const int hf = __builtin_amdgcn_readfirstlane((tid >> 8) & 1);
  const int q  = __builtin_amdgcn_readfirstlane(tid >> 9);
  f32x2 a01 = {0.f, 0.f}, a23 = {0.f, 0.f};

#pragma unroll
  for (int half = 0; half < 2; ++half) {
    for (int idx = tid; idx < 96 * 16; idx += 1024) {
      int ddl = idx >> 4, pq = idx & 15;
      int w0 = pq * 4;
      int dd = half * 96 + ddl;
      const bf16t* base = xz + ((size_t)b * 384 + dd) * LL + h * 64 + w0;
      const float* wp = cw + dd * 9;
      float bv = cb[dd];
      f32x2 s01 = {bv, bv}, s23 = {bv, bv};
#pragma unroll
      for (int dh = -1; dh <= 1; ++dh) {
        int hh = h + dh;
        if (hh < 0 || hh >= HH) continue;
        const bf16t* row = base + dh * 64;
        ushort4 cmu = *(const ushort4*)row;
        float cmx = b2f(cmu.x), cmy = b2f(cmu.y), cmz = b2f(cmu.z), cmw = b2f(cmu.w);
        float lf = (w0 > 0)  ? b2f(row[-1]) : 0.0f;
        float rt = (w0 < 60) ? b2f(row[4])  : 0.0f;
        float c0 = wp[(dh + 1) * 3], c1 = wp[(dh + 1) * 3 + 1], c2 = wp[(dh + 1) * 3 + 2];
        s01 = pkfma((f32x2){lf,  cmx}, (f32x2){c0, c0}, s01);
        s01 = pkfma((f32x2){cmx, cmy}, (f32x2){c1, c1}, s01);
        s01 = pkfma((f32x2){cmy, cmz}, (f32x2){c2, c2}, s01);
        s23 = pkfma((f32x2){cmy, cmz}, (f32x2){c0, c0}, s23);
        s23 = pkfma((f32x2){cmz, cmw}, (f32x2){c1, c1}, s23);
        s23 = pkfma((f32x2){cmw, rt},  (f32x2){c2, c2}, s23);
      }
      float* so = &sX[ddl * 65 + w0];
      float v0 = s01[0], v1 = s01[1], v2 = s23[0], v3 = s23[1];
      so[0] = v0 * sigf(v0);
      so[1] = v1 * sigf(v1);
      so[2] = v2 * sigf(v2);
      so[3] = v3 * sigf(v3);
    }
    __syncthreads();
    for (int idx = tid; idx < 64 * 96; idx += 1024) {
      int pp = idx / 96, ddl = idx % 96;
      xcT[((size_t)b * LL + h * 64 + pp) * DIN + half * 96 + ddl] =
          f2b(sX[ddl * 65 + pp]);
    }
    {
      const int ddl0 = q * 48;
      const float* wp = xpwT + (size_t)ku * (DIN * 8) + (half * 96 + ddl0) * 8 + hf * 4;
#pragma unroll 8
      for (int d48 = 0; d48 < 48; ++d48) {
        float xv = sX[(ddl0 + d48) * 65 + px];
        const float4 w4 = *(const float4*)(wp + d48 * 8);
        const f32x2 xv2 = {xv, xv};
        a01 = pkfma(xv2, (f32x2){w4.x, w4.y}, a01);
        a23 = pkfma(xv2, (f32x2){w4.z, w4.w}, a23);
      }
    }
    __syncthreads();
  }
  const int slot = tid & 511;
  if (q == 1) sP[slot] = make_float4(a01[0], a01[1], a23[0], a23[1]);
  __syncthreads();
  if (q == 0) {
    float4 o = sP[slot];
    float r0 = a01[0] + o.x, r1 = a01[1] + o.y, r2 = a23[0] + o.z, r3 = a23[1] + o.w;
    const int p = h * 64 + px;
    int l;
    if (ku == 0) l = p;
    else if (ku == 1) l = trp(p);
    else if (ku == 2) l = LL - 1 - p;
    else l = LL - 1 - trp(p);
    float* pb = projS + (((size_t)b * KK + ku) * LL + l) * 8 + hf * 4;
    *(float4*)pb = make_float4(r0, r1, r2, r3);
  }
}

// ---------------------------------------------------------------------------
// Scan pass 1 (PAIRED): xcT bf16; carries f32.
// ---------------------------------------------------------------------------
__global__ __launch_bounds__(192) void scan_part_k(const bf16t* __restrict__ xcT,
                                                   const float* __restrict__ projS,
                                                   const float* __restrict__ dtw,
                                                   const float* __restrict__ dtb,
                                                   const float* __restrict__ A_logs,
                                                   float* __restrict__ carrP,
                                                   float* __restrict__ carrH) {
  const int s = blockIdx.x, kp = blockIdx.y, b = blockIdx.z;
  const int d = threadIdx.x;
  const int kA = kp, kB = kp + 2;
  const int s2 = SS - 1 - s;
  const int kdA = kA * DIN + d, kdB = kB * DIN + d;
  float wrA[6], wrB[6];
#pragma unroll
  for (int r = 0; r < 6; ++r) { wrA[r] = dtw[kdA * 6 + r]; wrB[r] = dtw[kdB * 6 + r]; }
  const float biasA = dtb[kdA], biasB = dtb[kdB];
  const float AaA = -__expf(A_logs[kdA]), AaB = -__expf(A_logs[kdB]);
  const int l0 = s * LC;
  const int p0 = pix_of(kA, l0);
  const int dp = pix_of(kA, l0 + 1) - p0;
  const bf16t* xp = xcT + ((size_t)b * LL + p0) * DIN + d;
  const long xstep = (long)dp * DIN;
  const float* prA = projS + (((size_t)b * KK + kA) * LL + l0) * 8;
  const float* prB = projS + (((size_t)b * KK + kB) * LL + s2 * LC + (LC - 1)) * 8;
  float PA = 1.0f, HA = 0.0f, PB = 1.0f, HB = 0.0f;
#pragma unroll 2
  for (int j = 0; j < LC; ++j) {
    float4 a0 = *(const float4*)prA;
    float4 a1 = *(const float4*)(prA + 4);
    prA += 8;
    float4 b0 = *(const float4*)prB;
    float4 b1 = *(const float4*)(prB + 4);
    prB -= 8;
    float xv = b2f(*xp);
    xp += xstep;
    {
      float dtr = biasA;
      dtr = fmaf(a0.x, wrA[0], dtr);
      dtr = fmaf(a0.y, wrA[1], dtr);
      dtr = fmaf(a0.z, wrA[2], dtr);
      dtr = fmaf(a0.w, wrA[3], dtr);
      dtr = fmaf(a1.x, wrA[4], dtr);
      dtr = fmaf(a1.y, wrA[5], dtr);
      float e = exp2fast(fminf(dtr, 80.0f) * LOG2E);
      float u = log2fast(1.0f + e);
      float a = exp2fast(u * AaA);
      float dt = u * LN2;
      HA = fmaf(a, HA, dt * a1.z * xv);
      PA *= a;
    }
    {
      float dtr = biasB;
      dtr = fmaf(b0.x, wrB[0], dtr);
      dtr = fmaf(b0.y, wrB[1], dtr);
      dtr = fmaf(b0.z, wrB[2], dtr);
      dtr = fmaf(b0.w, wrB[3], dtr);
      dtr = fmaf(b1.x, wrB[4], dtr);
      dtr = fmaf(b1.y, wrB[5], dtr);
      float e = exp2fast(fminf(dtr, 80.0f) * LOG2E);
      float u = log2fast(1.0f + e);
      float a = exp2fast(u * AaB);
      float dt = u * LN2;
      HB = fmaf(PB, dt * b1.z * xv, HB);
      PB *= a;
    }
  }
  size_t oA = ((size_t)((b * KK + kA) * SS + s)) * DIN + d;
  size_t oB = ((size_t)((b * KK + kB) * SS + s2)) * DIN + d;
  carrP[oA] = PA;
  carrH[oA] = HA;
  carrP[oB] = PB;
  carrH[oB] = HB;
}

// ---------------------------------------------------------------------------
// Scan pass 2: serial combine of SS carries -> per-segment initial state h0
// ---------------------------------------------------------------------------
__global__ __launch_bounds__(192) void scan_fix_k(const float* __restrict__ carrP,
                                                  const float* __restrict__ carrH,
                                                  float* __restrict__ h0) {
  const int k = blockIdx.x, b = blockIdx.y, d = threadIdx.x;
  size_t base = ((size_t)(b * KK + k)) * SS * DIN + d;
  float h = 0.0f;
#pragma unroll 4
  for (int s = 0; s < SS; ++s) {
    h0[base + (size_t)s * DIN] = h;
    h = fmaf(carrP[base + (size_t)s * DIN], h, carrH[base + (size_t)s * DIN]);
  }
}

// ---------------------------------------------------------------------------
// Scan pass 3: apply + gate + paired merge; xcT bf16 in (reg-cached for dir B),
// ymT/ymT2 bf16 out.
// ---------------------------------------------------------------------------
__global__ __launch_bounds__(192) void scan_apply_k(const bf16t* __restrict__ xcT,
                                                    const float* __restrict__ projS,
                                                    const float* __restrict__ Wg,
                                                    const float* __restrict__ h0,
                                                    const float* __restrict__ dtw,
                                                    const float* __restrict__ dtb,
                                                    const float* __restrict__ A_logs,
                                                    const float* __restrict__ Ds,
                                                    bf16t* __restrict__ ymT,
                                                    bf16t* __restrict__ ymT2) {
  const int s = blockIdx.x, kp = blockIdx.y, b = blockIdx.z;
  const int d = threadIdx.x;
  __shared__ float sAcc[LC * DIN];  // 24 KB, column d thread-private
  float xr[LC];                     // register cache of this segment's xv
  {
    const int k = kp, kd = k * DIN + d;
    float wr[6];
#pragma unroll
    for (int r = 0; r < 6; ++r) wr[r] = dtw[kd * 6 + r];
    const float bias = dtb[kd];
    const float Aa = -__expf(A_logs[kd]);
    const float Dv = Ds[kd];
    const int l0 = s * LC;
    const int p0 = pix_of(k, l0);
    const int dp = pix_of(k, l0 + 1) - p0;
    const bf16t* xp = xcT + ((size_t)b * LL + p0) * DIN + d;
    const long xstep = (long)dp * DIN;
    const float* pr = projS + (((size_t)b * KK + k) * LL + l0) * 8;
    const float* wg = Wg + ((size_t)b * KK + k) * LL + l0;
    float h = h0[((size_t)((b * KK + k) * SS + s)) * DIN + d];
#pragma unroll
    for (int j = 0; j < LC; ++j) {
      float4 q0 = *(const float4*)pr;
      float4 q1 = *(const float4*)(pr + 4);
      pr += 8;
      float xv = b2f(*xp);
      xp += xstep;
      xr[j] = xv;
      float dtr = bias;
      dtr = fmaf(q0.x, wr[0], dtr);
      dtr = fmaf(q0.y, wr[1], dtr);
      dtr = fmaf(q0.z, wr[2], dtr);
      dtr = fmaf(q0.w, wr[3], dtr);
      dtr = fmaf(q1.x, wr[4], dtr);
      dtr = fmaf(q1.y, wr[5], dtr);
      float e = exp2fast(fminf(dtr, 80.0f) * LOG2E);
      float u = log2fast(1.0f + e);
      float a = exp2fast(u * Aa);
      float dt = u * LN2;
      h = fmaf(a, h, dt * q1.z * xv);
      sAcc[j * DIN + d] = fmaf(h, q1.w, Dv * xv) * wg[j];
    }
  }
  {
    const int k = kp + 2, kd = k * DIN + d;
    const int s2 = SS - 1 - s;
    float wr[6];
#pragma unroll
    for (int r = 0; r < 6; ++r) wr[r] = dtw[kd * 6 + r];
    const float bias = dtb[kd];
    const float Aa = -__expf(A_logs[kd]);
    const float Dv = Ds[kd];
    const int l0 = s2 * LC;
    const float* pr = projS + (((size_t)b * KK + k) * LL + l0) * 8;
    const float* wg = Wg + ((size_t)b * KK + k) * LL + l0;
    float h = h0[((size_t)((b * KK + k) * SS + s2)) * DIN + d];
#pragma unroll
    for (int j = 0; j < LC; ++j) {
      float4 q0 = *(const float4*)pr;
      float4 q1 = *(const float4*)(pr + 4);
      pr += 8;
      float xv = xr[LC - 1 - j];   // same pixels, reversed (static index)
      float dtr = bias;
      dtr = fmaf(q0.x, wr[0], dtr);
      dtr = fmaf(q0.y, wr[1], dtr);
      dtr = fmaf(q0.z, wr[2], dtr);
      dtr = fmaf(q0.w, wr[3], dtr);
      dtr = fmaf(q1.x, wr[4], dtr);
      dtr = fmaf(q1.y, wr[5], dtr);
      float e = exp2fast(fminf(dtr, 80.0f) * LOG2E);
      float u = log2fast(1.0f + e);
      float a = exp2fast(u * Aa);
      float dt = u * LN2;
      h = fmaf(a, h, dt * q1.z * xv);
      float y = fmaf(h, q1.w, Dv * xv) * wg[j];
      sAcc[(LC - 1 - j) * DIN + d] += y;
    }
  }
  bf16t* dst;
  if (kp == 0)
    dst = ymT + (size_t)b * (384 * (size_t)LL) + (size_t)(s * LC) * DIN + d;  // xz overlay
  else
    dst = ymT2 + ((size_t)b * LL + s * LC) * DIN + d;
#pragma unroll 4
  for (int j = 0; j < LC; ++j) dst[(size_t)j * DIN] = f2b(sAcc[j * DIN + d]);
}

// ---------------------------------------------------------------------------
extern "C" void kernel_launch(void* const* d_in, const int* in_sizes, int n_in,
                              void* d_out, int out_size, void* d_ws, size_t ws_size,
                              hipStream_t stream) {
  const float* x      = (const float*)d_in[0];
  const float* prior  = (const float*)d_in[1];
  const float* alpha  = (const float*)d_in[2];
  const float* ipw    = (const float*)d_in[3];
  const float* cw     = (const float*)d_in[4];
  const float* cb     = (const float*)d_in[5];
  const float* xpw    = (const float*)d_in[6];
  const float* dtw    = (const float*)d_in[7];
  const float* dtb    = (const float*)d_in[8];
  const float* A_logs = (const float*)d_in[9];
  const float* Ds     = (const float*)d_in[10];
  const float* onw    = (const float*)d_in[11];
  const float* onb    = (const float*)d_in[12];
  const float* opw    = (const float*)d_in[13];
  const float* w1     = (const float*)d_in[14];
  const float* b1     = (const float*)d_in[15];
  const float* bnw    = (const float*)d_in[16];
  const float* bnb    = (const float*)d_in[17];
  const float* bnm    = (const float*)d_in[18];
  const float* bnv    = (const float*)d_in[19];
  const float* w2     = (const float*)d_in[20];
  const float* b2     = (const float*)d_in[21];
  float* out = (float*)d_out;

  char* ws = (char*)d_ws;
  // bf16 intermediates; footprint ends at 64,659,456 B.
  bf16t* xz    = (bf16t*)(ws);              // [B,384,L] bf16  25.2 MB
  bf16t* xcT   = (bf16t*)(ws + 25165824);   // [B,L,192] bf16  12.6 MB
  bf16t* ymT2  = (bf16t*)(ws + 37748736);   // [B,L,192] bf16  12.6 MB
  float* projS = (float*)(ws + 50331648);   // [B,K,L,8] f32    4.2 MB
  float* Wgb   = (float*)(ws + 54525952);   // [B,4,L]          0.5 MB
  float* carrP = (float*)(ws + 55050240);   // [B,K,SS,192]     3.0 MB
  float* carrH = (float*)(ws + 58195968);   // [B,K,SS,192]     3.0 MB
  float* h0b   = (float*)(ws + 61341696);   // [B,K,SS,192]     3.0 MB
  float* xpwT  = (float*)(ws + 64487424);   // [K,DIN,8]       24.6 KB
  bf16t* ipwb  = (bf16t*)(ws + 64512000);   // [384,96] bf16   73.7 KB
  bf16t* opwbh = (bf16t*)(ws + 64585728);   // [96,192] bf16   36.9 KB
  bf16t* opwbl = (bf16t*)(ws + 64622592);   // [96,192] bf16   36.9 KB (ends 64659456)
  bf16t* ymT   = xz;   // overlay: x_ssm half of xz (dead after convproj)

  // 1) prior -> direction gates (+ weight preps in blocks 0,1,2)
  p2w_k<<<(BB * LL) / 256, 256, 0, stream>>>(prior, alpha, w1, b1, bnw, bnb, bnm,
                                             bnv, w2, b2, xpw, ipw, opw, xpwT,
                                             ipwb, opwbh, opwbl, Wgb);
  // 2) in_proj via MFMA bf16 -> xz bf16
  gemm_in_mfma_k<<<dim3(LL / 32, 1, BB), 256, 0, stream>>>(x, ipwb, xz);
  // 3) fused dwconv+SiLU + x_proj(scan-order) + transpose
  convproj_k<<<dim3(HH, BB), 1024, 0, stream>>>(xz, cw, cb, xpwT, xcT, projS);
  // 4) scan: paired segment carries
  scan_part_k<<<dim3(SS, 2, BB), 192, 0, stream>>>(xcT, projS, dtw, dtb, A_logs,
                                                   carrP, carrH);
  // 5) scan: serial carry combine
  scan_fix_k<<<dim3(KK, BB), 192, 0, stream>>>(carrP, carrH, h0b);
  // 6) scan: apply + gate + paired merge (ymT overlaid on xz x_ssm half)
  scan_apply_k<<<dim3(SS, 2, BB), 192, 0, stream>>>(xcT, projS, Wgb, h0b, dtw, dtb,
                                                    A_logs, Ds, ymT, ymT2);
  // 7) fused LayerNorm*silu(z) + out_proj MFMA -> out f32
  ln_gemm_out_k<<<dim3(LL / 64, 1, BB), 384, 0, stream>>>(ymT, ymT2, xz, onw, onb,
                                                          opwbh, opwbl, out);
}